// Round 8
// baseline (721.919 us; speedup 1.0000x reference)
//
#include <hip/hip_runtime.h>
#include <math.h>

#define EPSB 1e-5f

// Bi=128 Bc=64 T=32 C=300 OQK=75 H=128 LAT=1024
// Padded stacked o-dim (512): q [0,96) (75 real), k [96,192) (75 real), v [192,512) (300 real)
// Compact packed kall (per image, ushort): q/k tiles ot 0..11: units ot*20+ks*2+pl (hi+lo);
//   v tiles ot 12..31: units 240+(ot-12)*10+ks (hi only). 440 units x 512 ushort = 225280 ushort/img.
// Unit layout: [lane=64][8] ushort; element (o=16*ot+lr, c=32*ks+8*kg+e), lane=kg*16+lr.
// ws layout (float offsets):
static const long OFS_BASE  = 0;                      // 128*128
static const long OFS_BALL  = 16384;                  // 128*512
static const long OFS_MEAN  = 81920;                  // 128*1024
static const long OFS_CAPB  = 212992;                 // capP: 64*20480 ushort = 655360 floats
static const long OFS_RAWP  = 868352;                 // kall: 128*225280 ushort = 14,417,920 floats
static const long OFS_X     = 15286272;               // 128*64*300
static const long OFS_H1    = OFS_RAWP;               // alias (kall dead after k_attn8)

using bf16x8 = __attribute__((ext_vector_type(8))) __bf16;
using f32x4  = __attribute__((ext_vector_type(4))) float;
#define MFMA16(a, b, c) __builtin_amdgcn_mfma_f32_16x16x32_bf16(a, b, c, 0, 0, 0)

__device__ inline ushort f2bf(float f) {
  const unsigned u = __float_as_uint(f);
  return (ushort)((u + 0x7FFFu + ((u >> 16) & 1u)) >> 16);
}
__device__ inline float bf2f(ushort h) { return __uint_as_float(((unsigned)h) << 16); }

// ---------------- K1a: img_mean over 36 regions ----------------
__global__ void k_mean(const float* __restrict__ img, float* __restrict__ mean) {
  const int idx = blockIdx.x * 256 + threadIdx.x;      // 131072 total
  const int i = idx >> 10, l = idx & 1023;
  const float* p = img + (size_t)i * 36 * 1024 + l;
  float s = 0.f;
#pragma unroll
  for (int r = 0; r < 36; ++r) s += p[r * 1024];
  mean[idx] = s * (1.0f / 36.0f);
}

// ---------------- K1b: base = mean @ adapt_W^T + adapt_b ----------------
__global__ void k_base(const float* __restrict__ mean, const float* __restrict__ W,
                       const float* __restrict__ b, float* __restrict__ base) {
  __shared__ float m_s[1024];
  const int i = blockIdx.x, tid = threadIdx.x;   // 128 threads
  for (int k = 0; k < 8; ++k) m_s[tid + 128 * k] = mean[i * 1024 + tid + 128 * k];
  __syncthreads();
  float acc = b[tid];
  const float* wr = W + (size_t)tid * 1024;
#pragma unroll 4
  for (int l = 0; l < 1024; ++l) acc = fmaf(m_s[l], wr[l], acc);
  base[i * 128 + tid] = acc;
}

// ---------------- K2b: stacked conv biases ball[i][512] ----------------
__global__ void k_bias(const float* __restrict__ qbW, const float* __restrict__ qbb,
                       const float* __restrict__ kbW, const float* __restrict__ kbb,
                       const float* __restrict__ vbW, const float* __restrict__ vbb,
                       const float* __restrict__ base, float* __restrict__ ball) {
  __shared__ float bs[128];
  const int i = blockIdx.y, tid = threadIdx.x;
  if (tid < 128) bs[tid] = base[i * 128 + tid];
  __syncthreads();
  const int o = blockIdx.x * 256 + tid;
  if (o >= 512) return;
  const float* Wr = nullptr;
  float bb = 0.0f;
  if (o < 75)                   { Wr = qbW + (size_t)o * 128;         bb = qbb[o]; }
  else if (o >= 96 && o < 171)  { Wr = kbW + (size_t)(o - 96) * 128;  bb = kbb[o - 96]; }
  else if (o >= 192 && o < 492) { Wr = vbW + (size_t)(o - 192) * 128; bb = vbb[o - 192]; }
  float acc = 0.0f;
  if (Wr) {
#pragma unroll 4
    for (int h = 0; h < 128; ++h) acc = fmaf(Wr[h], bs[h], acc);
    acc += bb;
  }
  ball[i * 512 + o] = acc;
}

// ---------------- K2c: cap -> packed split-bf16 capP [n][nt=2][ks=10][pl=2][64][8] ----------------
__global__ void __launch_bounds__(256) k_capp(const float* __restrict__ cap,
                                              ushort* __restrict__ capP) {
  __shared__ float ct[32 * 301];
  const int n = blockIdx.x, tid = threadIdx.x;
  const float* capn = cap + (size_t)n * 9600;
  {
    const int r = tid >> 3, c8 = tid & 7;
    for (int m = 0; m < 38; ++m) {
      const int c = c8 + 8 * m;
      if (c < 300) ct[r * 301 + c] = capn[r * 300 + c];
    }
  }
  __syncthreads();
  ushort* dst = capP + (size_t)n * 20480;
  for (int u = 0; u < 10; ++u) {
    const int ul = tid + 256 * u;
    const int unit = ul >> 6, lane = ul & 63;
    const int nt = unit / 20, rem = unit % 20;
    const int ks = rem >> 1, pl = rem & 1;
    const int kg = lane >> 4, lr = lane & 15;
    const int t = nt * 16 + lr;
    ushort o8[8];
#pragma unroll
    for (int e = 0; e < 8; ++e) {
      const int c = 32 * ks + 8 * kg + e;
      const float val = (c < 300) ? ct[t * 301 + c] : 0.f;
      const ushort hi = f2bf(val);
      o8[e] = pl ? f2bf(val - bf2f(hi)) : hi;
    }
    uint4 pk;
    pk.x = (uint)o8[0] | ((uint)o8[1] << 16);
    pk.y = (uint)o8[2] | ((uint)o8[3] << 16);
    pk.z = (uint)o8[4] | ((uint)o8[5] << 16);
    pk.w = (uint)o8[6] | ((uint)o8[7] << 16);
    *reinterpret_cast<uint4*>(dst + unit * 512 + lane * 8) = pk;
  }
}

// ---------------- K3: fused hypernet GEMM + row-BN + split-bf16 pack -> compact kall ----------------
__global__ void __launch_bounds__(256) k_hyp2(
    const float* __restrict__ qkW, const float* __restrict__ qkb,
    const float* __restrict__ kkW, const float* __restrict__ kkb,
    const float* __restrict__ vkW, const float* __restrict__ vkb,
    const float* __restrict__ qs, const float* __restrict__ qb,
    const float* __restrict__ ks_, const float* __restrict__ kb_,
    const float* __restrict__ vs, const float* __restrict__ vb,
    const float* __restrict__ base, ushort* __restrict__ kall) {
  __shared__ float smem[19200];
  __shared__ float scl[64], shf[64];
  const int g = blockIdx.x, half = blockIdx.y, tid = threadIdx.x;
  const int i0g = half * 64;
  const int ot = g >> 4, lr = g & 15;
  const bool isV = (g >= 192);

  const float* Wb = nullptr;
  const float* bvec = nullptr;
  float bns = 0.f, bnb = 0.f;
  if (g < 75)                    { Wb = qkW + (size_t)g * 38400;          bvec = qkb + g * 300;          bns = qs[g];        bnb = qb[g]; }
  else if (g >= 96 && g < 171)   { Wb = kkW + (size_t)(g - 96) * 38400;   bvec = kkb + (g - 96) * 300;   bns = ks_[g - 96];  bnb = kb_[g - 96]; }
  else if (g >= 192 && g < 492)  { Wb = vkW + (size_t)(g - 192) * 38400;  bvec = vkb + (g - 192) * 300;  bns = vs[g - 192];  bnb = vb[g - 192]; }

  if (!Wb) {  // pad rows: exact zeros
    const uint4 z = make_uint4(0, 0, 0, 0);
    if (!isV) {
      for (int m = 0; m < 20; ++m) {
        const int idx = tid + 256 * m;
        const int ii = idx & 63, zz = idx >> 6;
        const int kg2 = zz & 3, pl = (zz >> 2) & 1, ks2 = zz >> 3;
        const size_t off = (size_t)(i0g + ii) * 225280 +
                           (size_t)(ot * 20 + ks2 * 2 + pl) * 512 + (kg2 * 16 + lr) * 8;
        *reinterpret_cast<uint4*>(kall + off) = z;
      }
    } else {
      for (int m = 0; m < 10; ++m) {
        const int idx = tid + 256 * m;
        const int ii = idx & 63, zz = idx >> 6;
        const int kg2 = zz & 3, ks2 = zz >> 2;
        const size_t off = (size_t)(i0g + ii) * 225280 +
                           (size_t)(240 + (ot - 12) * 10 + ks2) * 512 + (kg2 * 16 + lr) * 8;
        *reinterpret_cast<uint4*>(kall + off) = z;
      }
    }
    return;
  }

  // stage base^T: bs[h*68 + i]
  for (int m = 0; m < 32; ++m) {
    const int idx = tid + 256 * m;
    const int ii = idx >> 7, h = idx & 127;
    smem[h * 68 + ii] = base[(size_t)(i0g + ii) * 128 + h];
  }
  __syncthreads();

  const int cg = tid >> 2, ig = tid & 3;
  const int c0 = cg * 5, i0 = ig * 16;
  float acc[5][16];
#pragma unroll
  for (int cc = 0; cc < 5; ++cc)
#pragma unroll
    for (int ii = 0; ii < 16; ++ii) acc[cc][ii] = 0.f;
  float* Ws = smem + 8704;
  for (int hc = 0; hc < 16; ++hc) {
    __syncthreads();
    for (int m = 0; m < 10; ++m) {
      const int idx = tid + 256 * m;
      const int c = idx >> 3, hh = idx & 7;
      Ws[c * 9 + hh] = (c < 300) ? Wb[(size_t)c * 128 + hc * 8 + hh] : 0.f;
    }
    __syncthreads();
#pragma unroll
    for (int hh = 0; hh < 8; ++hh) {
      const int hg = hc * 8 + hh;
      float bvf[16];
#pragma unroll
      for (int u2 = 0; u2 < 4; ++u2) {
        const float4 b4 = *reinterpret_cast<const float4*>(&smem[hg * 68 + i0 + u2 * 4]);
        bvf[u2 * 4 + 0] = b4.x; bvf[u2 * 4 + 1] = b4.y;
        bvf[u2 * 4 + 2] = b4.z; bvf[u2 * 4 + 3] = b4.w;
      }
#pragma unroll
      for (int cc = 0; cc < 5; ++cc) {
        const float wv = Ws[(c0 + cc) * 9 + hh];
#pragma unroll
        for (int ii = 0; ii < 16; ++ii) acc[cc][ii] = fmaf(wv, bvf[ii], acc[cc][ii]);
      }
    }
  }
  __syncthreads();
#pragma unroll
  for (int cc = 0; cc < 5; ++cc) {
    const int c = c0 + cc;
    if (c < 300) {
      const float bv = bvec[c];
#pragma unroll
      for (int ii = 0; ii < 16; ++ii) smem[c * 64 + i0 + ii] = acc[cc][ii] + bv;
    }
  }
  __syncthreads();
  {
    const int si = tid >> 2, p = tid & 3;
    float s1 = 0.f, s2 = 0.f;
    for (int c = p; c < 300; c += 4) {
      const float x = smem[c * 64 + si];
      s1 += x;
      s2 += x * x;
    }
    s1 += __shfl_xor(s1, 1); s2 += __shfl_xor(s2, 1);
    s1 += __shfl_xor(s1, 2); s2 += __shfl_xor(s2, 2);
    const float mu = s1 * (1.0f / 300.0f);
    const float var = s2 * (1.0f / 300.0f) - mu * mu;
    const float scale = bns / sqrtf(var + EPSB);
    if (p == 0) { scl[si] = scale; shf[si] = bnb - mu * scale; }
  }
  __syncthreads();
  if (!isV) {  // q/k: hi + lo planes
    for (int m = 0; m < 20; ++m) {
      const int idx = tid + 256 * m;
      const int ii = idx & 63, zz = idx >> 6;
      const int kg2 = zz & 3, pl = (zz >> 2) & 1, ks2 = zz >> 3;
      const float sc = scl[ii], sh = shf[ii];
      ushort o8[8];
#pragma unroll
      for (int e = 0; e < 8; ++e) {
        const int c = ks2 * 32 + kg2 * 8 + e;
        float val = 0.f;
        if (c < 300) val = fmaf(smem[c * 64 + ii], sc, sh);
        const ushort hi = f2bf(val);
        o8[e] = pl ? f2bf(val - bf2f(hi)) : hi;
      }
      uint4 pk;
      pk.x = (uint)o8[0] | ((uint)o8[1] << 16);
      pk.y = (uint)o8[2] | ((uint)o8[3] << 16);
      pk.z = (uint)o8[4] | ((uint)o8[5] << 16);
      pk.w = (uint)o8[6] | ((uint)o8[7] << 16);
      const size_t off = (size_t)(i0g + ii) * 225280 +
                         (size_t)(ot * 20 + ks2 * 2 + pl) * 512 + (kg2 * 16 + lr) * 8;
      *reinterpret_cast<uint4*>(kall + off) = pk;
    }
  } else {     // v: hi plane only
    for (int m = 0; m < 10; ++m) {
      const int idx = tid + 256 * m;
      const int ii = idx & 63, zz = idx >> 6;
      const int kg2 = zz & 3, ks2 = zz >> 2;
      const float sc = scl[ii], sh = shf[ii];
      ushort o8[8];
#pragma unroll
      for (int e = 0; e < 8; ++e) {
        const int c = ks2 * 32 + kg2 * 8 + e;
        float val = 0.f;
        if (c < 300) val = fmaf(smem[c * 64 + ii], sc, sh);
        o8[e] = f2bf(val);
      }
      uint4 pk;
      pk.x = (uint)o8[0] | ((uint)o8[1] << 16);
      pk.y = (uint)o8[2] | ((uint)o8[3] << 16);
      pk.z = (uint)o8[4] | ((uint)o8[5] << 16);
      pk.w = (uint)o8[6] | ((uint)o8[7] << 16);
      const size_t off = (size_t)(i0g + ii) * 225280 +
                         (size_t)(240 + (ot - 12) * 10 + ks2) * 512 + (kg2 * 16 + lr) * 8;
      *reinterpret_cast<uint4*>(kall + off) = pk;
    }
  }
}

// ---------------- K4: fused attention; dual-caption blocks share kall A-loads ----------------
__global__ void __launch_bounds__(256, 4) k_attn8(
    const float* __restrict__ cap, const ushort* __restrict__ kall,
    const ushort* __restrict__ capP, const float* __restrict__ ball,
    const float* __restrict__ gptr, float* __restrict__ x_all) {
  __shared__ float qk_s[192 * 36];
  __shared__ ushort at_p[2 * 2 * 2 * 64 * 8];   // [cap][tt][pl][64][8]
  // XCD swizzle: xcd = bid&7 owns images [xcd*16,+16); within: i-major, caption-pair minor
  const int bid = blockIdx.x;                   // 4096 blocks
  const int xcd = bid & 7, q = bid >> 3;
  const int i = xcd * 16 + (q >> 5);
  const int n0 = (q & 31) * 2;                  // captions n0, n0+1
  const int tid = threadIdx.x;
  const int lane = tid & 63, w = tid >> 6;
  const int lrow = lane & 15, kg = lane >> 4;
  const float gamma = gptr[0];
  const ushort* kpL = kall + (size_t)i * 225280 + lane * 8;
  const ushort* cpL[2] = {capP + (size_t)n0 * 20480 + lane * 8,
                          capP + (size_t)(n0 + 1) * 20480 + lane * 8};
  const float* bal = ball + i * 512;

  // ---- P1: q+k rows [0,192) for BOTH captions; A loaded once
  f32x4 acc[3][2][2];   // [mt][cap][nt]
#pragma unroll
  for (int a = 0; a < 3; ++a)
#pragma unroll
    for (int c2 = 0; c2 < 2; ++c2)
#pragma unroll
      for (int b2 = 0; b2 < 2; ++b2) acc[a][c2][b2] = (f32x4){0.f, 0.f, 0.f, 0.f};
  for (int ks = 0; ks < 10; ++ks) {
    bf16x8 Ah[3], Al[3];
#pragma unroll
    for (int mt = 0; mt < 3; ++mt) {
      const ushort* p = kpL + (size_t)((w * 3 + mt) * 20 + ks * 2) * 512;
      Ah[mt] = *reinterpret_cast<const bf16x8*>(p);
      Al[mt] = *reinterpret_cast<const bf16x8*>(p + 512);
    }
#pragma unroll
    for (int cc = 0; cc < 2; ++cc)
#pragma unroll
      for (int nt = 0; nt < 2; ++nt) {
        const ushort* p = cpL[cc] + (size_t)(nt * 20 + ks * 2) * 512;
        const bf16x8 Bh = *reinterpret_cast<const bf16x8*>(p);
        const bf16x8 Bl = *reinterpret_cast<const bf16x8*>(p + 512);
#pragma unroll
        for (int mt = 0; mt < 3; ++mt) {
          acc[mt][cc][nt] = MFMA16(Ah[mt], Bh, acc[mt][cc][nt]);
          acc[mt][cc][nt] = MFMA16(Ah[mt], Bl, acc[mt][cc][nt]);
          acc[mt][cc][nt] = MFMA16(Al[mt], Bh, acc[mt][cc][nt]);
        }
      }
  }

  // ---- P2 per caption (sequential; qk_s reused)
  for (int cc = 0; cc < 2; ++cc) {
    if (cc) __syncthreads();   // prior P2 readers done
#pragma unroll
    for (int mt = 0; mt < 3; ++mt)
#pragma unroll
      for (int nt = 0; nt < 2; ++nt)
#pragma unroll
        for (int r = 0; r < 4; ++r) {
          const int o = w * 48 + mt * 16 + kg * 4 + r;
          qk_s[o * 36 + nt * 16 + lrow] = acc[mt][cc][nt][r] + bal[o];
        }
    __syncthreads();
    {
      const int sg = tid & 7, tq = tid >> 3;
      const int s0 = sg * 4;
      float scA[4] = {0.f, 0.f, 0.f, 0.f}, scB[4] = {0.f, 0.f, 0.f, 0.f};
#pragma unroll 8
      for (int o = 0; o < 80; o += 2) {
        const float qa = qk_s[o * 36 + tq];
        const float4 ka = *reinterpret_cast<const float4*>(&qk_s[(96 + o) * 36 + s0]);
        const float qb = qk_s[(o + 1) * 36 + tq];
        const float4 kb = *reinterpret_cast<const float4*>(&qk_s[(97 + o) * 36 + s0]);
        scA[0] = fmaf(qa, ka.x, scA[0]); scB[0] = fmaf(qb, kb.x, scB[0]);
        scA[1] = fmaf(qa, ka.y, scA[1]); scB[1] = fmaf(qb, kb.y, scB[1]);
        scA[2] = fmaf(qa, ka.z, scA[2]); scB[2] = fmaf(qb, kb.z, scB[2]);
        scA[3] = fmaf(qa, ka.w, scA[3]); scB[3] = fmaf(qb, kb.w, scB[3]);
      }
      float sc[4];
#pragma unroll
      for (int u = 0; u < 4; ++u) sc[u] = scA[u] + scB[u];
      float m = fmaxf(fmaxf(sc[0], sc[1]), fmaxf(sc[2], sc[3]));
      m = fmaxf(m, __shfl_xor(m, 1));
      m = fmaxf(m, __shfl_xor(m, 2));
      m = fmaxf(m, __shfl_xor(m, 4));
      float ev[4], ssum = 0.f;
#pragma unroll
      for (int u = 0; u < 4; ++u) { ev[u] = expf(sc[u] - m); ssum += ev[u]; }
      ssum += __shfl_xor(ssum, 1);
      ssum += __shfl_xor(ssum, 2);
      ssum += __shfl_xor(ssum, 4);
      const float inv = 1.0f / ssum;
      const int tt = tq >> 4, lrp = tq & 15, kgp = sg >> 1, eb = (sg & 1) * 4;
      ushort h4[4], l4[4];
#pragma unroll
      for (int u = 0; u < 4; ++u) {
        const float val = ev[u] * inv;
        const ushort hi = f2bf(val);
        h4[u] = hi;
        l4[u] = f2bf(val - bf2f(hi));
      }
      uint2 ph, pl2;
      ph.x = (uint)h4[0] | ((uint)h4[1] << 16);
      ph.y = (uint)h4[2] | ((uint)h4[3] << 16);
      pl2.x = (uint)l4[0] | ((uint)l4[1] << 16);
      pl2.y = (uint)l4[2] | ((uint)l4[3] << 16);
      *reinterpret_cast<uint2*>(&at_p[cc * 2048 + ((tt * 2 + 0) * 64 + kgp * 16 + lrp) * 8 + eb]) = ph;
      *reinterpret_cast<uint2*>(&at_p[cc * 2048 + ((tt * 2 + 1) * 64 + kgp * 16 + lrp) * 8 + eb]) = pl2;
    }
  }
  __syncthreads();

  // ---- P3: v tiles [12,32) in 2 chunks; A loaded once, both captions
  ushort* vt = reinterpret_cast<ushort*>(qk_s);
#pragma unroll
  for (int ch = 0; ch < 2; ++ch) {
    const int TB = 12 + ch * 12;
    const int RB = TB * 16;
    const int nmt = ch ? 2 : 3;
    f32x4 vacc[3][2][2];   // [mi][cap][nt]
#pragma unroll
    for (int a = 0; a < 3; ++a)
#pragma unroll
      for (int c2 = 0; c2 < 2; ++c2)
#pragma unroll
        for (int b2 = 0; b2 < 2; ++b2) vacc[a][c2][b2] = (f32x4){0.f, 0.f, 0.f, 0.f};
    for (int ks = 0; ks < 10; ++ks) {
      bf16x8 Av[3];
      for (int mi = 0; mi < nmt; ++mi)
        Av[mi] = *reinterpret_cast<const bf16x8*>(
            kpL + (size_t)(240 + (TB - 12 + w + mi * 4) * 10 + ks) * 512);
#pragma unroll
      for (int cc = 0; cc < 2; ++cc)
#pragma unroll
        for (int nt = 0; nt < 2; ++nt) {
          const bf16x8 Bh = *reinterpret_cast<const bf16x8*>(cpL[cc] + (size_t)(nt * 20 + ks * 2) * 512);
          for (int mi = 0; mi < nmt; ++mi)
            vacc[mi][cc][nt] = MFMA16(Av[mi], Bh, vacc[mi][cc][nt]);
        }
    }
    for (int cc = 0; cc < 2; ++cc) {
      const int n = n0 + cc;
      __syncthreads();   // prior readers of vt/qk_s done
      for (int mi = 0; mi < nmt; ++mi) {
        const int tile = w + mi * 4;
#pragma unroll
        for (int nt = 0; nt < 2; ++nt) {
          const int kgp = nt * 2 + (lrow >> 3), ee = lrow & 7;
#pragma unroll
          for (int r = 0; r < 4; ++r) {
            const int vl = tile * 16 + kg * 4 + r;
            const float val = vacc[mi][cc][nt][r] + bal[RB + vl];
            const ushort hi = f2bf(val);
            vt[((tile * 2 + 0) * 64 + kgp * 16 + kg * 4 + r) * 8 + ee] = hi;
            vt[((tile * 2 + 1) * 64 + kgp * 16 + kg * 4 + r) * 8 + ee] = f2bf(val - bf2f(hi));
          }
        }
      }
      __syncthreads();
      {  // P3b: MFMA PV + residual + max
        bf16x8 ah[2], al[2];
#pragma unroll
        for (int tt = 0; tt < 2; ++tt) {
          ah[tt] = *reinterpret_cast<const bf16x8*>(&at_p[cc * 2048 + ((tt * 2 + 0) * 64 + lane) * 8]);
          al[tt] = *reinterpret_cast<const bf16x8*>(&at_p[cc * 2048 + ((tt * 2 + 1) * 64 + lane) * 8]);
        }
        const int npw = ch ? 2 : 3;
        for (int j = 0; j < npw; ++j) {
          const int ct = w * npw + j;
          const int c0 = ch * 192 + ct * 16 + (lane >> 4) * 4;
          const bf16x8 vh  = *reinterpret_cast<const bf16x8*>(&vt[((ct * 2 + 0) * 64 + lane) * 8]);
          const bf16x8 vl8 = *reinterpret_cast<const bf16x8*>(&vt[((ct * 2 + 1) * 64 + lane) * 8]);
          f32x4 a0 = (f32x4){0.f, 0.f, 0.f, 0.f}, a1 = (f32x4){0.f, 0.f, 0.f, 0.f};
          a0 = MFMA16(vh, ah[0], a0);
          a0 = MFMA16(vh, al[0], a0);
          a0 = MFMA16(vl8, ah[0], a0);
          a1 = MFMA16(vh, ah[1], a1);
          a1 = MFMA16(vh, al[1], a1);
          a1 = MFMA16(vl8, ah[1], a1);
          if (c0 < 300) {
            const int t0 = lane & 15;
            const float4 c4a = *reinterpret_cast<const float4*>(&cap[(size_t)n * 9600 + t0 * 300 + c0]);
            const float4 c4b = *reinterpret_cast<const float4*>(&cap[(size_t)n * 9600 + (t0 + 16) * 300 + c0]);
            float mx[4];
            mx[0] = fmaxf(fmaf(gamma, a0[0], c4a.x), fmaf(gamma, a1[0], c4b.x));
            mx[1] = fmaxf(fmaf(gamma, a0[1], c4a.y), fmaf(gamma, a1[1], c4b.y));
            mx[2] = fmaxf(fmaf(gamma, a0[2], c4a.z), fmaf(gamma, a1[2], c4b.z));
            mx[3] = fmaxf(fmaf(gamma, a0[3], c4a.w), fmaf(gamma, a1[3], c4b.w));
#pragma unroll
            for (int mmask = 1; mmask < 16; mmask <<= 1)
#pragma unroll
              for (int r = 0; r < 4; ++r) mx[r] = fmaxf(mx[r], __shfl_xor(mx[r], mmask));
            if ((lane & 15) == 0)
              *reinterpret_cast<float4*>(&x_all[((size_t)i * 64 + n) * 300 + c0]) =
                  make_float4(mx[0], mx[1], mx[2], mx[3]);
          }
        }
      }
    }
  }
}

// ---------------- K5a: h1 = x @ W1^T + b1 ----------------
__global__ void __launch_bounds__(256, 4) k_h1(
    const float* __restrict__ x_all, const float* __restrict__ W1,
    const float* __restrict__ b1, float* __restrict__ h1) {
  __shared__ float xt[32 * 68];
  __shared__ float wt[32 * 132];
  const int ec = blockIdx.x, i = blockIdx.y, tid = threadIdx.x;
  const int e0c = ec * 128;
  const int eg = tid & 15, ng = tid >> 4;
  const int e0 = eg * 8, n0 = ng * 4;
  float acc[4][8] = {};
  for (int cb = 0; cb < 10; ++cb) {
    const int c0 = cb * 32;
    __syncthreads();
    for (int k = 0; k < 8; ++k) {
      const int idx = tid + 256 * k;
      const int nn = idx >> 5, cl = idx & 31;
      const int c = c0 + cl;
      xt[cl * 68 + nn] = (c < 300) ? x_all[((size_t)i * 64 + nn) * 300 + c] : 0.0f;
    }
    for (int k = 0; k < 16; ++k) {
      const int idx = tid + 256 * k;
      const int ee = idx >> 5, cl = idx & 31;
      const int c = c0 + cl;
      wt[cl * 132 + ee] = (c < 300) ? W1[(size_t)(e0c + ee) * 300 + c] : 0.0f;
    }
    __syncthreads();
#pragma unroll 4
    for (int cl = 0; cl < 32; ++cl) {
      const float4 xv = *reinterpret_cast<const float4*>(&xt[cl * 68 + n0]);
      const float4 wa = *reinterpret_cast<const float4*>(&wt[cl * 132 + e0]);
      const float4 wb = *reinterpret_cast<const float4*>(&wt[cl * 132 + e0 + 4]);
      const float xv4[4] = {xv.x, xv.y, xv.z, xv.w};
      const float wv8[8] = {wa.x, wa.y, wa.z, wa.w, wb.x, wb.y, wb.z, wb.w};
#pragma unroll
      for (int u = 0; u < 4; ++u)
#pragma unroll
        for (int v = 0; v < 8; ++v) acc[u][v] = fmaf(xv4[u], wv8[v], acc[u][v]);
    }
  }
  float b1v[8];
#pragma unroll
  for (int v = 0; v < 8; ++v) b1v[v] = b1[e0c + e0 + v];
#pragma unroll
  for (int u = 0; u < 4; ++u) {
    float* dst = h1 + ((size_t)i * 64 + n0 + u) * 512 + e0c + e0;
    *reinterpret_cast<float4*>(dst) =
        make_float4(acc[u][0] + b1v[0], acc[u][1] + b1v[1], acc[u][2] + b1v[2], acc[u][3] + b1v[3]);
    *reinterpret_cast<float4*>(dst + 4) =
        make_float4(acc[u][4] + b1v[4], acc[u][5] + b1v[5], acc[u][6] + b1v[6], acc[u][7] + b1v[7]);
  }
}

// ---------------- K5b: BN1+relu, h2, BN2+relu, out ----------------
__global__ void __launch_bounds__(256) k_mlp(
    const float* __restrict__ h1, const float* __restrict__ bn1s, const float* __restrict__ bn1b,
    const float* __restrict__ W2, const float* __restrict__ b2,
    const float* __restrict__ bn2s, const float* __restrict__ bn2b,
    const float* __restrict__ W3, const float* __restrict__ b3, float* __restrict__ out) {
  __shared__ float h1s[64 * 521];
  __shared__ float h2s[64 * 65];
  const int i = blockIdx.x, tid = threadIdx.x;
  for (int m = 0; m < 128; ++m) {
    const int idx = tid + 256 * m;
    h1s[(idx >> 9) * 521 + (idx & 511)] = h1[(size_t)i * 32768 + idx];
  }
  __syncthreads();
  for (int half = 0; half < 2; ++half) {
    const int e = tid + 256 * half;
    float s1 = 0.f, s2 = 0.f;
    for (int nn = 0; nn < 64; ++nn) {
      const float v = h1s[nn * 521 + e];
      s1 += v;
      s2 += v * v;
    }
    const float mu = s1 * (1.0f / 64.0f);
    const float var = s2 * (1.0f / 64.0f) - mu * mu;
    const float scale = bn1s[e] / sqrtf(var + EPSB);
    const float shift = bn1b[e] - mu * scale;
    for (int nn = 0; nn < 64; ++nn) {
      const float v = fmaf(h1s[nn * 521 + e], scale, shift);
      h1s[nn * 521 + e] = fmaxf(v, 0.0f);
    }
  }
  __syncthreads();
  {
    const int dg = tid & 15, ng = tid >> 4;
    const int d0 = dg * 4, n0 = ng * 4;
    float acc[4][4] = {};
#pragma unroll 2
    for (int e = 0; e < 512; ++e) {
      float h4[4], w4[4];
#pragma unroll
      for (int u = 0; u < 4; ++u) h4[u] = h1s[(n0 + u) * 521 + e];
#pragma unroll
      for (int v = 0; v < 4; ++v) w4[v] = W2[(size_t)(d0 + v) * 512 + e];
#pragma unroll
      for (int u = 0; u < 4; ++u)
#pragma unroll
        for (int v = 0; v < 4; ++v) acc[u][v] = fmaf(h4[u], w4[v], acc[u][v]);
    }
#pragma unroll
    for (int u = 0; u < 4; ++u)
#pragma unroll
      for (int v = 0; v < 4; ++v) h2s[(n0 + u) * 65 + d0 + v] = acc[u][v] + b2[d0 + v];
  }
  __syncthreads();
  if (tid < 64) {
    const int d = tid;
    float s1 = 0.f, s2 = 0.f;
    for (int nn = 0; nn < 64; ++nn) {
      const float v = h2s[nn * 65 + d];
      s1 += v;
      s2 += v * v;
    }
    const float mu = s1 * (1.0f / 64.0f);
    const float var = s2 * (1.0f / 64.0f) - mu * mu;
    const float scale = bn2s[d] / sqrtf(var + EPSB);
    const float shift = bn2b[d] - mu * scale;
    for (int nn = 0; nn < 64; ++nn)
      h2s[nn * 65 + d] = fmaxf(fmaf(h2s[nn * 65 + d], scale, shift), 0.0f);
  }
  __syncthreads();
  if (tid < 64) {
    const int nn = tid;
    float acc = b3[0];
    for (int d = 0; d < 64; ++d) acc = fmaf(h2s[nn * 65 + d], W3[d], acc);
    out[i * 64 + nn] = acc;
  }
}

extern "C" void kernel_launch(void* const* d_in, const int* in_sizes, int n_in,
                              void* d_out, int out_size, void* d_ws, size_t ws_size,
                              hipStream_t stream) {
  const float* img  = (const float*)d_in[0];
  const float* cap  = (const float*)d_in[1];
  const float* adW  = (const float*)d_in[2];
  const float* adb  = (const float*)d_in[3];
  const float* qkW  = (const float*)d_in[4];
  const float* qkb  = (const float*)d_in[5];
  const float* qbW  = (const float*)d_in[6];
  const float* qbb  = (const float*)d_in[7];
  const float* qbns = (const float*)d_in[8];
  const float* qbnb = (const float*)d_in[9];
  const float* kkW  = (const float*)d_in[10];
  const float* kkb  = (const float*)d_in[11];
  const float* kbW  = (const float*)d_in[12];
  const float* kbb  = (const float*)d_in[13];
  const float* kbns = (const float*)d_in[14];
  const float* kbnb = (const float*)d_in[15];
  const float* vkW  = (const float*)d_in[16];
  const float* vkb  = (const float*)d_in[17];
  const float* vbW  = (const float*)d_in[18];
  const float* vbb  = (const float*)d_in[19];
  const float* vbns = (const float*)d_in[20];
  const float* vbnb = (const float*)d_in[21];
  const float* gamma= (const float*)d_in[22];
  const float* W1   = (const float*)d_in[23];
  const float* b1   = (const float*)d_in[24];
  const float* bn1s = (const float*)d_in[25];
  const float* bn1b = (const float*)d_in[26];
  const float* W2   = (const float*)d_in[27];
  const float* b2   = (const float*)d_in[28];
  const float* bn2s = (const float*)d_in[29];
  const float* bn2b = (const float*)d_in[30];
  const float* W3   = (const float*)d_in[31];
  const float* b3   = (const float*)d_in[32];

  float* ws    = (float*)d_ws;
  float* base  = ws + OFS_BASE;
  float* ball  = ws + OFS_BALL;
  float* mean  = ws + OFS_MEAN;
  ushort* capP = (ushort*)(ws + OFS_CAPB);
  ushort* kall = (ushort*)(ws + OFS_RAWP);
  float* x_all = ws + OFS_X;
  float* h1    = ws + OFS_H1;    // aliases kall (dead after k_attn8)
  float* out   = (float*)d_out;

  k_mean<<<512, 256, 0, stream>>>(img, mean);
  k_base<<<128, 128, 0, stream>>>(mean, adW, adb, base);
  k_bias<<<dim3(2, 128), 256, 0, stream>>>(qbW, qbb, kbW, kbb, vbW, vbb, base, ball);
  k_capp<<<64, 256, 0, stream>>>(cap, capP);
  k_hyp2<<<dim3(512, 2), 256, 0, stream>>>(qkW, qkb, kkW, kkb, vkW, vkb,
                                           qbns, qbnb, kbns, kbnb, vbns, vbnb, base, kall);
  k_attn8<<<4096, 256, 0, stream>>>(cap, kall, capP, ball, gamma, x_all);
  k_h1<<<dim3(4, 128), 256, 0, stream>>>(x_all, W1, b1, h1);
  k_mlp<<<128, 256, 0, stream>>>(h1, bn1s, bn1b, W2, b2, bn2s, bn2b, W3, b3, out);
}

// Round 9
// 566.901 us; speedup vs baseline: 1.2734x; 1.2734x over previous
//
#include <hip/hip_runtime.h>
#include <math.h>

#define EPSB 1e-5f

// Bi=128 Bc=64 T=32 C=300 OQK=75 H=128 LAT=1024
// Padded stacked o-dim (512): q [0,96) (75 real), k [96,192) (75 real), v [192,512) (300 real)
// Compact packed kall (per image, ushort): q/k tiles ot 0..11: units ot*20+ks*2+pl (hi+lo);
//   v tiles ot 12..31: units 240+(ot-12)*10+ks (hi only). 440 units x 512 ushort = 225280 ushort/img.
// Unit layout: [lane=64][8] ushort; element (o=16*ot+lr, c=32*ks+8*kg+e), lane=kg*16+lr.
// ws layout (float offsets):
static const long OFS_BASE  = 0;                      // 128*128
static const long OFS_BALL  = 16384;                  // 128*512
static const long OFS_MEAN  = 81920;                  // 128*1024
static const long OFS_CAPB  = 212992;                 // capP: 64*20480 ushort = 655360 floats
static const long OFS_RAWP  = 868352;                 // kall: 128*225280 ushort = 14,417,920 floats
static const long OFS_X     = 15286272;               // 128*64*300
static const long OFS_H2    = 17743872;               // 128*64*64
static const long OFS_H1    = OFS_RAWP;               // alias (kall dead after k_attn9)

using bf16x8 = __attribute__((ext_vector_type(8))) __bf16;
using f32x4  = __attribute__((ext_vector_type(4))) float;
#define MFMA16(a, b, c) __builtin_amdgcn_mfma_f32_16x16x32_bf16(a, b, c, 0, 0, 0)

__device__ inline ushort f2bf(float f) {
  const unsigned u = __float_as_uint(f);
  return (ushort)((u + 0x7FFFu + ((u >> 16) & 1u)) >> 16);
}
__device__ inline float bf2f(ushort h) { return __uint_as_float(((unsigned)h) << 16); }

// ---------------- K1a: img_mean over 36 regions ----------------
__global__ void k_mean(const float* __restrict__ img, float* __restrict__ mean) {
  const int idx = blockIdx.x * 256 + threadIdx.x;      // 131072 total
  const int i = idx >> 10, l = idx & 1023;
  const float* p = img + (size_t)i * 36 * 1024 + l;
  float s = 0.f;
#pragma unroll
  for (int r = 0; r < 36; ++r) s += p[r * 1024];
  mean[idx] = s * (1.0f / 36.0f);
}

// ---------------- K1b: base = mean @ adapt_W^T + adapt_b ----------------
__global__ void k_base(const float* __restrict__ mean, const float* __restrict__ W,
                       const float* __restrict__ b, float* __restrict__ base) {
  __shared__ float m_s[1024];
  const int i = blockIdx.x, tid = threadIdx.x;   // 128 threads
  for (int k = 0; k < 8; ++k) m_s[tid + 128 * k] = mean[i * 1024 + tid + 128 * k];
  __syncthreads();
  float acc = b[tid];
  const float* wr = W + (size_t)tid * 1024;
#pragma unroll 4
  for (int l = 0; l < 1024; ++l) acc = fmaf(m_s[l], wr[l], acc);
  base[i * 128 + tid] = acc;
}

// ---------------- K2b: stacked conv biases ball[i][512] ----------------
__global__ void k_bias(const float* __restrict__ qbW, const float* __restrict__ qbb,
                       const float* __restrict__ kbW, const float* __restrict__ kbb,
                       const float* __restrict__ vbW, const float* __restrict__ vbb,
                       const float* __restrict__ base, float* __restrict__ ball) {
  __shared__ float bs[128];
  const int i = blockIdx.y, tid = threadIdx.x;
  if (tid < 128) bs[tid] = base[i * 128 + tid];
  __syncthreads();
  const int o = blockIdx.x * 256 + tid;
  if (o >= 512) return;
  const float* Wr = nullptr;
  float bb = 0.0f;
  if (o < 75)                   { Wr = qbW + (size_t)o * 128;         bb = qbb[o]; }
  else if (o >= 96 && o < 171)  { Wr = kbW + (size_t)(o - 96) * 128;  bb = kbb[o - 96]; }
  else if (o >= 192 && o < 492) { Wr = vbW + (size_t)(o - 192) * 128; bb = vbb[o - 192]; }
  float acc = 0.0f;
  if (Wr) {
#pragma unroll 4
    for (int h = 0; h < 128; ++h) acc = fmaf(Wr[h], bs[h], acc);
    acc += bb;
  }
  ball[i * 512 + o] = acc;
}

// ---------------- K2c: cap -> packed split-bf16 capP [n][nt=2][ks=10][pl=2][64][8] ----------------
__global__ void __launch_bounds__(256) k_capp(const float* __restrict__ cap,
                                              ushort* __restrict__ capP) {
  __shared__ float ct[32 * 301];
  const int n = blockIdx.x, tid = threadIdx.x;
  const float* capn = cap + (size_t)n * 9600;
  {
    const int r = tid >> 3, c8 = tid & 7;
    for (int m = 0; m < 38; ++m) {
      const int c = c8 + 8 * m;
      if (c < 300) ct[r * 301 + c] = capn[r * 300 + c];
    }
  }
  __syncthreads();
  ushort* dst = capP + (size_t)n * 20480;
  for (int u = 0; u < 10; ++u) {
    const int ul = tid + 256 * u;
    const int unit = ul >> 6, lane = ul & 63;
    const int nt = unit / 20, rem = unit % 20;
    const int ks = rem >> 1, pl = rem & 1;
    const int kg = lane >> 4, lr = lane & 15;
    const int t = nt * 16 + lr;
    ushort o8[8];
#pragma unroll
    for (int e = 0; e < 8; ++e) {
      const int c = 32 * ks + 8 * kg + e;
      const float val = (c < 300) ? ct[t * 301 + c] : 0.f;
      const ushort hi = f2bf(val);
      o8[e] = pl ? f2bf(val - bf2f(hi)) : hi;
    }
    uint4 pk;
    pk.x = (uint)o8[0] | ((uint)o8[1] << 16);
    pk.y = (uint)o8[2] | ((uint)o8[3] << 16);
    pk.z = (uint)o8[4] | ((uint)o8[5] << 16);
    pk.w = (uint)o8[6] | ((uint)o8[7] << 16);
    *reinterpret_cast<uint4*>(dst + unit * 512 + lane * 8) = pk;
  }
}

// ---------------- K3: fused hypernet GEMM + row-BN + split-bf16 pack -> compact kall ----------------
// W staged in 32-h chunks via float4 (coalesced 128B per 8-thread group); 8 barriers total.
__global__ void __launch_bounds__(256) k_hyp3(
    const float* __restrict__ qkW, const float* __restrict__ qkb,
    const float* __restrict__ kkW, const float* __restrict__ kkb,
    const float* __restrict__ vkW, const float* __restrict__ vkb,
    const float* __restrict__ qs, const float* __restrict__ qb,
    const float* __restrict__ ks_, const float* __restrict__ kb_,
    const float* __restrict__ vs, const float* __restrict__ vb,
    const float* __restrict__ base, ushort* __restrict__ kall) {
  __shared__ float smem[19504];   // bs[128*68]=8704 | Ws[300*36]=10800 at +8704; out[300*64]=19200 reuse
  __shared__ float scl[64], shf[64];
  const int g = blockIdx.x, half = blockIdx.y, tid = threadIdx.x;
  const int i0g = half * 64;
  const int ot = g >> 4, lr = g & 15;
  const bool isV = (g >= 192);

  const float* Wb = nullptr;
  const float* bvec = nullptr;
  float bns = 0.f, bnb = 0.f;
  if (g < 75)                    { Wb = qkW + (size_t)g * 38400;          bvec = qkb + g * 300;          bns = qs[g];        bnb = qb[g]; }
  else if (g >= 96 && g < 171)   { Wb = kkW + (size_t)(g - 96) * 38400;   bvec = kkb + (g - 96) * 300;   bns = ks_[g - 96];  bnb = kb_[g - 96]; }
  else if (g >= 192 && g < 492)  { Wb = vkW + (size_t)(g - 192) * 38400;  bvec = vkb + (g - 192) * 300;  bns = vs[g - 192];  bnb = vb[g - 192]; }

  if (!Wb) {  // pad rows: exact zeros (P2 relies on them)
    const uint4 z = make_uint4(0, 0, 0, 0);
    if (!isV) {
      for (int m = 0; m < 20; ++m) {
        const int idx = tid + 256 * m;
        const int ii = idx & 63, zz = idx >> 6;
        const int kg2 = zz & 3, pl = (zz >> 2) & 1, ks2 = zz >> 3;
        const size_t off = (size_t)(i0g + ii) * 225280 +
                           (size_t)(ot * 20 + ks2 * 2 + pl) * 512 + (kg2 * 16 + lr) * 8;
        *reinterpret_cast<uint4*>(kall + off) = z;
      }
    } else {
      for (int m = 0; m < 10; ++m) {
        const int idx = tid + 256 * m;
        const int ii = idx & 63, zz = idx >> 6;
        const int kg2 = zz & 3, ks2 = zz >> 2;
        const size_t off = (size_t)(i0g + ii) * 225280 +
                           (size_t)(240 + (ot - 12) * 10 + ks2) * 512 + (kg2 * 16 + lr) * 8;
        *reinterpret_cast<uint4*>(kall + off) = z;
      }
    }
    return;
  }

  // stage base^T: bs[h*68 + i]
  for (int m = 0; m < 32; ++m) {
    const int idx = tid + 256 * m;
    const int ii = idx >> 7, h = idx & 127;
    smem[h * 68 + ii] = base[(size_t)(i0g + ii) * 128 + h];
  }

  const int cg = tid >> 2, ig = tid & 3;
  const int c0 = cg * 5, i0 = ig * 16;
  float acc[5][16];
#pragma unroll
  for (int cc = 0; cc < 5; ++cc)
#pragma unroll
    for (int ii = 0; ii < 16; ++ii) acc[cc][ii] = 0.f;
  float* Ws = smem + 8704;   // [300][36]
  for (int hc = 0; hc < 4; ++hc) {
    __syncthreads();
    for (int m = 0; m < 10; ++m) {
      const int u = tid + 256 * m;      // 2400 float4-units = 300c x 8
      if (u < 2400) {
        const int c = u >> 3, h4 = (u & 7) * 4;
        const float4 wv4 = *reinterpret_cast<const float4*>(Wb + (size_t)c * 128 + hc * 32 + h4);
        *reinterpret_cast<float4*>(&Ws[c * 36 + h4]) = wv4;
      }
    }
    __syncthreads();
#pragma unroll 4
    for (int hh = 0; hh < 32; ++hh) {
      const int hg = hc * 32 + hh;
      float bvf[16];
#pragma unroll
      for (int u2 = 0; u2 < 4; ++u2) {
        const float4 b4 = *reinterpret_cast<const float4*>(&smem[hg * 68 + i0 + u2 * 4]);
        bvf[u2 * 4 + 0] = b4.x; bvf[u2 * 4 + 1] = b4.y;
        bvf[u2 * 4 + 2] = b4.z; bvf[u2 * 4 + 3] = b4.w;
      }
#pragma unroll
      for (int cc = 0; cc < 5; ++cc) {
        const float wv = Ws[(c0 + cc) * 36 + hh];
#pragma unroll
        for (int ii = 0; ii < 16; ++ii) acc[cc][ii] = fmaf(wv, bvf[ii], acc[cc][ii]);
      }
    }
  }
  __syncthreads();
#pragma unroll
  for (int cc = 0; cc < 5; ++cc) {
    const int c = c0 + cc;
    if (c < 300) {
      const float bv = bvec[c];
#pragma unroll
      for (int ii = 0; ii < 16; ++ii) smem[c * 64 + i0 + ii] = acc[cc][ii] + bv;
    }
  }
  __syncthreads();
  {
    const int si = tid >> 2, p = tid & 3;
    float s1 = 0.f, s2 = 0.f;
    for (int c = p; c < 300; c += 4) {
      const float x = smem[c * 64 + si];
      s1 += x;
      s2 += x * x;
    }
    s1 += __shfl_xor(s1, 1); s2 += __shfl_xor(s2, 1);
    s1 += __shfl_xor(s1, 2); s2 += __shfl_xor(s2, 2);
    const float mu = s1 * (1.0f / 300.0f);
    const float var = s2 * (1.0f / 300.0f) - mu * mu;
    const float scale = bns / sqrtf(var + EPSB);
    if (p == 0) { scl[si] = scale; shf[si] = bnb - mu * scale; }
  }
  __syncthreads();
  if (!isV) {  // q/k: hi + lo planes
    for (int m = 0; m < 20; ++m) {
      const int idx = tid + 256 * m;
      const int ii = idx & 63, zz = idx >> 6;
      const int kg2 = zz & 3, pl = (zz >> 2) & 1, ks2 = zz >> 3;
      const float sc = scl[ii], sh = shf[ii];
      ushort o8[8];
#pragma unroll
      for (int e = 0; e < 8; ++e) {
        const int c = ks2 * 32 + kg2 * 8 + e;
        float val = 0.f;
        if (c < 300) val = fmaf(smem[c * 64 + ii], sc, sh);
        const ushort hi = f2bf(val);
        o8[e] = pl ? f2bf(val - bf2f(hi)) : hi;
      }
      uint4 pk;
      pk.x = (uint)o8[0] | ((uint)o8[1] << 16);
      pk.y = (uint)o8[2] | ((uint)o8[3] << 16);
      pk.z = (uint)o8[4] | ((uint)o8[5] << 16);
      pk.w = (uint)o8[6] | ((uint)o8[7] << 16);
      const size_t off = (size_t)(i0g + ii) * 225280 +
                         (size_t)(ot * 20 + ks2 * 2 + pl) * 512 + (kg2 * 16 + lr) * 8;
      *reinterpret_cast<uint4*>(kall + off) = pk;
    }
  } else {     // v: hi plane only
    for (int m = 0; m < 10; ++m) {
      const int idx = tid + 256 * m;
      const int ii = idx & 63, zz = idx >> 6;
      const int kg2 = zz & 3, ks2 = zz >> 2;
      const float sc = scl[ii], sh = shf[ii];
      ushort o8[8];
#pragma unroll
      for (int e = 0; e < 8; ++e) {
        const int c = ks2 * 32 + kg2 * 8 + e;
        float val = 0.f;
        if (c < 300) val = fmaf(smem[c * 64 + ii], sc, sh);
        o8[e] = f2bf(val);
      }
      uint4 pk;
      pk.x = (uint)o8[0] | ((uint)o8[1] << 16);
      pk.y = (uint)o8[2] | ((uint)o8[3] << 16);
      pk.z = (uint)o8[4] | ((uint)o8[5] << 16);
      pk.w = (uint)o8[6] | ((uint)o8[7] << 16);
      const size_t off = (size_t)(i0g + ii) * 225280 +
                         (size_t)(240 + (ot - 12) * 10 + ks2) * 512 + (kg2 * 16 + lr) * 8;
      *reinterpret_cast<uint4*>(kall + off) = pk;
    }
  }
}

// ---------------- K4: fused attention; single caption/block (R7 structure), compact kall ----------------
__global__ void __launch_bounds__(256, 4) k_attn9(
    const float* __restrict__ cap, const ushort* __restrict__ kall,
    const ushort* __restrict__ capP, const float* __restrict__ ball,
    const float* __restrict__ gptr, float* __restrict__ x_all) {
  __shared__ float qk_s[192 * 36];
  __shared__ ushort at_p[2 * 2 * 64 * 8];
  // XCD-aware swizzle: xcd = bid&7 owns images [xcd*16, +16), n-major within
  const int bid = blockIdx.x;
  const int xcd = bid & 7, q = bid >> 3;
  const int i = xcd * 16 + (q >> 6), n = q & 63;
  const int tid = threadIdx.x;
  const int lane = tid & 63, w = tid >> 6;
  const int lrow = lane & 15, kg = lane >> 4;
  const float gamma = gptr[0];
  const ushort* kpL = kall + (size_t)i * 225280 + lane * 8;
  const ushort* cpL = capP + (size_t)n * 20480 + lane * 8;
  const float* bal = ball + i * 512;

  // ---- P1: q+k rows [0,192), wave w owns tiles {3w..3w+2}
  {
    f32x4 acc[3][2];
#pragma unroll
    for (int a = 0; a < 3; ++a)
#pragma unroll
      for (int b2 = 0; b2 < 2; ++b2) acc[a][b2] = (f32x4){0.f, 0.f, 0.f, 0.f};
    for (int ks = 0; ks < 10; ++ks) {
      bf16x8 Ah[3], Al[3], Bh[2], Bl[2];
#pragma unroll
      for (int mt = 0; mt < 3; ++mt) {
        const ushort* p = kpL + (size_t)((w * 3 + mt) * 20 + ks * 2) * 512;
        Ah[mt] = *reinterpret_cast<const bf16x8*>(p);
        Al[mt] = *reinterpret_cast<const bf16x8*>(p + 512);
      }
#pragma unroll
      for (int nt = 0; nt < 2; ++nt) {
        const ushort* p = cpL + (size_t)(nt * 20 + ks * 2) * 512;
        Bh[nt] = *reinterpret_cast<const bf16x8*>(p);
        Bl[nt] = *reinterpret_cast<const bf16x8*>(p + 512);
      }
#pragma unroll
      for (int mt = 0; mt < 3; ++mt)
#pragma unroll
        for (int nt = 0; nt < 2; ++nt) {
          acc[mt][nt] = MFMA16(Ah[mt], Bh[nt], acc[mt][nt]);
          acc[mt][nt] = MFMA16(Ah[mt], Bl[nt], acc[mt][nt]);
          acc[mt][nt] = MFMA16(Al[mt], Bh[nt], acc[mt][nt]);
        }
    }
#pragma unroll
    for (int mt = 0; mt < 3; ++mt)
#pragma unroll
      for (int nt = 0; nt < 2; ++nt)
#pragma unroll
        for (int r = 0; r < 4; ++r) {
          const int o = w * 48 + mt * 16 + kg * 4 + r;
          qk_s[o * 36 + nt * 16 + lrow] = acc[mt][nt][r] + bal[o];
        }
  }
  __syncthreads();

  // ---- P2: scores + softmax (fp32); write packed bf16 hi/lo attn in MFMA-B layout
  {
    const int sg = tid & 7, tq = tid >> 3;
    const int s0 = sg * 4;
    float scA[4] = {0.f, 0.f, 0.f, 0.f}, scB[4] = {0.f, 0.f, 0.f, 0.f};
#pragma unroll 8
    for (int o = 0; o < 80; o += 2) {
      const float qa = qk_s[o * 36 + tq];
      const float4 ka = *reinterpret_cast<const float4*>(&qk_s[(96 + o) * 36 + s0]);
      const float qb = qk_s[(o + 1) * 36 + tq];
      const float4 kb = *reinterpret_cast<const float4*>(&qk_s[(97 + o) * 36 + s0]);
      scA[0] = fmaf(qa, ka.x, scA[0]); scB[0] = fmaf(qb, kb.x, scB[0]);
      scA[1] = fmaf(qa, ka.y, scA[1]); scB[1] = fmaf(qb, kb.y, scB[1]);
      scA[2] = fmaf(qa, ka.z, scA[2]); scB[2] = fmaf(qb, kb.z, scB[2]);
      scA[3] = fmaf(qa, ka.w, scA[3]); scB[3] = fmaf(qb, kb.w, scB[3]);
    }
    float sc[4];
#pragma unroll
    for (int u = 0; u < 4; ++u) sc[u] = scA[u] + scB[u];
    float m = fmaxf(fmaxf(sc[0], sc[1]), fmaxf(sc[2], sc[3]));
    m = fmaxf(m, __shfl_xor(m, 1));
    m = fmaxf(m, __shfl_xor(m, 2));
    m = fmaxf(m, __shfl_xor(m, 4));
    float ev[4], ssum = 0.f;
#pragma unroll
    for (int u = 0; u < 4; ++u) { ev[u] = expf(sc[u] - m); ssum += ev[u]; }
    ssum += __shfl_xor(ssum, 1);
    ssum += __shfl_xor(ssum, 2);
    ssum += __shfl_xor(ssum, 4);
    const float inv = 1.0f / ssum;
    const int tt = tq >> 4, lrp = tq & 15, kgp = sg >> 1, eb = (sg & 1) * 4;
    ushort h4[4], l4[4];
#pragma unroll
    for (int u = 0; u < 4; ++u) {
      const float val = ev[u] * inv;
      const ushort hi = f2bf(val);
      h4[u] = hi;
      l4[u] = f2bf(val - bf2f(hi));
    }
    uint2 ph, pl2;
    ph.x = (uint)h4[0] | ((uint)h4[1] << 16);
    ph.y = (uint)h4[2] | ((uint)h4[3] << 16);
    pl2.x = (uint)l4[0] | ((uint)l4[1] << 16);
    pl2.y = (uint)l4[2] | ((uint)l4[3] << 16);
    *reinterpret_cast<uint2*>(&at_p[((tt * 2 + 0) * 64 + kgp * 16 + lrp) * 8 + eb]) = ph;
    *reinterpret_cast<uint2*>(&at_p[((tt * 2 + 1) * 64 + kgp * 16 + lrp) * 8 + eb]) = pl2;
  }
  __syncthreads();

  // ---- P3: v tiles [12,32) in 2 chunks; 1-pass bf16 proj + MFMA PV (3-pass)
  ushort* vt = reinterpret_cast<ushort*>(qk_s);
#pragma unroll
  for (int ch = 0; ch < 2; ++ch) {
    const int TB = 12 + ch * 12;
    const int RB = TB * 16;
    const int nmt = ch ? 2 : 3;
    f32x4 vacc[3][2];
#pragma unroll
    for (int a = 0; a < 3; ++a)
#pragma unroll
      for (int b2 = 0; b2 < 2; ++b2) vacc[a][b2] = (f32x4){0.f, 0.f, 0.f, 0.f};
    for (int ks = 0; ks < 10; ++ks) {
      bf16x8 Av[3], Bh[2];
      for (int mi = 0; mi < nmt; ++mi)
        Av[mi] = *reinterpret_cast<const bf16x8*>(
            kpL + (size_t)(240 + (TB - 12 + w + mi * 4) * 10 + ks) * 512);
#pragma unroll
      for (int nt = 0; nt < 2; ++nt)
        Bh[nt] = *reinterpret_cast<const bf16x8*>(cpL + (size_t)(nt * 20 + ks * 2) * 512);
      for (int mi = 0; mi < nmt; ++mi)
#pragma unroll
        for (int nt = 0; nt < 2; ++nt)
          vacc[mi][nt] = MFMA16(Av[mi], Bh[nt], vacc[mi][nt]);
    }
    if (ch) __syncthreads();   // prior P3b readers of vt done
    for (int mi = 0; mi < nmt; ++mi) {
      const int tile = w + mi * 4;
#pragma unroll
      for (int nt = 0; nt < 2; ++nt) {
        const int kgp = nt * 2 + (lrow >> 3), ee = lrow & 7;
#pragma unroll
        for (int r = 0; r < 4; ++r) {
          const int vl = tile * 16 + kg * 4 + r;
          const float val = vacc[mi][nt][r] + bal[RB + vl];
          const ushort hi = f2bf(val);
          vt[((tile * 2 + 0) * 64 + kgp * 16 + kg * 4 + r) * 8 + ee] = hi;
          vt[((tile * 2 + 1) * 64 + kgp * 16 + kg * 4 + r) * 8 + ee] = f2bf(val - bf2f(hi));
        }
      }
    }
    __syncthreads();
    {  // P3b: MFMA PV + residual + max
      bf16x8 ah[2], al[2];
#pragma unroll
      for (int tt = 0; tt < 2; ++tt) {
        ah[tt] = *reinterpret_cast<const bf16x8*>(&at_p[((tt * 2 + 0) * 64 + lane) * 8]);
        al[tt] = *reinterpret_cast<const bf16x8*>(&at_p[((tt * 2 + 1) * 64 + lane) * 8]);
      }
      const int npw = ch ? 2 : 3;
      for (int j = 0; j < npw; ++j) {
        const int ct = w * npw + j;
        const int c0 = ch * 192 + ct * 16 + (lane >> 4) * 4;
        const bf16x8 vh  = *reinterpret_cast<const bf16x8*>(&vt[((ct * 2 + 0) * 64 + lane) * 8]);
        const bf16x8 vl8 = *reinterpret_cast<const bf16x8*>(&vt[((ct * 2 + 1) * 64 + lane) * 8]);
        f32x4 a0 = (f32x4){0.f, 0.f, 0.f, 0.f}, a1 = (f32x4){0.f, 0.f, 0.f, 0.f};
        a0 = MFMA16(vh, ah[0], a0);
        a0 = MFMA16(vh, al[0], a0);
        a0 = MFMA16(vl8, ah[0], a0);
        a1 = MFMA16(vh, ah[1], a1);
        a1 = MFMA16(vh, al[1], a1);
        a1 = MFMA16(vl8, ah[1], a1);
        if (c0 < 300) {
          const int t0 = lane & 15;
          const float4 c4a = *reinterpret_cast<const float4*>(&cap[(size_t)n * 9600 + t0 * 300 + c0]);
          const float4 c4b = *reinterpret_cast<const float4*>(&cap[(size_t)n * 9600 + (t0 + 16) * 300 + c0]);
          float mx[4];
          mx[0] = fmaxf(fmaf(gamma, a0[0], c4a.x), fmaf(gamma, a1[0], c4b.x));
          mx[1] = fmaxf(fmaf(gamma, a0[1], c4a.y), fmaf(gamma, a1[1], c4b.y));
          mx[2] = fmaxf(fmaf(gamma, a0[2], c4a.z), fmaf(gamma, a1[2], c4b.z));
          mx[3] = fmaxf(fmaf(gamma, a0[3], c4a.w), fmaf(gamma, a1[3], c4b.w));
#pragma unroll
          for (int mmask = 1; mmask < 16; mmask <<= 1)
#pragma unroll
            for (int r = 0; r < 4; ++r) mx[r] = fmaxf(mx[r], __shfl_xor(mx[r], mmask));
          if ((lane & 15) == 0)
            *reinterpret_cast<float4*>(&x_all[((size_t)i * 64 + n) * 300 + c0]) =
                make_float4(mx[0], mx[1], mx[2], mx[3]);
        }
      }
    }
  }
}

// ---------------- K5a: h1 = relu(BN1(x @ W1^T + b1)) — BN1 fused (block owns all 64 n) ----------------
__global__ void __launch_bounds__(256, 4) k_h1b(
    const float* __restrict__ x_all, const float* __restrict__ W1,
    const float* __restrict__ b1, const float* __restrict__ bn1s,
    const float* __restrict__ bn1b, float* __restrict__ h1) {
  __shared__ float xt[32 * 68];
  __shared__ float wt[32 * 132];
  __shared__ float sc1[128], sh1[128];
  const int ec = blockIdx.x, i = blockIdx.y, tid = threadIdx.x;
  const int e0c = ec * 128;
  const int eg = tid & 15, ng = tid >> 4;
  const int e0 = eg * 8, n0 = ng * 4;
  float acc[4][8] = {};
  for (int cb = 0; cb < 10; ++cb) {
    const int c0 = cb * 32;
    __syncthreads();
    for (int k = 0; k < 8; ++k) {
      const int idx = tid + 256 * k;
      const int nn = idx >> 5, cl = idx & 31;
      const int c = c0 + cl;
      xt[cl * 68 + nn] = (c < 300) ? x_all[((size_t)i * 64 + nn) * 300 + c] : 0.0f;
    }
    for (int k = 0; k < 16; ++k) {
      const int idx = tid + 256 * k;
      const int ee = idx >> 5, cl = idx & 31;
      const int c = c0 + cl;
      wt[cl * 132 + ee] = (c < 300) ? W1[(size_t)(e0c + ee) * 300 + c] : 0.0f;
    }
    __syncthreads();
#pragma unroll 4
    for (int cl = 0; cl < 32; ++cl) {
      const float4 xv = *reinterpret_cast<const float4*>(&xt[cl * 68 + n0]);
      const float4 wa = *reinterpret_cast<const float4*>(&wt[cl * 132 + e0]);
      const float4 wb = *reinterpret_cast<const float4*>(&wt[cl * 132 + e0 + 4]);
      const float xv4[4] = {xv.x, xv.y, xv.z, xv.w};
      const float wv8[8] = {wa.x, wa.y, wa.z, wa.w, wb.x, wb.y, wb.z, wb.w};
#pragma unroll
      for (int u = 0; u < 4; ++u)
#pragma unroll
        for (int v = 0; v < 8; ++v) acc[u][v] = fmaf(xv4[u], wv8[v], acc[u][v]);
    }
  }
  float b1v[8];
#pragma unroll
  for (int v = 0; v < 8; ++v) b1v[v] = b1[e0c + e0 + v];
  float val[4][8];
#pragma unroll
  for (int u = 0; u < 4; ++u)
#pragma unroll
    for (int v = 0; v < 8; ++v) val[u][v] = acc[u][v] + b1v[v];
  // BN1 stats over n (64) per e: partial per ng group -> LDS tree (reuse xt/wt)
  __syncthreads();
  float* ps1 = xt;   // [16][132]
  float* ps2 = wt;   // [16][132]
#pragma unroll
  for (int v = 0; v < 8; ++v) {
    float su = 0.f, sq = 0.f;
#pragma unroll
    for (int u = 0; u < 4; ++u) { su += val[u][v]; sq += val[u][v] * val[u][v]; }
    ps1[ng * 132 + e0 + v] = su;
    ps2[ng * 132 + e0 + v] = sq;
  }
  __syncthreads();
  if (tid < 128) {
    const int e = tid;
    float s1 = 0.f, s2 = 0.f;
#pragma unroll 4
    for (int gq = 0; gq < 16; ++gq) { s1 += ps1[gq * 132 + e]; s2 += ps2[gq * 132 + e]; }
    const float mu = s1 * (1.0f / 64.0f);
    const float var = s2 * (1.0f / 64.0f) - mu * mu;
    const float scale = bn1s[e0c + e] / sqrtf(var + EPSB);
    sc1[e] = scale;
    sh1[e] = bn1b[e0c + e] - mu * scale;
  }
  __syncthreads();
#pragma unroll
  for (int u = 0; u < 4; ++u) {
    float o8[8];
#pragma unroll
    for (int v = 0; v < 8; ++v)
      o8[v] = fmaxf(fmaf(val[u][v], sc1[e0 + v], sh1[e0 + v]), 0.0f);
    float* dst = h1 + ((size_t)i * 64 + n0 + u) * 512 + e0c + e0;
    *reinterpret_cast<float4*>(dst) = make_float4(o8[0], o8[1], o8[2], o8[3]);
    *reinterpret_cast<float4*>(dst + 4) = make_float4(o8[4], o8[5], o8[6], o8[7]);
  }
}

// ---------------- K5b: h2 = h1 @ W2^T + b2 (grid 2x128 for full occupancy) ----------------
__global__ void __launch_bounds__(256) k_h2(
    const float* __restrict__ h1, const float* __restrict__ W2,
    const float* __restrict__ b2, float* __restrict__ h2buf) {
  __shared__ float h1s[32 * 517];
  const int jn = blockIdx.x, i = blockIdx.y, tid = threadIdx.x;
  const int bn = jn * 32;
  for (int m = 0; m < 64; ++m) {
    const int idx = tid + 256 * m;   // 16384
    h1s[(idx >> 9) * 517 + (idx & 511)] = h1[((size_t)i * 64 + bn) * 512 + idx];
  }
  __syncthreads();
  const int dg = tid & 15, ng2 = tid >> 4;
  const int d0 = dg * 4, n0 = ng2 * 2;
  float a0[4] = {}, a1[4] = {};
#pragma unroll 4
  for (int e = 0; e < 512; ++e) {
    const float h0 = h1s[n0 * 517 + e];
    const float h1v = h1s[(n0 + 1) * 517 + e];
#pragma unroll
    for (int v = 0; v < 4; ++v) {
      const float wv = W2[(size_t)(d0 + v) * 512 + e];
      a0[v] = fmaf(h0, wv, a0[v]);
      a1[v] = fmaf(h1v, wv, a1[v]);
    }
  }
  const float4 bb = *reinterpret_cast<const float4*>(&b2[d0]);
  float* dst0 = h2buf + ((size_t)i * 64 + bn + n0) * 64 + d0;
  *reinterpret_cast<float4*>(dst0) = make_float4(a0[0] + bb.x, a0[1] + bb.y, a0[2] + bb.z, a0[3] + bb.w);
  *reinterpret_cast<float4*>(dst0 + 64) = make_float4(a1[0] + bb.x, a1[1] + bb.y, a1[2] + bb.z, a1[3] + bb.w);
}

// ---------------- K5c: BN2 + relu + W3 dot -> out ----------------
__global__ void __launch_bounds__(256) k_out(
    const float* __restrict__ h2buf, const float* __restrict__ bn2s,
    const float* __restrict__ bn2b, const float* __restrict__ W3,
    const float* __restrict__ b3, float* __restrict__ out) {
  __shared__ float h2s[64 * 65];
  const int i = blockIdx.x, tid = threadIdx.x;
  for (int m = 0; m < 16; ++m) {
    const int idx = tid + 256 * m;   // 4096
    h2s[(idx >> 6) * 65 + (idx & 63)] = h2buf[(size_t)i * 4096 + idx];
  }
  __syncthreads();
  if (tid < 64) {
    const int d = tid;
    float s1 = 0.f, s2 = 0.f;
    for (int nn = 0; nn < 64; ++nn) {
      const float v = h2s[nn * 65 + d];
      s1 += v;
      s2 += v * v;
    }
    const float mu = s1 * (1.0f / 64.0f);
    const float var = s2 * (1.0f / 64.0f) - mu * mu;
    const float scale = bn2s[d] / sqrtf(var + EPSB);
    const float shift = bn2b[d] - mu * scale;
    for (int nn = 0; nn < 64; ++nn)
      h2s[nn * 65 + d] = fmaxf(fmaf(h2s[nn * 65 + d], scale, shift), 0.0f);
  }
  __syncthreads();
  if (tid < 64) {
    const int nn = tid;
    float acc = b3[0];
    for (int d = 0; d < 64; ++d) acc = fmaf(h2s[nn * 65 + d], W3[d], acc);
    out[i * 64 + nn] = acc;
  }
}

extern "C" void kernel_launch(void* const* d_in, const int* in_sizes, int n_in,
                              void* d_out, int out_size, void* d_ws, size_t ws_size,
                              hipStream_t stream) {
  const float* img  = (const float*)d_in[0];
  const float* cap  = (const float*)d_in[1];
  const float* adW  = (const float*)d_in[2];
  const float* adb  = (const float*)d_in[3];
  const float* qkW  = (const float*)d_in[4];
  const float* qkb  = (const float*)d_in[5];
  const float* qbW  = (const float*)d_in[6];
  const float* qbb  = (const float*)d_in[7];
  const float* qbns = (const float*)d_in[8];
  const float* qbnb = (const float*)d_in[9];
  const float* kkW  = (const float*)d_in[10];
  const float* kkb  = (const float*)d_in[11];
  const float* kbW  = (const float*)d_in[12];
  const float* kbb  = (const float*)d_in[13];
  const float* kbns = (const float*)d_in[14];
  const float* kbnb = (const float*)d_in[15];
  const float* vkW  = (const float*)d_in[16];
  const float* vkb  = (const float*)d_in[17];
  const float* vbW  = (const float*)d_in[18];
  const float* vbb  = (const float*)d_in[19];
  const float* vbns = (const float*)d_in[20];
  const float* vbnb = (const float*)d_in[21];
  const float* gamma= (const float*)d_in[22];
  const float* W1   = (const float*)d_in[23];
  const float* b1   = (const float*)d_in[24];
  const float* bn1s = (const float*)d_in[25];
  const float* bn1b = (const float*)d_in[26];
  const float* W2   = (const float*)d_in[27];
  const float* b2   = (const float*)d_in[28];
  const float* bn2s = (const float*)d_in[29];
  const float* bn2b = (const float*)d_in[30];
  const float* W3   = (const float*)d_in[31];
  const float* b3   = (const float*)d_in[32];

  float* ws    = (float*)d_ws;
  float* base  = ws + OFS_BASE;
  float* ball  = ws + OFS_BALL;
  float* mean  = ws + OFS_MEAN;
  ushort* capP = (ushort*)(ws + OFS_CAPB);
  ushort* kall = (ushort*)(ws + OFS_RAWP);
  float* x_all = ws + OFS_X;
  float* h2buf = ws + OFS_H2;
  float* h1    = ws + OFS_H1;    // aliases kall (dead after k_attn9)
  float* out   = (float*)d_out;

  k_mean<<<512, 256, 0, stream>>>(img, mean);
  k_base<<<128, 128, 0, stream>>>(mean, adW, adb, base);
  k_bias<<<dim3(2, 128), 256, 0, stream>>>(qbW, qbb, kbW, kbb, vbW, vbb, base, ball);
  k_capp<<<64, 256, 0, stream>>>(cap, capP);
  k_hyp3<<<dim3(512, 2), 256, 0, stream>>>(qkW, qkb, kkW, kkb, vkW, vkb,
                                           qbns, qbnb, kbns, kbnb, vbns, vbnb, base, kall);
  k_attn9<<<8192, 256, 0, stream>>>(cap, kall, capP, ball, gamma, x_all);
  k_h1b<<<dim3(4, 128), 256, 0, stream>>>(x_all, W1, b1, bn1s, bn1b, h1);
  k_h2<<<dim3(2, 128), 256, 0, stream>>>(h1, W2, b2, h2buf);
  k_out<<<128, 256, 0, stream>>>(h2buf, bn2s, bn2b, W3, b3, out);
}

// Round 10
// 550.361 us; speedup vs baseline: 1.3117x; 1.0301x over previous
//
#include <hip/hip_runtime.h>
#include <math.h>

#define EPSB 1e-5f

// Bi=128 Bc=64 T=32 C=300 OQK=75 H=128 LAT=1024
// Padded stacked o-dim (512): q [0,96) (75 real), k [96,192) (75 real), v [192,512) (300 real)
// Compact packed kall (per image, ushort): q/k tiles ot 0..11: units ot*20+ks*2+pl (hi+lo);
//   v tiles ot 12..31: units 240+(ot-12)*10+ks (hi only). 440 units x 512 ushort = 225280 ushort/img.
// Unit layout: [lane=64][8] ushort; element (o=16*ot+lr, c=32*ks+8*kg+e), lane=kg*16+lr.
// ws layout (float offsets):
static const long OFS_BASE  = 0;                      // 128*128
static const long OFS_BALL  = 16384;                  // 128*512
static const long OFS_MEAN  = 81920;                  // 128*1024
static const long OFS_CAPB  = 212992;                 // capP: 64*20480 ushort = 655360 floats
static const long OFS_RAWP  = 868352;                 // kall: 128*225280 ushort = 14,417,920 floats
static const long OFS_X     = 15286272;               // 128*64*300
static const long OFS_H2    = 17743872;               // 128*64*64
static const long OFS_H1    = OFS_RAWP;               // alias (kall dead after k_attn10)

using bf16x8 = __attribute__((ext_vector_type(8))) __bf16;
using f32x4  = __attribute__((ext_vector_type(4))) float;
#define MFMA16(a, b, c) __builtin_amdgcn_mfma_f32_16x16x32_bf16(a, b, c, 0, 0, 0)

__device__ inline ushort f2bf(float f) {
  const unsigned u = __float_as_uint(f);
  return (ushort)((u + 0x7FFFu + ((u >> 16) & 1u)) >> 16);
}
__device__ inline float bf2f(ushort h) { return __uint_as_float(((unsigned)h) << 16); }

// ---------------- K1a: img_mean over 36 regions ----------------
__global__ void k_mean(const float* __restrict__ img, float* __restrict__ mean) {
  const int idx = blockIdx.x * 256 + threadIdx.x;      // 131072 total
  const int i = idx >> 10, l = idx & 1023;
  const float* p = img + (size_t)i * 36 * 1024 + l;
  float s = 0.f;
#pragma unroll
  for (int r = 0; r < 36; ++r) s += p[r * 1024];
  mean[idx] = s * (1.0f / 36.0f);
}

// ---------------- K1b: base = mean @ adapt_W^T + adapt_b ----------------
__global__ void k_base(const float* __restrict__ mean, const float* __restrict__ W,
                       const float* __restrict__ b, float* __restrict__ base) {
  __shared__ float m_s[1024];
  const int i = blockIdx.x, tid = threadIdx.x;   // 128 threads
  for (int k = 0; k < 8; ++k) m_s[tid + 128 * k] = mean[i * 1024 + tid + 128 * k];
  __syncthreads();
  float acc = b[tid];
  const float* wr = W + (size_t)tid * 1024;
#pragma unroll 4
  for (int l = 0; l < 1024; ++l) acc = fmaf(m_s[l], wr[l], acc);
  base[i * 128 + tid] = acc;
}

// ---------------- K2b: stacked conv biases ball[i][512] ----------------
__global__ void k_bias(const float* __restrict__ qbW, const float* __restrict__ qbb,
                       const float* __restrict__ kbW, const float* __restrict__ kbb,
                       const float* __restrict__ vbW, const float* __restrict__ vbb,
                       const float* __restrict__ base, float* __restrict__ ball) {
  __shared__ float bs[128];
  const int i = blockIdx.y, tid = threadIdx.x;
  if (tid < 128) bs[tid] = base[i * 128 + tid];
  __syncthreads();
  const int o = blockIdx.x * 256 + tid;
  if (o >= 512) return;
  const float* Wr = nullptr;
  float bb = 0.0f;
  if (o < 75)                   { Wr = qbW + (size_t)o * 128;         bb = qbb[o]; }
  else if (o >= 96 && o < 171)  { Wr = kbW + (size_t)(o - 96) * 128;  bb = kbb[o - 96]; }
  else if (o >= 192 && o < 492) { Wr = vbW + (size_t)(o - 192) * 128; bb = vbb[o - 192]; }
  float acc = 0.0f;
  if (Wr) {
#pragma unroll 4
    for (int h = 0; h < 128; ++h) acc = fmaf(Wr[h], bs[h], acc);
    acc += bb;
  }
  ball[i * 512 + o] = acc;
}

// ---------------- K2c: cap -> packed split-bf16 capP [n][nt=2][ks=10][pl=2][64][8] ----------------
__global__ void __launch_bounds__(256) k_capp(const float* __restrict__ cap,
                                              ushort* __restrict__ capP) {
  __shared__ float ct[32 * 301];
  const int n = blockIdx.x, tid = threadIdx.x;
  const float* capn = cap + (size_t)n * 9600;
  {
    const int r = tid >> 3, c8 = tid & 7;
    for (int m = 0; m < 38; ++m) {
      const int c = c8 + 8 * m;
      if (c < 300) ct[r * 301 + c] = capn[r * 300 + c];
    }
  }
  __syncthreads();
  ushort* dst = capP + (size_t)n * 20480;
  for (int u = 0; u < 10; ++u) {
    const int ul = tid + 256 * u;
    const int unit = ul >> 6, lane = ul & 63;
    const int nt = unit / 20, rem = unit % 20;
    const int ks = rem >> 1, pl = rem & 1;
    const int kg = lane >> 4, lr = lane & 15;
    const int t = nt * 16 + lr;
    ushort o8[8];
#pragma unroll
    for (int e = 0; e < 8; ++e) {
      const int c = 32 * ks + 8 * kg + e;
      const float val = (c < 300) ? ct[t * 301 + c] : 0.f;
      const ushort hi = f2bf(val);
      o8[e] = pl ? f2bf(val - bf2f(hi)) : hi;
    }
    uint4 pk;
    pk.x = (uint)o8[0] | ((uint)o8[1] << 16);
    pk.y = (uint)o8[2] | ((uint)o8[3] << 16);
    pk.z = (uint)o8[4] | ((uint)o8[5] << 16);
    pk.w = (uint)o8[6] | ((uint)o8[7] << 16);
    *reinterpret_cast<uint4*>(dst + unit * 512 + lane * 8) = pk;
  }
}

// ---------------- K3: fused hypernet GEMM + row-BN + split-bf16 pack -> compact kall ----------------
__global__ void __launch_bounds__(256) k_hyp3(
    const float* __restrict__ qkW, const float* __restrict__ qkb,
    const float* __restrict__ kkW, const float* __restrict__ kkb,
    const float* __restrict__ vkW, const float* __restrict__ vkb,
    const float* __restrict__ qs, const float* __restrict__ qb,
    const float* __restrict__ ks_, const float* __restrict__ kb_,
    const float* __restrict__ vs, const float* __restrict__ vb,
    const float* __restrict__ base, ushort* __restrict__ kall) {
  __shared__ float smem[19504];   // bs[128*68]=8704 | Ws[300*36]=10800 at +8704; out[300*64]=19200 reuse
  __shared__ float scl[64], shf[64];
  const int g = blockIdx.x, half = blockIdx.y, tid = threadIdx.x;
  const int i0g = half * 64;
  const int ot = g >> 4, lr = g & 15;
  const bool isV = (g >= 192);

  const float* Wb = nullptr;
  const float* bvec = nullptr;
  float bns = 0.f, bnb = 0.f;
  if (g < 75)                    { Wb = qkW + (size_t)g * 38400;          bvec = qkb + g * 300;          bns = qs[g];        bnb = qb[g]; }
  else if (g >= 96 && g < 171)   { Wb = kkW + (size_t)(g - 96) * 38400;   bvec = kkb + (g - 96) * 300;   bns = ks_[g - 96];  bnb = kb_[g - 96]; }
  else if (g >= 192 && g < 492)  { Wb = vkW + (size_t)(g - 192) * 38400;  bvec = vkb + (g - 192) * 300;  bns = vs[g - 192];  bnb = vb[g - 192]; }

  if (!Wb) {  // pad rows: exact zeros (P2 relies on them)
    const uint4 z = make_uint4(0, 0, 0, 0);
    if (!isV) {
      for (int m = 0; m < 20; ++m) {
        const int idx = tid + 256 * m;
        const int ii = idx & 63, zz = idx >> 6;
        const int kg2 = zz & 3, pl = (zz >> 2) & 1, ks2 = zz >> 3;
        const size_t off = (size_t)(i0g + ii) * 225280 +
                           (size_t)(ot * 20 + ks2 * 2 + pl) * 512 + (kg2 * 16 + lr) * 8;
        *reinterpret_cast<uint4*>(kall + off) = z;
      }
    } else {
      for (int m = 0; m < 10; ++m) {
        const int idx = tid + 256 * m;
        const int ii = idx & 63, zz = idx >> 6;
        const int kg2 = zz & 3, ks2 = zz >> 2;
        const size_t off = (size_t)(i0g + ii) * 225280 +
                           (size_t)(240 + (ot - 12) * 10 + ks2) * 512 + (kg2 * 16 + lr) * 8;
        *reinterpret_cast<uint4*>(kall + off) = z;
      }
    }
    return;
  }

  // stage base^T: bs[h*68 + i]
  for (int m = 0; m < 32; ++m) {
    const int idx = tid + 256 * m;
    const int ii = idx >> 7, h = idx & 127;
    smem[h * 68 + ii] = base[(size_t)(i0g + ii) * 128 + h];
  }

  const int cg = tid >> 2, ig = tid & 3;
  const int c0 = cg * 5, i0 = ig * 16;
  float acc[5][16];
#pragma unroll
  for (int cc = 0; cc < 5; ++cc)
#pragma unroll
    for (int ii = 0; ii < 16; ++ii) acc[cc][ii] = 0.f;
  float* Ws = smem + 8704;   // [300][36]
  for (int hc = 0; hc < 4; ++hc) {
    __syncthreads();
    for (int m = 0; m < 10; ++m) {
      const int u = tid + 256 * m;      // 2400 float4-units = 300c x 8
      if (u < 2400) {
        const int c = u >> 3, h4 = (u & 7) * 4;
        const float4 wv4 = *reinterpret_cast<const float4*>(Wb + (size_t)c * 128 + hc * 32 + h4);
        *reinterpret_cast<float4*>(&Ws[c * 36 + h4]) = wv4;
      }
    }
    __syncthreads();
#pragma unroll 4
    for (int hh = 0; hh < 32; ++hh) {
      const int hg = hc * 32 + hh;
      float bvf[16];
#pragma unroll
      for (int u2 = 0; u2 < 4; ++u2) {
        const float4 b4 = *reinterpret_cast<const float4*>(&smem[hg * 68 + i0 + u2 * 4]);
        bvf[u2 * 4 + 0] = b4.x; bvf[u2 * 4 + 1] = b4.y;
        bvf[u2 * 4 + 2] = b4.z; bvf[u2 * 4 + 3] = b4.w;
      }
#pragma unroll
      for (int cc = 0; cc < 5; ++cc) {
        const float wv = Ws[(c0 + cc) * 36 + hh];
#pragma unroll
        for (int ii = 0; ii < 16; ++ii) acc[cc][ii] = fmaf(wv, bvf[ii], acc[cc][ii]);
      }
    }
  }
  __syncthreads();
#pragma unroll
  for (int cc = 0; cc < 5; ++cc) {
    const int c = c0 + cc;
    if (c < 300) {
      const float bv = bvec[c];
#pragma unroll
      for (int ii = 0; ii < 16; ++ii) smem[c * 64 + i0 + ii] = acc[cc][ii] + bv;
    }
  }
  __syncthreads();
  {
    const int si = tid >> 2, p = tid & 3;
    float s1 = 0.f, s2 = 0.f;
    for (int c = p; c < 300; c += 4) {
      const float x = smem[c * 64 + si];
      s1 += x;
      s2 += x * x;
    }
    s1 += __shfl_xor(s1, 1); s2 += __shfl_xor(s2, 1);
    s1 += __shfl_xor(s1, 2); s2 += __shfl_xor(s2, 2);
    const float mu = s1 * (1.0f / 300.0f);
    const float var = s2 * (1.0f / 300.0f) - mu * mu;
    const float scale = bns / sqrtf(var + EPSB);
    if (p == 0) { scl[si] = scale; shf[si] = bnb - mu * scale; }
  }
  __syncthreads();
  if (!isV) {  // q/k: hi + lo planes
    for (int m = 0; m < 20; ++m) {
      const int idx = tid + 256 * m;
      const int ii = idx & 63, zz = idx >> 6;
      const int kg2 = zz & 3, pl = (zz >> 2) & 1, ks2 = zz >> 3;
      const float sc = scl[ii], sh = shf[ii];
      ushort o8[8];
#pragma unroll
      for (int e = 0; e < 8; ++e) {
        const int c = ks2 * 32 + kg2 * 8 + e;
        float val = 0.f;
        if (c < 300) val = fmaf(smem[c * 64 + ii], sc, sh);
        const ushort hi = f2bf(val);
        o8[e] = pl ? f2bf(val - bf2f(hi)) : hi;
      }
      uint4 pk;
      pk.x = (uint)o8[0] | ((uint)o8[1] << 16);
      pk.y = (uint)o8[2] | ((uint)o8[3] << 16);
      pk.z = (uint)o8[4] | ((uint)o8[5] << 16);
      pk.w = (uint)o8[6] | ((uint)o8[7] << 16);
      const size_t off = (size_t)(i0g + ii) * 225280 +
                         (size_t)(ot * 20 + ks2 * 2 + pl) * 512 + (kg2 * 16 + lr) * 8;
      *reinterpret_cast<uint4*>(kall + off) = pk;
    }
  } else {     // v: hi plane only
    for (int m = 0; m < 10; ++m) {
      const int idx = tid + 256 * m;
      const int ii = idx & 63, zz = idx >> 6;
      const int kg2 = zz & 3, ks2 = zz >> 2;
      const float sc = scl[ii], sh = shf[ii];
      ushort o8[8];
#pragma unroll
      for (int e = 0; e < 8; ++e) {
        const int c = ks2 * 32 + kg2 * 8 + e;
        float val = 0.f;
        if (c < 300) val = fmaf(smem[c * 64 + ii], sc, sh);
        o8[e] = f2bf(val);
      }
      uint4 pk;
      pk.x = (uint)o8[0] | ((uint)o8[1] << 16);
      pk.y = (uint)o8[2] | ((uint)o8[3] << 16);
      pk.z = (uint)o8[4] | ((uint)o8[5] << 16);
      pk.w = (uint)o8[6] | ((uint)o8[7] << 16);
      const size_t off = (size_t)(i0g + ii) * 225280 +
                         (size_t)(240 + (ot - 12) * 10 + ks2) * 512 + (kg2 * 16 + lr) * 8;
      *reinterpret_cast<uint4*>(kall + off) = pk;
    }
  }
}

// ---------------- K4: fused attention; MFMA scores + 2-deep A-prefetch ----------------
// q/k proj: 3-pass split-bf16. scores: MFMA 4-pass split (q/k re-split to bf16 hi/lo in LDS).
// v proj: 1-pass bf16. PV: 3-pass split MFMA.
__global__ void __launch_bounds__(256, 4) k_attn10(
    const float* __restrict__ cap, const ushort* __restrict__ kall,
    const ushort* __restrict__ capP, const float* __restrict__ ball,
    const float* __restrict__ gptr, float* __restrict__ x_all) {
  __shared__ ushort qkp[24 * 512];       // P1/P2: packed q (units 0-11) + k (12-23); P3: vt
  __shared__ float sc_s[32 * 36];        // fp32 scores [t][s]
  __shared__ ushort at_p[2 * 2 * 64 * 8];
  // XCD-aware swizzle: xcd = bid&7 owns images [xcd*16, +16), n-major within
  const int bid = blockIdx.x;
  const int xcd = bid & 7, q = bid >> 3;
  const int i = xcd * 16 + (q >> 6), n = q & 63;
  const int tid = threadIdx.x;
  const int lane = tid & 63, w = tid >> 6;
  const int lrow = lane & 15, kg = lane >> 4;
  const float gamma = gptr[0];
  const ushort* kpL = kall + (size_t)i * 225280 + lane * 8;
  const ushort* cpL = capP + (size_t)n * 20480 + lane * 8;
  const float* bal = ball + i * 512;

  // ---- P1: q+k rows [0,192), wave w owns tiles {3w..3w+2}; 2-deep A-prefetch
  {
    f32x4 acc[3][2];
#pragma unroll
    for (int a = 0; a < 3; ++a)
#pragma unroll
      for (int b2 = 0; b2 < 2; ++b2) acc[a][b2] = (f32x4){0.f, 0.f, 0.f, 0.f};
    bf16x8 AhA[3], AlA[3], AhB[3], AlB[3];
#pragma unroll
    for (int mt = 0; mt < 3; ++mt) {   // preload kstep 0
      const ushort* p = kpL + (size_t)((w * 3 + mt) * 20) * 512;
      AhA[mt] = *reinterpret_cast<const bf16x8*>(p);
      AlA[mt] = *reinterpret_cast<const bf16x8*>(p + 512);
    }
#pragma unroll
    for (int kp = 0; kp < 5; ++kp) {
      {  // even kstep 2kp: consume set A; prefetch 2kp+1 into B
        const int ks = 2 * kp;
        bf16x8 Bh[2], Bl[2];
#pragma unroll
        for (int nt = 0; nt < 2; ++nt) {
          const ushort* p = cpL + (size_t)(nt * 20 + ks * 2) * 512;
          Bh[nt] = *reinterpret_cast<const bf16x8*>(p);
          Bl[nt] = *reinterpret_cast<const bf16x8*>(p + 512);
        }
#pragma unroll
        for (int mt = 0; mt < 3; ++mt) {
          const ushort* p = kpL + (size_t)((w * 3 + mt) * 20 + (ks + 1) * 2) * 512;
          AhB[mt] = *reinterpret_cast<const bf16x8*>(p);
          AlB[mt] = *reinterpret_cast<const bf16x8*>(p + 512);
        }
#pragma unroll
        for (int mt = 0; mt < 3; ++mt)
#pragma unroll
          for (int nt = 0; nt < 2; ++nt) {
            acc[mt][nt] = MFMA16(AhA[mt], Bh[nt], acc[mt][nt]);
            acc[mt][nt] = MFMA16(AhA[mt], Bl[nt], acc[mt][nt]);
            acc[mt][nt] = MFMA16(AlA[mt], Bh[nt], acc[mt][nt]);
          }
      }
      {  // odd kstep 2kp+1: consume set B; prefetch 2kp+2 into A
        const int ks = 2 * kp + 1;
        bf16x8 Bh[2], Bl[2];
#pragma unroll
        for (int nt = 0; nt < 2; ++nt) {
          const ushort* p = cpL + (size_t)(nt * 20 + ks * 2) * 512;
          Bh[nt] = *reinterpret_cast<const bf16x8*>(p);
          Bl[nt] = *reinterpret_cast<const bf16x8*>(p + 512);
        }
        if (kp < 4) {
#pragma unroll
          for (int mt = 0; mt < 3; ++mt) {
            const ushort* p = kpL + (size_t)((w * 3 + mt) * 20 + (ks + 1) * 2) * 512;
            AhA[mt] = *reinterpret_cast<const bf16x8*>(p);
            AlA[mt] = *reinterpret_cast<const bf16x8*>(p + 512);
          }
        }
#pragma unroll
        for (int mt = 0; mt < 3; ++mt)
#pragma unroll
          for (int nt = 0; nt < 2; ++nt) {
            acc[mt][nt] = MFMA16(AhB[mt], Bh[nt], acc[mt][nt]);
            acc[mt][nt] = MFMA16(AhB[mt], Bl[nt], acc[mt][nt]);
            acc[mt][nt] = MFMA16(AlB[mt], Bh[nt], acc[mt][nt]);
          }
      }
    }
    // epilogue: write q/k as packed split-bf16 MFMA fragments
    // q (rows 0-95) -> A-frags [tt][ks3][pl] units 0-11: element (t,o): lane'=((o&31)>>3)*16+(t&15), e=o&7
    // k (rows 96-191) -> B-frags units 12-23: element (o,s): lane'=((o&31)>>3)*16+(s&15), e=o&7
#pragma unroll
    for (int mt = 0; mt < 3; ++mt)
#pragma unroll
      for (int nt = 0; nt < 2; ++nt)
#pragma unroll
        for (int r = 0; r < 4; ++r) {
          const int og = w * 48 + mt * 16 + kg * 4 + r;
          const float val = acc[mt][nt][r] + bal[og];
          const ushort hi = f2bf(val);
          const ushort lo = f2bf(val - bf2f(hi));
          const int os = (w < 2) ? og : og - 96;
          const int ub = ((w < 2) ? 0 : 12) + nt * 6 + (os >> 5) * 2;
          const int lp = ((os & 31) >> 3) * 16 + lrow;
          const int e = os & 7;
          qkp[(ub + 0) * 512 + lp * 8 + e] = hi;
          qkp[(ub + 1) * 512 + lp * 8 + e] = lo;
        }
  }
  __syncthreads();

  // ---- P2a: scores via MFMA (4-pass split, K=96 over 3 ksteps); wave w -> quadrant (tt,st)
  {
    const int tt = w >> 1, st = w & 1;
    bf16x8 Aq[3][2], Bk[3][2];
#pragma unroll
    for (int k3 = 0; k3 < 3; ++k3)
#pragma unroll
      for (int pl = 0; pl < 2; ++pl) {
        Aq[k3][pl] = *reinterpret_cast<const bf16x8*>(&qkp[(tt * 6 + k3 * 2 + pl) * 512 + lane * 8]);
        Bk[k3][pl] = *reinterpret_cast<const bf16x8*>(&qkp[(12 + st * 6 + k3 * 2 + pl) * 512 + lane * 8]);
      }
    f32x4 D = (f32x4){0.f, 0.f, 0.f, 0.f};
#pragma unroll
    for (int k3 = 0; k3 < 3; ++k3) {
      D = MFMA16(Aq[k3][0], Bk[k3][0], D);
      D = MFMA16(Aq[k3][0], Bk[k3][1], D);
      D = MFMA16(Aq[k3][1], Bk[k3][0], D);
      D = MFMA16(Aq[k3][1], Bk[k3][1], D);
    }
#pragma unroll
    for (int r = 0; r < 4; ++r)
      sc_s[(tt * 16 + kg * 4 + r) * 36 + st * 16 + lrow] = D[r];
  }
  __syncthreads();

  // ---- P2b: softmax (fp32) + pack attn to at_p (bf16 hi/lo, MFMA-B layout)
  {
    const int sg = tid & 7, tq = tid >> 3;
    const int s0 = sg * 4;
    const float4 sv = *reinterpret_cast<const float4*>(&sc_s[tq * 36 + s0]);
    float sc[4] = {sv.x, sv.y, sv.z, sv.w};
    float m = fmaxf(fmaxf(sc[0], sc[1]), fmaxf(sc[2], sc[3]));
    m = fmaxf(m, __shfl_xor(m, 1));
    m = fmaxf(m, __shfl_xor(m, 2));
    m = fmaxf(m, __shfl_xor(m, 4));
    float ev[4], ssum = 0.f;
#pragma unroll
    for (int u = 0; u < 4; ++u) { ev[u] = expf(sc[u] - m); ssum += ev[u]; }
    ssum += __shfl_xor(ssum, 1);
    ssum += __shfl_xor(ssum, 2);
    ssum += __shfl_xor(ssum, 4);
    const float inv = 1.0f / ssum;
    const int tt = tq >> 4, lrp = tq & 15, kgp = sg >> 1, eb = (sg & 1) * 4;
    ushort h4[4], l4[4];
#pragma unroll
    for (int u = 0; u < 4; ++u) {
      const float val = ev[u] * inv;
      const ushort hi = f2bf(val);
      h4[u] = hi;
      l4[u] = f2bf(val - bf2f(hi));
    }
    uint2 ph, pl2;
    ph.x = (uint)h4[0] | ((uint)h4[1] << 16);
    ph.y = (uint)h4[2] | ((uint)h4[3] << 16);
    pl2.x = (uint)l4[0] | ((uint)l4[1] << 16);
    pl2.y = (uint)l4[2] | ((uint)l4[3] << 16);
    *reinterpret_cast<uint2*>(&at_p[((tt * 2 + 0) * 64 + kgp * 16 + lrp) * 8 + eb]) = ph;
    *reinterpret_cast<uint2*>(&at_p[((tt * 2 + 1) * 64 + kgp * 16 + lrp) * 8 + eb]) = pl2;
  }
  __syncthreads();

  // ---- P3: v tiles [12,32) in 2 chunks; 1-pass bf16 proj (2-deep A-prefetch) + MFMA PV
  ushort* vt = qkp;
#pragma unroll
  for (int ch = 0; ch < 2; ++ch) {
    const int TB = 12 + ch * 12;
    const int RB = TB * 16;
    const int nmt = ch ? 2 : 3;
    f32x4 vacc[3][2];
#pragma unroll
    for (int a = 0; a < 3; ++a)
#pragma unroll
      for (int b2 = 0; b2 < 2; ++b2) vacc[a][b2] = (f32x4){0.f, 0.f, 0.f, 0.f};
    bf16x8 AvA[3], AvB[3];
    for (int mi = 0; mi < nmt; ++mi)   // preload kstep 0
      AvA[mi] = *reinterpret_cast<const bf16x8*>(
          kpL + (size_t)(240 + (TB - 12 + w + mi * 4) * 10) * 512);
#pragma unroll
    for (int kp = 0; kp < 5; ++kp) {
      {  // even ks=2kp
        const int ks = 2 * kp;
        bf16x8 Bh[2];
#pragma unroll
        for (int nt = 0; nt < 2; ++nt)
          Bh[nt] = *reinterpret_cast<const bf16x8*>(cpL + (size_t)(nt * 20 + ks * 2) * 512);
        for (int mi = 0; mi < nmt; ++mi)
          AvB[mi] = *reinterpret_cast<const bf16x8*>(
              kpL + (size_t)(240 + (TB - 12 + w + mi * 4) * 10 + ks + 1) * 512);
        for (int mi = 0; mi < nmt; ++mi)
#pragma unroll
          for (int nt = 0; nt < 2; ++nt)
            vacc[mi][nt] = MFMA16(AvA[mi], Bh[nt], vacc[mi][nt]);
      }
      {  // odd ks=2kp+1
        const int ks = 2 * kp + 1;
        bf16x8 Bh[2];
#pragma unroll
        for (int nt = 0; nt < 2; ++nt)
          Bh[nt] = *reinterpret_cast<const bf16x8*>(cpL + (size_t)(nt * 20 + ks * 2) * 512);
        if (kp < 4) {
          for (int mi = 0; mi < nmt; ++mi)
            AvA[mi] = *reinterpret_cast<const bf16x8*>(
                kpL + (size_t)(240 + (TB - 12 + w + mi * 4) * 10 + ks + 1) * 512);
        }
        for (int mi = 0; mi < nmt; ++mi)
#pragma unroll
          for (int nt = 0; nt < 2; ++nt)
            vacc[mi][nt] = MFMA16(AvB[mi], Bh[nt], vacc[mi][nt]);
      }
    }
    if (ch) __syncthreads();   // prior P3b readers of vt done
    for (int mi = 0; mi < nmt; ++mi) {
      const int tile = w + mi * 4;
#pragma unroll
      for (int nt = 0; nt < 2; ++nt) {
        const int kgp = nt * 2 + (lrow >> 3), ee = lrow & 7;
#pragma unroll
        for (int r = 0; r < 4; ++r) {
          const int vl = tile * 16 + kg * 4 + r;
          const float val = vacc[mi][nt][r] + bal[RB + vl];
          const ushort hi = f2bf(val);
          vt[((tile * 2 + 0) * 64 + kgp * 16 + kg * 4 + r) * 8 + ee] = hi;
          vt[((tile * 2 + 1) * 64 + kgp * 16 + kg * 4 + r) * 8 + ee] = f2bf(val - bf2f(hi));
        }
      }
    }
    __syncthreads();
    {  // P3b: MFMA PV + residual + max
      bf16x8 ah[2], al[2];
#pragma unroll
      for (int tt = 0; tt < 2; ++tt) {
        ah[tt] = *reinterpret_cast<const bf16x8*>(&at_p[((tt * 2 + 0) * 64 + lane) * 8]);
        al[tt] = *reinterpret_cast<const bf16x8*>(&at_p[((tt * 2 + 1) * 64 + lane) * 8]);
      }
      const int npw = ch ? 2 : 3;
      for (int j = 0; j < npw; ++j) {
        const int ct = w * npw + j;
        const int c0 = ch * 192 + ct * 16 + (lane >> 4) * 4;
        const bf16x8 vh  = *reinterpret_cast<const bf16x8*>(&vt[((ct * 2 + 0) * 64 + lane) * 8]);
        const bf16x8 vl8 = *reinterpret_cast<const bf16x8*>(&vt[((ct * 2 + 1) * 64 + lane) * 8]);
        f32x4 a0 = (f32x4){0.f, 0.f, 0.f, 0.f}, a1 = (f32x4){0.f, 0.f, 0.f, 0.f};
        a0 = MFMA16(vh, ah[0], a0);
        a0 = MFMA16(vh, al[0], a0);
        a0 = MFMA16(vl8, ah[0], a0);
        a1 = MFMA16(vh, ah[1], a1);
        a1 = MFMA16(vh, al[1], a1);
        a1 = MFMA16(vl8, ah[1], a1);
        if (c0 < 300) {
          const int t0 = lane & 15;
          const float4 c4a = *reinterpret_cast<const float4*>(&cap[(size_t)n * 9600 + t0 * 300 + c0]);
          const float4 c4b = *reinterpret_cast<const float4*>(&cap[(size_t)n * 9600 + (t0 + 16) * 300 + c0]);
          float mx[4];
          mx[0] = fmaxf(fmaf(gamma, a0[0], c4a.x), fmaf(gamma, a1[0], c4b.x));
          mx[1] = fmaxf(fmaf(gamma, a0[1], c4a.y), fmaf(gamma, a1[1], c4b.y));
          mx[2] = fmaxf(fmaf(gamma, a0[2], c4a.z), fmaf(gamma, a1[2], c4b.z));
          mx[3] = fmaxf(fmaf(gamma, a0[3], c4a.w), fmaf(gamma, a1[3], c4b.w));
#pragma unroll
          for (int mmask = 1; mmask < 16; mmask <<= 1)
#pragma unroll
            for (int r = 0; r < 4; ++r) mx[r] = fmaxf(mx[r], __shfl_xor(mx[r], mmask));
          if ((lane & 15) == 0)
            *reinterpret_cast<float4*>(&x_all[((size_t)i * 64 + n) * 300 + c0]) =
                make_float4(mx[0], mx[1], mx[2], mx[3]);
        }
      }
    }
  }
}

// ---------------- K5a: h1 = relu(BN1(x @ W1^T + b1)) — BN1 fused ----------------
__global__ void __launch_bounds__(256, 4) k_h1b(
    const float* __restrict__ x_all, const float* __restrict__ W1,
    const float* __restrict__ b1, const float* __restrict__ bn1s,
    const float* __restrict__ bn1b, float* __restrict__ h1) {
  __shared__ float xt[32 * 68];
  __shared__ float wt[32 * 132];
  __shared__ float sc1[128], sh1[128];
  const int ec = blockIdx.x, i = blockIdx.y, tid = threadIdx.x;
  const int e0c = ec * 128;
  const int eg = tid & 15, ng = tid >> 4;
  const int e0 = eg * 8, n0 = ng * 4;
  float acc[4][8] = {};
  for (int cb = 0; cb < 10; ++cb) {
    const int c0 = cb * 32;
    __syncthreads();
    for (int k = 0; k < 8; ++k) {
      const int idx = tid + 256 * k;
      const int nn = idx >> 5, cl = idx & 31;
      const int c = c0 + cl;
      xt[cl * 68 + nn] = (c < 300) ? x_all[((size_t)i * 64 + nn) * 300 + c] : 0.0f;
    }
    for (int k = 0; k < 16; ++k) {
      const int idx = tid + 256 * k;
      const int ee = idx >> 5, cl = idx & 31;
      const int c = c0 + cl;
      wt[cl * 132 + ee] = (c < 300) ? W1[(size_t)(e0c + ee) * 300 + c] : 0.0f;
    }
    __syncthreads();
#pragma unroll 4
    for (int cl = 0; cl < 32; ++cl) {
      const float4 xv = *reinterpret_cast<const float4*>(&xt[cl * 68 + n0]);
      const float4 wa = *reinterpret_cast<const float4*>(&wt[cl * 132 + e0]);
      const float4 wb = *reinterpret_cast<const float4*>(&wt[cl * 132 + e0 + 4]);
      const float xv4[4] = {xv.x, xv.y, xv.z, xv.w};
      const float wv8[8] = {wa.x, wa.y, wa.z, wa.w, wb.x, wb.y, wb.z, wb.w};
#pragma unroll
      for (int u = 0; u < 4; ++u)
#pragma unroll
        for (int v = 0; v < 8; ++v) acc[u][v] = fmaf(xv4[u], wv8[v], acc[u][v]);
    }
  }
  float b1v[8];
#pragma unroll
  for (int v = 0; v < 8; ++v) b1v[v] = b1[e0c + e0 + v];
  float val[4][8];
#pragma unroll
  for (int u = 0; u < 4; ++u)
#pragma unroll
    for (int v = 0; v < 8; ++v) val[u][v] = acc[u][v] + b1v[v];
  __syncthreads();
  float* ps1 = xt;   // [16][132]
  float* ps2 = wt;   // [16][132]
#pragma unroll
  for (int v = 0; v < 8; ++v) {
    float su = 0.f, sq = 0.f;
#pragma unroll
    for (int u = 0; u < 4; ++u) { su += val[u][v]; sq += val[u][v] * val[u][v]; }
    ps1[ng * 132 + e0 + v] = su;
    ps2[ng * 132 + e0 + v] = sq;
  }
  __syncthreads();
  if (tid < 128) {
    const int e = tid;
    float s1 = 0.f, s2 = 0.f;
#pragma unroll 4
    for (int gq = 0; gq < 16; ++gq) { s1 += ps1[gq * 132 + e]; s2 += ps2[gq * 132 + e]; }
    const float mu = s1 * (1.0f / 64.0f);
    const float var = s2 * (1.0f / 64.0f) - mu * mu;
    const float scale = bn1s[e0c + e] / sqrtf(var + EPSB);
    sc1[e] = scale;
    sh1[e] = bn1b[e0c + e] - mu * scale;
  }
  __syncthreads();
#pragma unroll
  for (int u = 0; u < 4; ++u) {
    float o8[8];
#pragma unroll
    for (int v = 0; v < 8; ++v)
      o8[v] = fmaxf(fmaf(val[u][v], sc1[e0 + v], sh1[e0 + v]), 0.0f);
    float* dst = h1 + ((size_t)i * 64 + n0 + u) * 512 + e0c + e0;
    *reinterpret_cast<float4*>(dst) = make_float4(o8[0], o8[1], o8[2], o8[3]);
    *reinterpret_cast<float4*>(dst + 4) = make_float4(o8[4], o8[5], o8[6], o8[7]);
  }
}

// ---------------- K5b: h2 = h1 @ W2^T + b2 ----------------
__global__ void __launch_bounds__(256) k_h2(
    const float* __restrict__ h1, const float* __restrict__ W2,
    const float* __restrict__ b2, float* __restrict__ h2buf) {
  __shared__ float h1s[32 * 517];
  const int jn = blockIdx.x, i = blockIdx.y, tid = threadIdx.x;
  const int bn = jn * 32;
  for (int m = 0; m < 64; ++m) {
    const int idx = tid + 256 * m;   // 16384
    h1s[(idx >> 9) * 517 + (idx & 511)] = h1[((size_t)i * 64 + bn) * 512 + idx];
  }
  __syncthreads();
  const int dg = tid & 15, ng2 = tid >> 4;
  const int d0 = dg * 4, n0 = ng2 * 2;
  float a0[4] = {}, a1[4] = {};
#pragma unroll 4
  for (int e = 0; e < 512; ++e) {
    const float h0 = h1s[n0 * 517 + e];
    const float h1v = h1s[(n0 + 1) * 517 + e];
#pragma unroll
    for (int v = 0; v < 4; ++v) {
      const float wv = W2[(size_t)(d0 + v) * 512 + e];
      a0[v] = fmaf(h0, wv, a0[v]);
      a1[v] = fmaf(h1v, wv, a1[v]);
    }
  }
  const float4 bb = *reinterpret_cast<const float4*>(&b2[d0]);
  float* dst0 = h2buf + ((size_t)i * 64 + bn + n0) * 64 + d0;
  *reinterpret_cast<float4*>(dst0) = make_float4(a0[0] + bb.x, a0[1] + bb.y, a0[2] + bb.z, a0[3] + bb.w);
  *reinterpret_cast<float4*>(dst0 + 64) = make_float4(a1[0] + bb.x, a1[1] + bb.y, a1[2] + bb.z, a1[3] + bb.w);
}

// ---------------- K5c: BN2 + relu + W3 dot -> out ----------------
__global__ void __launch_bounds__(256) k_out(
    const float* __restrict__ h2buf, const float* __restrict__ bn2s,
    const float* __restrict__ bn2b, const float* __restrict__ W3,
    const float* __restrict__ b3, float* __restrict__ out) {
  __shared__ float h2s[64 * 65];
  const int i = blockIdx.x, tid = threadIdx.x;
  for (int m = 0; m < 16; ++m) {
    const int idx = tid + 256 * m;   // 4096
    h2s[(idx >> 6) * 65 + (idx & 63)] = h2buf[(size_t)i * 4096 + idx];
  }
  __syncthreads();
  if (tid < 64) {
    const int d = tid;
    float s1 = 0.f, s2 = 0.f;
    for (int nn = 0; nn < 64; ++nn) {
      const float v = h2s[nn * 65 + d];
      s1 += v;
      s2 += v * v;
    }
    const float mu = s1 * (1.0f / 64.0f);
    const float var = s2 * (1.0f / 64.0f) - mu * mu;
    const float scale = bn2s[d] / sqrtf(var + EPSB);
    const float shift = bn2b[d] - mu * scale;
    for (int nn = 0; nn < 64; ++nn)
      h2s[nn * 65 + d] = fmaxf(fmaf(h2s[nn * 65 + d], scale, shift), 0.0f);
  }
  __syncthreads();
  if (tid < 64) {
    const int nn = tid;
    float acc = b3[0];
    for (int d = 0; d < 64; ++d) acc = fmaf(h2s[nn * 65 + d], W3[d], acc);
    out[i * 64 + nn] = acc;
  }
}

extern "C" void kernel_launch(void* const* d_in, const int* in_sizes, int n_in,
                              void* d_out, int out_size, void* d_ws, size_t ws_size,
                              hipStream_t stream) {
  const float* img  = (const float*)d_in[0];
  const float* cap  = (const float*)d_in[1];
  const float* adW  = (const float*)d_in[2];
  const float* adb  = (const float*)d_in[3];
  const float* qkW  = (const float*)d_in[4];
  const float* qkb  = (const float*)d_in[5];
  const float* qbW  = (const float*)d_in[6];
  const float* qbb  = (const float*)d_in[7];
  const float* qbns = (const float*)d_in[8];
  const float* qbnb = (const float*)d_in[9];
  const float* kkW  = (const float*)d_in[10];
  const float* kkb  = (const float*)d_in[11];
  const float* kbW  = (const float*)d_in[12];
  const float* kbb  = (const float*)d_in[13];
  const float* kbns = (const float*)d_in[14];
  const float* kbnb = (const float*)d_in[15];
  const float* vkW  = (const float*)d_in[16];
  const float* vkb  = (const float*)d_in[17];
  const float* vbW  = (const float*)d_in[18];
  const float* vbb  = (const float*)d_in[19];
  const float* vbns = (const float*)d_in[20];
  const float* vbnb = (const float*)d_in[21];
  const float* gamma= (const float*)d_in[22];
  const float* W1   = (const float*)d_in[23];
  const float* b1   = (const float*)d_in[24];
  const float* bn1s = (const float*)d_in[25];
  const float* bn1b = (const float*)d_in[26];
  const float* W2   = (const float*)d_in[27];
  const float* b2   = (const float*)d_in[28];
  const float* bn2s = (const float*)d_in[29];
  const float* bn2b = (const float*)d_in[30];
  const float* W3   = (const float*)d_in[31];
  const float* b3   = (const float*)d_in[32];

  float* ws    = (float*)d_ws;
  float* base  = ws + OFS_BASE;
  float* ball  = ws + OFS_BALL;
  float* mean  = ws + OFS_MEAN;
  ushort* capP = (ushort*)(ws + OFS_CAPB);
  ushort* kall = (ushort*)(ws + OFS_RAWP);
  float* x_all = ws + OFS_X;
  float* h2buf = ws + OFS_H2;
  float* h1    = ws + OFS_H1;    // aliases kall (dead after k_attn10)
  float* out   = (float*)d_out;

  k_mean<<<512, 256, 0, stream>>>(img, mean);
  k_base<<<128, 128, 0, stream>>>(mean, adW, adb, base);
  k_bias<<<dim3(2, 128), 256, 0, stream>>>(qbW, qbb, kbW, kbb, vbW, vbb, base, ball);
  k_capp<<<64, 256, 0, stream>>>(cap, capP);
  k_hyp3<<<dim3(512, 2), 256, 0, stream>>>(qkW, qkb, kkW, kkb, vkW, vkb,
                                           qbns, qbnb, kbns, kbnb, vbns, vbnb, base, kall);
  k_attn10<<<8192, 256, 0, stream>>>(cap, kall, capP, ball, gamma, x_all);
  k_h1b<<<dim3(4, 128), 256, 0, stream>>>(x_all, W1, b1, bn1s, bn1b, h1);
  k_h2<<<dim3(2, 128), 256, 0, stream>>>(h1, W2, b2, h2buf);
  k_out<<<128, 256, 0, stream>>>(h2buf, bn2s, bn2b, W3, b3, out);
}

// Round 11
// 516.415 us; speedup vs baseline: 1.3979x; 1.0657x over previous
//
#include <hip/hip_runtime.h>
#include <math.h>

#define EPSB 1e-5f

// Bi=128 Bc=64 T=32 C=300 OQK=75 H=128 LAT=1024
// Padded stacked o-dim (512): q [0,96) (75 real), k [96,192) (75 real), v [192,512) (300 real)
// Compact packed kall (per image, ushort): q/k tiles ot 0..11: units ot*20+ks*2+pl (hi+lo);
//   v tiles ot 12..31: units 240+(ot-12)*10+ks (hi only). 440 units x 512 ushort = 225280 ushort/img.
// Unit layout: [lane=64][8] ushort; element (o=16*ot+lr, c=32*ks+8*kg+e), lane=kg*16+lr.
// NOTE: o-tiles 5 and 11 are ALL-PAD; k_attn skips them (bit-exact) and k_hyp4 never writes them.
// ws layout (float offsets):
static const long OFS_BASE  = 0;                      // 128*128
static const long OFS_BALL  = 16384;                  // 128*512
static const long OFS_MEAN  = 81920;                  // 128*1024
static const long OFS_CAPB  = 212992;                 // capP: 64*20480 ushort = 655360 floats
static const long OFS_RAWP  = 868352;                 // kall: 128*225280 ushort = 14,417,920 floats
static const long OFS_X     = 15286272;               // 128*64*300
static const long OFS_H2    = 17743872;               // 128*64*64
static const long OFS_BASP  = 18268160;               // basP: 2*32*512 ushort = 16384 floats
static const long OFS_H1    = OFS_RAWP;               // alias (kall dead after k_attn11)

using bf16x8 = __attribute__((ext_vector_type(8))) __bf16;
using f32x4  = __attribute__((ext_vector_type(4))) float;
#define MFMA16(a, b, c) __builtin_amdgcn_mfma_f32_16x16x32_bf16(a, b, c, 0, 0, 0)

__device__ inline ushort f2bf(float f) {
  const unsigned u = __float_as_uint(f);
  return (ushort)((u + 0x7FFFu + ((u >> 16) & 1u)) >> 16);
}
__device__ inline float bf2f(ushort h) { return __uint_as_float(((unsigned)h) << 16); }

// ---------------- K1a: img_mean over 36 regions ----------------
__global__ void k_mean(const float* __restrict__ img, float* __restrict__ mean) {
  const int idx = blockIdx.x * 256 + threadIdx.x;      // 131072 total
  const int i = idx >> 10, l = idx & 1023;
  const float* p = img + (size_t)i * 36 * 1024 + l;
  float s = 0.f;
#pragma unroll
  for (int r = 0; r < 36; ++r) s += p[r * 1024];
  mean[idx] = s * (1.0f / 36.0f);
}

// ---------------- K1b: base = mean @ adapt_W^T + adapt_b ----------------
__global__ void k_base(const float* __restrict__ mean, const float* __restrict__ W,
                       const float* __restrict__ b, float* __restrict__ base) {
  __shared__ float m_s[1024];
  const int i = blockIdx.x, tid = threadIdx.x;   // 128 threads
  for (int k = 0; k < 8; ++k) m_s[tid + 128 * k] = mean[i * 1024 + tid + 128 * k];
  __syncthreads();
  float acc = b[tid];
  const float* wr = W + (size_t)tid * 1024;
#pragma unroll 4
  for (int l = 0; l < 1024; ++l) acc = fmaf(m_s[l], wr[l], acc);
  base[i * 128 + tid] = acc;
}

// ---------------- K1c: base -> packed split-bf16 B-frags basP[half][it4][ks4][pl2][64][8] ----------------
__global__ void __launch_bounds__(256) k_basp(const float* __restrict__ base,
                                              ushort* __restrict__ basP) {
  const int half = blockIdx.x, tid = threadIdx.x;
  for (int m = 0; m < 8; ++m) {
    const int u = tid + 256 * m;            // 2048 lane-units
    const int ln = u & 63, unit = u >> 6;   // 32 units
    const int it = unit >> 3, ks = (unit >> 1) & 3, pl = unit & 1;
    const int i = half * 64 + it * 16 + (ln & 15);
    const int h = ks * 32 + (ln >> 4) * 8;
    ushort o8[8];
#pragma unroll
    for (int e = 0; e < 8; ++e) {
      const float v = base[(size_t)i * 128 + h + e];
      const ushort hi = f2bf(v);
      o8[e] = pl ? f2bf(v - bf2f(hi)) : hi;
    }
    uint4 pk;
    pk.x = (uint)o8[0] | ((uint)o8[1] << 16);
    pk.y = (uint)o8[2] | ((uint)o8[3] << 16);
    pk.z = (uint)o8[4] | ((uint)o8[5] << 16);
    pk.w = (uint)o8[6] | ((uint)o8[7] << 16);
    *reinterpret_cast<uint4*>(basP + (size_t)(half * 32 + unit) * 512 + ln * 8) = pk;
  }
}

// ---------------- K2b: stacked conv biases ball[i][512] ----------------
__global__ void k_bias(const float* __restrict__ qbW, const float* __restrict__ qbb,
                       const float* __restrict__ kbW, const float* __restrict__ kbb,
                       const float* __restrict__ vbW, const float* __restrict__ vbb,
                       const float* __restrict__ base, float* __restrict__ ball) {
  __shared__ float bs[128];
  const int i = blockIdx.y, tid = threadIdx.x;
  if (tid < 128) bs[tid] = base[i * 128 + tid];
  __syncthreads();
  const int o = blockIdx.x * 256 + tid;
  if (o >= 512) return;
  const float* Wr = nullptr;
  float bb = 0.0f;
  if (o < 75)                   { Wr = qbW + (size_t)o * 128;         bb = qbb[o]; }
  else if (o >= 96 && o < 171)  { Wr = kbW + (size_t)(o - 96) * 128;  bb = kbb[o - 96]; }
  else if (o >= 192 && o < 492) { Wr = vbW + (size_t)(o - 192) * 128; bb = vbb[o - 192]; }
  float acc = 0.0f;
  if (Wr) {
#pragma unroll 4
    for (int h = 0; h < 128; ++h) acc = fmaf(Wr[h], bs[h], acc);
    acc += bb;
  }
  ball[i * 512 + o] = acc;
}

// ---------------- K2c: cap -> packed split-bf16 capP [n][nt=2][ks=10][pl=2][64][8] ----------------
__global__ void __launch_bounds__(256) k_capp(const float* __restrict__ cap,
                                              ushort* __restrict__ capP) {
  __shared__ float ct[32 * 301];
  const int n = blockIdx.x, tid = threadIdx.x;
  const float* capn = cap + (size_t)n * 9600;
  {
    const int r = tid >> 3, c8 = tid & 7;
    for (int m = 0; m < 38; ++m) {
      const int c = c8 + 8 * m;
      if (c < 300) ct[r * 301 + c] = capn[r * 300 + c];
    }
  }
  __syncthreads();
  ushort* dst = capP + (size_t)n * 20480;
  for (int u = 0; u < 10; ++u) {
    const int ul = tid + 256 * u;
    const int unit = ul >> 6, lane = ul & 63;
    const int nt = unit / 20, rem = unit % 20;
    const int ks = rem >> 1, pl = rem & 1;
    const int kg = lane >> 4, lr = lane & 15;
    const int t = nt * 16 + lr;
    ushort o8[8];
#pragma unroll
    for (int e = 0; e < 8; ++e) {
      const int c = 32 * ks + 8 * kg + e;
      const float val = (c < 300) ? ct[t * 301 + c] : 0.f;
      const ushort hi = f2bf(val);
      o8[e] = pl ? f2bf(val - bf2f(hi)) : hi;
    }
    uint4 pk;
    pk.x = (uint)o8[0] | ((uint)o8[1] << 16);
    pk.y = (uint)o8[2] | ((uint)o8[3] << 16);
    pk.z = (uint)o8[4] | ((uint)o8[5] << 16);
    pk.w = (uint)o8[6] | ((uint)o8[7] << 16);
    *reinterpret_cast<uint4*>(dst + unit * 512 + lane * 8) = pk;
  }
}

// ---------------- K3: MFMA hypernet GEMM + row-BN + split-bf16 pack -> compact kall ----------------
// Per (g,half): D[c][i] = sum_h W_g[c][h]*base[i][h] via 3-pass split-bf16 MFMA (19 c-tiles,
// wave w = i-tile). W staged fp32 in LDS (pad-305), cooperatively converted to A-frags per kstep.
// BN-stats + pack stages identical to the verified k_hyp3 (out stride 64 -> 65).
__global__ void __launch_bounds__(256) k_hyp4(
    const float* __restrict__ qkW, const float* __restrict__ qkb,
    const float* __restrict__ kkW, const float* __restrict__ kkb,
    const float* __restrict__ vkW, const float* __restrict__ vkb,
    const float* __restrict__ qs, const float* __restrict__ qb,
    const float* __restrict__ ks_, const float* __restrict__ kb_,
    const float* __restrict__ vs, const float* __restrict__ vb,
    const ushort* __restrict__ basP, ushort* __restrict__ kall) {
  __shared__ float smem[19760];   // A: WsF[32][305]=9760 | Af 19456 ushort at +9760; B: outF[300*65]=19500
  __shared__ float scl[64], shf[64];
  const int g = blockIdx.x, half = blockIdx.y, tid = threadIdx.x;
  const int i0g = half * 64;
  const int ot = g >> 4, lr = g & 15;
  const bool isV = (g >= 192);
  // tiles 5 and 11 are never read by k_attn11 -> skip entirely
  if ((g >= 80 && g < 96) || (g >= 176 && g < 192)) return;

  const float* Wb = nullptr;
  const float* bvec = nullptr;
  float bns = 0.f, bnb = 0.f;
  if (g < 75)                    { Wb = qkW + (size_t)g * 38400;          bvec = qkb + g * 300;          bns = qs[g];        bnb = qb[g]; }
  else if (g >= 96 && g < 171)   { Wb = kkW + (size_t)(g - 96) * 38400;   bvec = kkb + (g - 96) * 300;   bns = ks_[g - 96];  bnb = kb_[g - 96]; }
  else if (g >= 192 && g < 492)  { Wb = vkW + (size_t)(g - 192) * 38400;  bvec = vkb + (g - 192) * 300;  bns = vs[g - 192];  bnb = vb[g - 192]; }

  if (!Wb) {  // pad rows within read tiles: exact zeros
    const uint4 z = make_uint4(0, 0, 0, 0);
    if (!isV) {
      for (int m = 0; m < 20; ++m) {
        const int idx = tid + 256 * m;
        const int ii = idx & 63, zz = idx >> 6;
        const int kg2 = zz & 3, pl = (zz >> 2) & 1, ks2 = zz >> 3;
        const size_t off = (size_t)(i0g + ii) * 225280 +
                           (size_t)(ot * 20 + ks2 * 2 + pl) * 512 + (kg2 * 16 + lr) * 8;
        *reinterpret_cast<uint4*>(kall + off) = z;
      }
    } else {
      for (int m = 0; m < 10; ++m) {
        const int idx = tid + 256 * m;
        const int ii = idx & 63, zz = idx >> 6;
        const int kg2 = zz & 3, ks2 = zz >> 2;
        const size_t off = (size_t)(i0g + ii) * 225280 +
                           (size_t)(240 + (ot - 12) * 10 + ks2) * 512 + (kg2 * 16 + lr) * 8;
        *reinterpret_cast<uint4*>(kall + off) = z;
      }
    }
    return;
  }

  const int lane = tid & 63, w = tid >> 6;
  const int lrow = lane & 15, kg = lane >> 4;
  ushort* Af = reinterpret_cast<ushort*>(smem + 9760);

  f32x4 acc[19];
#pragma unroll
  for (int ct = 0; ct < 19; ++ct) acc[ct] = (f32x4){0.f, 0.f, 0.f, 0.f};

  for (int hc = 0; hc < 4; ++hc) {
    __syncthreads();   // prior MFMA done (Af free), prior conversion's WsF reads done
    // stage WsF transposed: WsF[h][c] with stride 305 (fp32), h in [0,32), c in [0,304)
    for (int m = 0; m < 10; ++m) {
      const int u = tid + 256 * m;          // 2432 float4-units = 304c x 8
      if (u < 2432) {
        const int c = u >> 3, h4 = (u & 7) * 4;
        float4 wv = make_float4(0.f, 0.f, 0.f, 0.f);
        if (c < 300) wv = *reinterpret_cast<const float4*>(Wb + (size_t)c * 128 + hc * 32 + h4);
        smem[(h4 + 0) * 305 + c] = wv.x;
        smem[(h4 + 1) * 305 + c] = wv.y;
        smem[(h4 + 2) * 305 + c] = wv.z;
        smem[(h4 + 3) * 305 + c] = wv.w;
      }
    }
    __syncthreads();
    // convert to Af frags [ct][pl][64][8] for this kstep
    for (int m = 0; m < 5; ++m) {
      const int u = tid + 256 * m;          // 1216 lane-units
      if (u < 1216) {
        const int ln = u & 63, ct = u >> 6;
        const int cc = ct * 16 + (ln & 15);
        const int hb = (ln >> 4) * 8;
        ushort h8[8], l8[8];
#pragma unroll
        for (int e = 0; e < 8; ++e) {
          const float v = smem[(hb + e) * 305 + cc];
          const ushort hi = f2bf(v);
          h8[e] = hi;
          l8[e] = f2bf(v - bf2f(hi));
        }
        uint4 ph, pl4;
        ph.x = (uint)h8[0] | ((uint)h8[1] << 16);
        ph.y = (uint)h8[2] | ((uint)h8[3] << 16);
        ph.z = (uint)h8[4] | ((uint)h8[5] << 16);
        ph.w = (uint)h8[6] | ((uint)h8[7] << 16);
        pl4.x = (uint)l8[0] | ((uint)l8[1] << 16);
        pl4.y = (uint)l8[2] | ((uint)l8[3] << 16);
        pl4.z = (uint)l8[4] | ((uint)l8[5] << 16);
        pl4.w = (uint)l8[6] | ((uint)l8[7] << 16);
        *reinterpret_cast<uint4*>(&Af[(ct * 2 + 0) * 512 + ln * 8]) = ph;
        *reinterpret_cast<uint4*>(&Af[(ct * 2 + 1) * 512 + ln * 8]) = pl4;
      }
    }
    // B frags (global, L2-hot; wave w = i-tile)
    const bf16x8 Bh = *reinterpret_cast<const bf16x8*>(
        basP + (size_t)(half * 32 + w * 8 + hc * 2 + 0) * 512 + lane * 8);
    const bf16x8 Bl = *reinterpret_cast<const bf16x8*>(
        basP + (size_t)(half * 32 + w * 8 + hc * 2 + 1) * 512 + lane * 8);
    __syncthreads();
#pragma unroll
    for (int ct = 0; ct < 19; ++ct) {
      const bf16x8 Ah = *reinterpret_cast<const bf16x8*>(&Af[(ct * 2 + 0) * 512 + lane * 8]);
      const bf16x8 Al = *reinterpret_cast<const bf16x8*>(&Af[(ct * 2 + 1) * 512 + lane * 8]);
      acc[ct] = MFMA16(Ah, Bh, acc[ct]);
      acc[ct] = MFMA16(Ah, Bl, acc[ct]);
      acc[ct] = MFMA16(Al, Bh, acc[ct]);
    }
  }
  __syncthreads();   // all Af reads done before outF overwrite
  // write outF[c][i] (+ hypernet bias); D layout: col=lane&15 -> i, row=kg*4+r -> c
#pragma unroll
  for (int ct = 0; ct < 19; ++ct)
#pragma unroll
    for (int r = 0; r < 4; ++r) {
      const int c = ct * 16 + kg * 4 + r;
      if (c < 300) smem[c * 65 + w * 16 + lrow] = acc[ct][r] + bvec[c];
    }
  __syncthreads();
  {  // BN stats per i over c<300 (verified k_hyp3 code, stride 65)
    const int si = tid >> 2, p = tid & 3;
    float s1 = 0.f, s2 = 0.f;
    for (int c = p; c < 300; c += 4) {
      const float x = smem[c * 65 + si];
      s1 += x;
      s2 += x * x;
    }
    s1 += __shfl_xor(s1, 1); s2 += __shfl_xor(s2, 1);
    s1 += __shfl_xor(s1, 2); s2 += __shfl_xor(s2, 2);
    const float mu = s1 * (1.0f / 300.0f);
    const float var = s2 * (1.0f / 300.0f) - mu * mu;
    const float scale = bns / sqrtf(var + EPSB);
    if (p == 0) { scl[si] = scale; shf[si] = bnb - mu * scale; }
  }
  __syncthreads();
  if (!isV) {  // q/k: hi + lo planes
    for (int m = 0; m < 20; ++m) {
      const int idx = tid + 256 * m;
      const int ii = idx & 63, zz = idx >> 6;
      const int kg2 = zz & 3, pl = (zz >> 2) & 1, ks2 = zz >> 3;
      const float sc = scl[ii], sh = shf[ii];
      ushort o8[8];
#pragma unroll
      for (int e = 0; e < 8; ++e) {
        const int c = ks2 * 32 + kg2 * 8 + e;
        float val = 0.f;
        if (c < 300) val = fmaf(smem[c * 65 + ii], sc, sh);
        const ushort hi = f2bf(val);
        o8[e] = pl ? f2bf(val - bf2f(hi)) : hi;
      }
      uint4 pk;
      pk.x = (uint)o8[0] | ((uint)o8[1] << 16);
      pk.y = (uint)o8[2] | ((uint)o8[3] << 16);
      pk.z = (uint)o8[4] | ((uint)o8[5] << 16);
      pk.w = (uint)o8[6] | ((uint)o8[7] << 16);
      const size_t off = (size_t)(i0g + ii) * 225280 +
                         (size_t)(ot * 20 + ks2 * 2 + pl) * 512 + (kg2 * 16 + lr) * 8;
      *reinterpret_cast<uint4*>(kall + off) = pk;
    }
  } else {     // v: hi plane only
    for (int m = 0; m < 10; ++m) {
      const int idx = tid + 256 * m;
      const int ii = idx & 63, zz = idx >> 6;
      const int kg2 = zz & 3, ks2 = zz >> 2;
      const float sc = scl[ii], sh = shf[ii];
      ushort o8[8];
#pragma unroll
      for (int e = 0; e < 8; ++e) {
        const int c = ks2 * 32 + kg2 * 8 + e;
        float val = 0.f;
        if (c < 300) val = fmaf(smem[c * 65 + ii], sc, sh);
        o8[e] = f2bf(val);
      }
      uint4 pk;
      pk.x = (uint)o8[0] | ((uint)o8[1] << 16);
      pk.y = (uint)o8[2] | ((uint)o8[3] << 16);
      pk.z = (uint)o8[4] | ((uint)o8[5] << 16);
      pk.w = (uint)o8[6] | ((uint)o8[7] << 16);
      const size_t off = (size_t)(i0g + ii) * 225280 +
                         (size_t)(240 + (ot - 12) * 10 + ks2) * 512 + (kg2 * 16 + lr) * 8;
      *reinterpret_cast<uint4*>(kall + off) = pk;
    }
  }
}

// ---------------- K4: fused attention; MFMA scores + 2-deep A-prefetch; pad-tiles skipped ----------------
__global__ void __launch_bounds__(256, 4) k_attn11(
    const float* __restrict__ cap, const ushort* __restrict__ kall,
    const ushort* __restrict__ capP, const float* __restrict__ ball,
    const float* __restrict__ gptr, float* __restrict__ x_all) {
  __shared__ ushort qkp[24 * 512];       // P1/P2: packed q (units 0-11) + k (12-23); P3: vt
  __shared__ float sc_s[32 * 36];        // fp32 scores [t][s]
  __shared__ ushort at_p[2 * 2 * 64 * 8];
  const int bid = blockIdx.x;
  const int xcd = bid & 7, q = bid >> 3;
  const int i = xcd * 16 + (q >> 6), n = q & 63;
  const int tid = threadIdx.x;
  const int lane = tid & 63, w = tid >> 6;
  const int lrow = lane & 15, kg = lane >> 4;
  const float gamma = gptr[0];
  const ushort* kpL = kall + (size_t)i * 225280 + lane * 8;
  const ushort* cpL = capP + (size_t)n * 20480 + lane * 8;
  const float* bal = ball + i * 512;
  const bool oddw = (w & 1);   // waves 1,3 own only 2 real tiles (tiles 5,11 are all-pad)

  // ---- P1: q+k tiles {0..4, 6..10}, wave w tiles {3w..}; 2-deep A-prefetch
  {
    f32x4 acc[3][2];
#pragma unroll
    for (int a = 0; a < 3; ++a)
#pragma unroll
      for (int b2 = 0; b2 < 2; ++b2) acc[a][b2] = (f32x4){0.f, 0.f, 0.f, 0.f};
    bf16x8 AhA[3], AlA[3], AhB[3], AlB[3];
#pragma unroll
    for (int mt = 0; mt < 3; ++mt)
      if (!oddw || mt < 2) {   // preload kstep 0
        const ushort* p = kpL + (size_t)((w * 3 + mt) * 20) * 512;
        AhA[mt] = *reinterpret_cast<const bf16x8*>(p);
        AlA[mt] = *reinterpret_cast<const bf16x8*>(p + 512);
      }
#pragma unroll
    for (int kp = 0; kp < 5; ++kp) {
      {  // even kstep 2kp
        const int ks = 2 * kp;
        bf16x8 Bh[2], Bl[2];
#pragma unroll
        for (int nt = 0; nt < 2; ++nt) {
          const ushort* p = cpL + (size_t)(nt * 20 + ks * 2) * 512;
          Bh[nt] = *reinterpret_cast<const bf16x8*>(p);
          Bl[nt] = *reinterpret_cast<const bf16x8*>(p + 512);
        }
#pragma unroll
        for (int mt = 0; mt < 3; ++mt)
          if (!oddw || mt < 2) {
            const ushort* p = kpL + (size_t)((w * 3 + mt) * 20 + (ks + 1) * 2) * 512;
            AhB[mt] = *reinterpret_cast<const bf16x8*>(p);
            AlB[mt] = *reinterpret_cast<const bf16x8*>(p + 512);
          }
#pragma unroll
        for (int mt = 0; mt < 3; ++mt)
          if (!oddw || mt < 2)
#pragma unroll
            for (int nt = 0; nt < 2; ++nt) {
              acc[mt][nt] = MFMA16(AhA[mt], Bh[nt], acc[mt][nt]);
              acc[mt][nt] = MFMA16(AhA[mt], Bl[nt], acc[mt][nt]);
              acc[mt][nt] = MFMA16(AlA[mt], Bh[nt], acc[mt][nt]);
            }
      }
      {  // odd kstep 2kp+1
        const int ks = 2 * kp + 1;
        bf16x8 Bh[2], Bl[2];
#pragma unroll
        for (int nt = 0; nt < 2; ++nt) {
          const ushort* p = cpL + (size_t)(nt * 20 + ks * 2) * 512;
          Bh[nt] = *reinterpret_cast<const bf16x8*>(p);
          Bl[nt] = *reinterpret_cast<const bf16x8*>(p + 512);
        }
        if (kp < 4) {
#pragma unroll
          for (int mt = 0; mt < 3; ++mt)
            if (!oddw || mt < 2) {
              const ushort* p = kpL + (size_t)((w * 3 + mt) * 20 + (ks + 1) * 2) * 512;
              AhA[mt] = *reinterpret_cast<const bf16x8*>(p);
              AlA[mt] = *reinterpret_cast<const bf16x8*>(p + 512);
            }
        }
#pragma unroll
        for (int mt = 0; mt < 3; ++mt)
          if (!oddw || mt < 2)
#pragma unroll
            for (int nt = 0; nt < 2; ++nt) {
              acc[mt][nt] = MFMA16(AhB[mt], Bh[nt], acc[mt][nt]);
              acc[mt][nt] = MFMA16(AhB[mt], Bl[nt], acc[mt][nt]);
              acc[mt][nt] = MFMA16(AlB[mt], Bh[nt], acc[mt][nt]);
            }
      }
    }
    // epilogue: write q/k as packed split-bf16 MFMA fragments (phantom tiles: acc=0, bal=0 -> zeros)
#pragma unroll
    for (int mt = 0; mt < 3; ++mt)
#pragma unroll
      for (int nt = 0; nt < 2; ++nt)
#pragma unroll
        for (int r = 0; r < 4; ++r) {
          const int og = w * 48 + mt * 16 + kg * 4 + r;
          const float val = acc[mt][nt][r] + bal[og];
          const ushort hi = f2bf(val);
          const ushort lo = f2bf(val - bf2f(hi));
          const int os = (w < 2) ? og : og - 96;
          const int ub = ((w < 2) ? 0 : 12) + nt * 6 + (os >> 5) * 2;
          const int lp = ((os & 31) >> 3) * 16 + lrow;
          const int e = os & 7;
          qkp[(ub + 0) * 512 + lp * 8 + e] = hi;
          qkp[(ub + 1) * 512 + lp * 8 + e] = lo;
        }
  }
  __syncthreads();

  // ---- P2a: scores via MFMA (4-pass split, K=96); wave w -> quadrant (tt,st)
  {
    const int tt = w >> 1, st = w & 1;
    bf16x8 Aq[3][2], Bk[3][2];
#pragma unroll
    for (int k3 = 0; k3 < 3; ++k3)
#pragma unroll
      for (int pl = 0; pl < 2; ++pl) {
        Aq[k3][pl] = *reinterpret_cast<const bf16x8*>(&qkp[(tt * 6 + k3 * 2 + pl) * 512 + lane * 8]);
        Bk[k3][pl] = *reinterpret_cast<const bf16x8*>(&qkp[(12 + st * 6 + k3 * 2 + pl) * 512 + lane * 8]);
      }
    f32x4 D = (f32x4){0.f, 0.f, 0.f, 0.f};
#pragma unroll
    for (int k3 = 0; k3 < 3; ++k3) {
      D = MFMA16(Aq[k3][0], Bk[k3][0], D);
      D = MFMA16(Aq[k3][0], Bk[k3][1], D);
      D = MFMA16(Aq[k3][1], Bk[k3][0], D);
      D = MFMA16(Aq[k3][1], Bk[k3][1], D);
    }
#pragma unroll
    for (int r = 0; r < 4; ++r)
      sc_s[(tt * 16 + kg * 4 + r) * 36 + st * 16 + lrow] = D[r];
  }
  __syncthreads();

  // ---- P2b: softmax (fp32) + pack attn to at_p (bf16 hi/lo, MFMA-B layout)
  {
    const int sg = tid & 7, tq = tid >> 3;
    const int s0 = sg * 4;
    const float4 sv = *reinterpret_cast<const float4*>(&sc_s[tq * 36 + s0]);
    float sc[4] = {sv.x, sv.y, sv.z, sv.w};
    float m = fmaxf(fmaxf(sc[0], sc[1]), fmaxf(sc[2], sc[3]));
    m = fmaxf(m, __shfl_xor(m, 1));
    m = fmaxf(m, __shfl_xor(m, 2));
    m = fmaxf(m, __shfl_xor(m, 4));
    float ev[4], ssum = 0.f;
#pragma unroll
    for (int u = 0; u < 4; ++u) { ev[u] = expf(sc[u] - m); ssum += ev[u]; }
    ssum += __shfl_xor(ssum, 1);
    ssum += __shfl_xor(ssum, 2);
    ssum += __shfl_xor(ssum, 4);
    const float inv = 1.0f / ssum;
    const int tt = tq >> 4, lrp = tq & 15, kgp = sg >> 1, eb = (sg & 1) * 4;
    ushort h4[4], l4[4];
#pragma unroll
    for (int u = 0; u < 4; ++u) {
      const float val = ev[u] * inv;
      const ushort hi = f2bf(val);
      h4[u] = hi;
      l4[u] = f2bf(val - bf2f(hi));
    }
    uint2 ph, pl2;
    ph.x = (uint)h4[0] | ((uint)h4[1] << 16);
    ph.y = (uint)h4[2] | ((uint)h4[3] << 16);
    pl2.x = (uint)l4[0] | ((uint)l4[1] << 16);
    pl2.y = (uint)l4[2] | ((uint)l4[3] << 16);
    *reinterpret_cast<uint2*>(&at_p[((tt * 2 + 0) * 64 + kgp * 16 + lrp) * 8 + eb]) = ph;
    *reinterpret_cast<uint2*>(&at_p[((tt * 2 + 1) * 64 + kgp * 16 + lrp) * 8 + eb]) = pl2;
  }
  __syncthreads();

  // ---- P3: v tiles [12,32) in 2 chunks; 1-pass bf16 proj (2-deep A-prefetch) + MFMA PV
  ushort* vt = qkp;
#pragma unroll
  for (int ch = 0; ch < 2; ++ch) {
    const int TB = 12 + ch * 12;
    const int RB = TB * 16;
    const int nmt = ch ? 2 : 3;
    f32x4 vacc[3][2];
#pragma unroll
    for (int a = 0; a < 3; ++a)
#pragma unroll
      for (int b2 = 0; b2 < 2; ++b2) vacc[a][b2] = (f32x4){0.f, 0.f, 0.f, 0.f};
    bf16x8 AvA[3], AvB[3];
    for (int mi = 0; mi < nmt; ++mi)   // preload kstep 0
      AvA[mi] = *reinterpret_cast<const bf16x8*>(
          kpL + (size_t)(240 + (TB - 12 + w + mi * 4) * 10) * 512);
#pragma unroll
    for (int kp = 0; kp < 5; ++kp) {
      {  // even ks=2kp
        const int ks = 2 * kp;
        bf16x8 Bh[2];
#pragma unroll
        for (int nt = 0; nt < 2; ++nt)
          Bh[nt] = *reinterpret_cast<const bf16x8*>(cpL + (size_t)(nt * 20 + ks * 2) * 512);
        for (int mi = 0; mi < nmt; ++mi)
          AvB[mi] = *reinterpret_cast<const bf16x8*>(
              kpL + (size_t)(240 + (TB - 12 + w + mi * 4) * 10 + ks + 1) * 512);
        for (int mi = 0; mi < nmt; ++mi)
#pragma unroll
          for (int nt = 0; nt < 2; ++nt)
            vacc[mi][nt] = MFMA16(AvA[mi], Bh[nt], vacc[mi][nt]);
      }
      {  // odd ks=2kp+1
        const int ks = 2 * kp + 1;
        bf16x8 Bh[2];
#pragma unroll
        for (int nt = 0; nt < 2; ++nt)
          Bh[nt] = *reinterpret_cast<const bf16x8*>(cpL + (size_t)(nt * 20 + ks * 2) * 512);
        if (kp < 4) {
          for (int mi = 0; mi < nmt; ++mi)
            AvA[mi] = *reinterpret_cast<const bf16x8*>(
                kpL + (size_t)(240 + (TB - 12 + w + mi * 4) * 10 + ks + 1) * 512);
        }
        for (int mi = 0; mi < nmt; ++mi)
#pragma unroll
          for (int nt = 0; nt < 2; ++nt)
            vacc[mi][nt] = MFMA16(AvB[mi], Bh[nt], vacc[mi][nt]);
      }
    }
    if (ch) __syncthreads();   // prior P3b readers of vt done
    for (int mi = 0; mi < nmt; ++mi) {
      const int tile = w + mi * 4;
#pragma unroll
      for (int nt = 0; nt < 2; ++nt) {
        const int kgp = nt * 2 + (lrow >> 3), ee = lrow & 7;
#pragma unroll
        for (int r = 0; r < 4; ++r) {
          const int vl = tile * 16 + kg * 4 + r;
          const float val = vacc[mi][nt][r] + bal[RB + vl];
          const ushort hi = f2bf(val);
          vt[((tile * 2 + 0) * 64 + kgp * 16 + kg * 4 + r) * 8 + ee] = hi;
          vt[((tile * 2 + 1) * 64 + kgp * 16 + kg * 4 + r) * 8 + ee] = f2bf(val - bf2f(hi));
        }
      }
    }
    __syncthreads();
    {  // P3b: MFMA PV + residual + max
      bf16x8 ah[2], al[2];
#pragma unroll
      for (int tt = 0; tt < 2; ++tt) {
        ah[tt] = *reinterpret_cast<const bf16x8*>(&at_p[((tt * 2 + 0) * 64 + lane) * 8]);
        al[tt] = *reinterpret_cast<const bf16x8*>(&at_p[((tt * 2 + 1) * 64 + lane) * 8]);
      }
      const int npw = ch ? 2 : 3;
      for (int j = 0; j < npw; ++j) {
        const int ct = w * npw + j;
        const int c0 = ch * 192 + ct * 16 + (lane >> 4) * 4;
        const bf16x8 vh  = *reinterpret_cast<const bf16x8*>(&vt[((ct * 2 + 0) * 64 + lane) * 8]);
        const bf16x8 vl8 = *reinterpret_cast<const bf16x8*>(&vt[((ct * 2 + 1) * 64 + lane) * 8]);
        f32x4 a0 = (f32x4){0.f, 0.f, 0.f, 0.f}, a1 = (f32x4){0.f, 0.f, 0.f, 0.f};
        a0 = MFMA16(vh, ah[0], a0);
        a0 = MFMA16(vh, al[0], a0);
        a0 = MFMA16(vl8, ah[0], a0);
        a1 = MFMA16(vh, ah[1], a1);
        a1 = MFMA16(vh, al[1], a1);
        a1 = MFMA16(vl8, ah[1], a1);
        if (c0 < 300) {
          const int t0 = lane & 15;
          const float4 c4a = *reinterpret_cast<const float4*>(&cap[(size_t)n * 9600 + t0 * 300 + c0]);
          const float4 c4b = *reinterpret_cast<const float4*>(&cap[(size_t)n * 9600 + (t0 + 16) * 300 + c0]);
          float mx[4];
          mx[0] = fmaxf(fmaf(gamma, a0[0], c4a.x), fmaf(gamma, a1[0], c4b.x));
          mx[1] = fmaxf(fmaf(gamma, a0[1], c4a.y), fmaf(gamma, a1[1], c4b.y));
          mx[2] = fmaxf(fmaf(gamma, a0[2], c4a.z), fmaf(gamma, a1[2], c4b.z));
          mx[3] = fmaxf(fmaf(gamma, a0[3], c4a.w), fmaf(gamma, a1[3], c4b.w));
#pragma unroll
          for (int mmask = 1; mmask < 16; mmask <<= 1)
#pragma unroll
            for (int r = 0; r < 4; ++r) mx[r] = fmaxf(mx[r], __shfl_xor(mx[r], mmask));
          if ((lane & 15) == 0)
            *reinterpret_cast<float4*>(&x_all[((size_t)i * 64 + n) * 300 + c0]) =
                make_float4(mx[0], mx[1], mx[2], mx[3]);
        }
      }
    }
  }
}

// ---------------- K5a: h1 = relu(BN1(x @ W1^T + b1)) — BN1 fused ----------------
__global__ void __launch_bounds__(256, 4) k_h1b(
    const float* __restrict__ x_all, const float* __restrict__ W1,
    const float* __restrict__ b1, const float* __restrict__ bn1s,
    const float* __restrict__ bn1b, float* __restrict__ h1) {
  __shared__ float xt[32 * 68];
  __shared__ float wt[32 * 132];
  __shared__ float sc1[128], sh1[128];
  const int ec = blockIdx.x, i = blockIdx.y, tid = threadIdx.x;
  const int e0c = ec * 128;
  const int eg = tid & 15, ng = tid >> 4;
  const int e0 = eg * 8, n0 = ng * 4;
  float acc[4][8] = {};
  for (int cb = 0; cb < 10; ++cb) {
    const int c0 = cb * 32;
    __syncthreads();
    for (int k = 0; k < 8; ++k) {
      const int idx = tid + 256 * k;
      const int nn = idx >> 5, cl = idx & 31;
      const int c = c0 + cl;
      xt[cl * 68 + nn] = (c < 300) ? x_all[((size_t)i * 64 + nn) * 300 + c] : 0.0f;
    }
    for (int k = 0; k < 16; ++k) {
      const int idx = tid + 256 * k;
      const int ee = idx >> 5, cl = idx & 31;
      const int c = c0 + cl;
      wt[cl * 132 + ee] = (c < 300) ? W1[(size_t)(e0c + ee) * 300 + c] : 0.0f;
    }
    __syncthreads();
#pragma unroll 4
    for (int cl = 0; cl < 32; ++cl) {
      const float4 xv = *reinterpret_cast<const float4*>(&xt[cl * 68 + n0]);
      const float4 wa = *reinterpret_cast<const float4*>(&wt[cl * 132 + e0]);
      const float4 wb = *reinterpret_cast<const float4*>(&wt[cl * 132 + e0 + 4]);
      const float xv4[4] = {xv.x, xv.y, xv.z, xv.w};
      const float wv8[8] = {wa.x, wa.y, wa.z, wa.w, wb.x, wb.y, wb.z, wb.w};
#pragma unroll
      for (int u = 0; u < 4; ++u)
#pragma unroll
        for (int v = 0; v < 8; ++v) acc[u][v] = fmaf(xv4[u], wv8[v], acc[u][v]);
    }
  }
  float b1v[8];
#pragma unroll
  for (int v = 0; v < 8; ++v) b1v[v] = b1[e0c + e0 + v];
  float val[4][8];
#pragma unroll
  for (int u = 0; u < 4; ++u)
#pragma unroll
    for (int v = 0; v < 8; ++v) val[u][v] = acc[u][v] + b1v[v];
  __syncthreads();
  float* ps1 = xt;   // [16][132]
  float* ps2 = wt;   // [16][132]
#pragma unroll
  for (int v = 0; v < 8; ++v) {
    float su = 0.f, sq = 0.f;
#pragma unroll
    for (int u = 0; u < 4; ++u) { su += val[u][v]; sq += val[u][v] * val[u][v]; }
    ps1[ng * 132 + e0 + v] = su;
    ps2[ng * 132 + e0 + v] = sq;
  }
  __syncthreads();
  if (tid < 128) {
    const int e = tid;
    float s1 = 0.f, s2 = 0.f;
#pragma unroll 4
    for (int gq = 0; gq < 16; ++gq) { s1 += ps1[gq * 132 + e]; s2 += ps2[gq * 132 + e]; }
    const float mu = s1 * (1.0f / 64.0f);
    const float var = s2 * (1.0f / 64.0f) - mu * mu;
    const float scale = bn1s[e0c + e] / sqrtf(var + EPSB);
    sc1[e] = scale;
    sh1[e] = bn1b[e0c + e] - mu * scale;
  }
  __syncthreads();
#pragma unroll
  for (int u = 0; u < 4; ++u) {
    float o8[8];
#pragma unroll
    for (int v = 0; v < 8; ++v)
      o8[v] = fmaxf(fmaf(val[u][v], sc1[e0 + v], sh1[e0 + v]), 0.0f);
    float* dst = h1 + ((size_t)i * 64 + n0 + u) * 512 + e0c + e0;
    *reinterpret_cast<float4*>(dst) = make_float4(o8[0], o8[1], o8[2], o8[3]);
    *reinterpret_cast<float4*>(dst + 4) = make_float4(o8[4], o8[5], o8[6], o8[7]);
  }
}

// ---------------- K5b: h2 = h1 @ W2^T + b2 ----------------
__global__ void __launch_bounds__(256) k_h2(
    const float* __restrict__ h1, const float* __restrict__ W2,
    const float* __restrict__ b2, float* __restrict__ h2buf) {
  __shared__ float h1s[32 * 517];
  const int jn = blockIdx.x, i = blockIdx.y, tid = threadIdx.x;
  const int bn = jn * 32;
  for (int m = 0; m < 64; ++m) {
    const int idx = tid + 256 * m;   // 16384
    h1s[(idx >> 9) * 517 + (idx & 511)] = h1[((size_t)i * 64 + bn) * 512 + idx];
  }
  __syncthreads();
  const int dg = tid & 15, ng2 = tid >> 4;
  const int d0 = dg * 4, n0 = ng2 * 2;
  float a0[4] = {}, a1[4] = {};
#pragma unroll 4
  for (int e = 0; e < 512; ++e) {
    const float h0 = h1s[n0 * 517 + e];
    const float h1v = h1s[(n0 + 1) * 517 + e];
#pragma unroll
    for (int v = 0; v < 4; ++v) {
      const float wv = W2[(size_t)(d0 + v) * 512 + e];
      a0[v] = fmaf(h0, wv, a0[v]);
      a1[v] = fmaf(h1v, wv, a1[v]);
    }
  }
  const float4 bb = *reinterpret_cast<const float4*>(&b2[d0]);
  float* dst0 = h2buf + ((size_t)i * 64 + bn + n0) * 64 + d0;
  *reinterpret_cast<float4*>(dst0) = make_float4(a0[0] + bb.x, a0[1] + bb.y, a0[2] + bb.z, a0[3] + bb.w);
  *reinterpret_cast<float4*>(dst0 + 64) = make_float4(a1[0] + bb.x, a1[1] + bb.y, a1[2] + bb.z, a1[3] + bb.w);
}

// ---------------- K5c: BN2 + relu + W3 dot -> out ----------------
__global__ void __launch_bounds__(256) k_out(
    const float* __restrict__ h2buf, const float* __restrict__ bn2s,
    const float* __restrict__ bn2b, const float* __restrict__ W3,
    const float* __restrict__ b3, float* __restrict__ out) {
  __shared__ float h2s[64 * 65];
  const int i = blockIdx.x, tid = threadIdx.x;
  for (int m = 0; m < 16; ++m) {
    const int idx = tid + 256 * m;   // 4096
    h2s[(idx >> 6) * 65 + (idx & 63)] = h2buf[(size_t)i * 4096 + idx];
  }
  __syncthreads();
  if (tid < 64) {
    const int d = tid;
    float s1 = 0.f, s2 = 0.f;
    for (int nn = 0; nn < 64; ++nn) {
      const float v = h2s[nn * 65 + d];
      s1 += v;
      s2 += v * v;
    }
    const float mu = s1 * (1.0f / 64.0f);
    const float var = s2 * (1.0f / 64.0f) - mu * mu;
    const float scale = bn2s[d] / sqrtf(var + EPSB);
    const float shift = bn2b[d] - mu * scale;
    for (int nn = 0; nn < 64; ++nn)
      h2s[nn * 65 + d] = fmaxf(fmaf(h2s[nn * 65 + d], scale, shift), 0.0f);
  }
  __syncthreads();
  if (tid < 64) {
    const int nn = tid;
    float acc = b3[0];
    for (int d = 0; d < 64; ++d) acc = fmaf(h2s[nn * 65 + d], W3[d], acc);
    out[i * 64 + nn] = acc;
  }
}

extern "C" void kernel_launch(void* const* d_in, const int* in_sizes, int n_in,
                              void* d_out, int out_size, void* d_ws, size_t ws_size,
                              hipStream_t stream) {
  const float* img  = (const float*)d_in[0];
  const float* cap  = (const float*)d_in[1];
  const float* adW  = (const float*)d_in[2];
  const float* adb  = (const float*)d_in[3];
  const float* qkW  = (const float*)d_in[4];
  const float* qkb  = (const float*)d_in[5];
  const float* qbW  = (const float*)d_in[6];
  const float* qbb  = (const float*)d_in[7];
  const float* qbns = (const float*)d_in[8];
  const float* qbnb = (const float*)d_in[9];
  const float* kkW  = (const float*)d_in[10];
  const float* kkb  = (const float*)d_in[11];
  const float* kbW  = (const float*)d_in[12];
  const float* kbb  = (const float*)d_in[13];
  const float* kbns = (const float*)d_in[14];
  const float* kbnb = (const float*)d_in[15];
  const float* vkW  = (const float*)d_in[16];
  const float* vkb  = (const float*)d_in[17];
  const float* vbW  = (const float*)d_in[18];
  const float* vbb  = (const float*)d_in[19];
  const float* vbns = (const float*)d_in[20];
  const float* vbnb = (const float*)d_in[21];
  const float* gamma= (const float*)d_in[22];
  const float* W1   = (const float*)d_in[23];
  const float* b1   = (const float*)d_in[24];
  const float* bn1s = (const float*)d_in[25];
  const float* bn1b = (const float*)d_in[26];
  const float* W2   = (const float*)d_in[27];
  const float* b2   = (const float*)d_in[28];
  const float* bn2s = (const float*)d_in[29];
  const float* bn2b = (const float*)d_in[30];
  const float* W3   = (const float*)d_in[31];
  const float* b3   = (const float*)d_in[32];

  float* ws    = (float*)d_ws;
  float* base  = ws + OFS_BASE;
  float* ball  = ws + OFS_BALL;
  float* mean  = ws + OFS_MEAN;
  ushort* capP = (ushort*)(ws + OFS_CAPB);
  ushort* kall = (ushort*)(ws + OFS_RAWP);
  float* x_all = ws + OFS_X;
  float* h2buf = ws + OFS_H2;
  ushort* basP = (ushort*)(ws + OFS_BASP);
  float* h1    = ws + OFS_H1;    // aliases kall (dead after k_attn11)
  float* out   = (float*)d_out;

  k_mean<<<512, 256, 0, stream>>>(img, mean);
  k_base<<<128, 128, 0, stream>>>(mean, adW, adb, base);
  k_basp<<<2, 256, 0, stream>>>(base, basP);
  k_bias<<<dim3(2, 128), 256, 0, stream>>>(qbW, qbb, kbW, kbb, vbW, vbb, base, ball);
  k_capp<<<64, 256, 0, stream>>>(cap, capP);
  k_hyp4<<<dim3(512, 2), 256, 0, stream>>>(qkW, qkb, kkW, kkb, vkW, vkb,
                                           qbns, qbnb, kbns, kbnb, vbns, vbnb, basP, kall);
  k_attn11<<<8192, 256, 0, stream>>>(cap, kall, capP, ball, gamma, x_all);
  k_h1b<<<dim3(4, 128), 256, 0, stream>>>(x_all, W1, b1, bn1s, bn1b, h1);
  k_h2<<<dim3(2, 128), 256, 0, stream>>>(h1, W2, b2, h2buf);
  k_out<<<128, 256, 0, stream>>>(h2buf, bn2s, bn2b, W3, b3, out);
}

// Round 12
// 485.956 us; speedup vs baseline: 1.4856x; 1.0627x over previous
//
#include <hip/hip_runtime.h>
#include <math.h>

#define EPSB 1e-5f

// Bi=128 Bc=64 T=32 C=300 OQK=75 H=128 LAT=1024
// Padded stacked o-dim (512): q [0,96) (75 real), k [96,192) (75 real), v [192,512) (300 real)
// Compact packed kall (per image, ushort): q/k tiles ot 0..11: units ot*20+ks*2+pl (hi+lo);
//   v tiles ot 12..31: units 240+(ot-12)*10+ks (hi only). 440 units x 512 ushort = 225280 ushort/img.
// Unit layout: [lane=64][8] ushort; element (o=16*ot+lr, c=32*ks+8*kg+e), lane=kg*16+lr.
// NOTE: o-tiles 5 and 11 are ALL-PAD; k_attn skips them (bit-exact) and k_hyp4 never writes them.
// ws layout (float offsets):
static const long OFS_BASE  = 0;                      // 128*128
static const long OFS_BALL  = 16384;                  // 128*512
static const long OFS_CAPB  = 212992;                 // capP: 64*20480 ushort = 655360 floats
static const long OFS_RAWP  = 868352;                 // kall: 128*225280 ushort = 14,417,920 floats
static const long OFS_X     = 15286272;               // 128*64*300
static const long OFS_H2    = 17743872;               // 128*64*64
static const long OFS_BASP  = 18268160;               // basP: 2*32*512 ushort = 16384 floats
static const long OFS_H1    = OFS_RAWP;               // alias (kall dead after k_attn12)

using bf16x8 = __attribute__((ext_vector_type(8))) __bf16;
using f32x4  = __attribute__((ext_vector_type(4))) float;
#define MFMA16(a, b, c) __builtin_amdgcn_mfma_f32_16x16x32_bf16(a, b, c, 0, 0, 0)

__device__ inline ushort f2bf(float f) {
  const unsigned u = __float_as_uint(f);
  return (ushort)((u + 0x7FFFu + ((u >> 16) & 1u)) >> 16);
}
__device__ inline float bf2f(ushort h) { return __uint_as_float(((unsigned)h) << 16); }

// ---------------- K1: fused img_mean + base GEMM (one block per image) ----------------
__global__ void __launch_bounds__(256) k_mb(const float* __restrict__ img,
                                            const float* __restrict__ W,
                                            const float* __restrict__ b,
                                            float* __restrict__ base) {
  __shared__ float m_s[1024];
  __shared__ float part[128];
  const int i = blockIdx.x, tid = threadIdx.x;
#pragma unroll
  for (int lc = 0; lc < 4; ++lc) {
    const int l = lc * 256 + tid;
    const float* p = img + (size_t)i * 36864 + l;
    float s = 0.f;
#pragma unroll
    for (int r = 0; r < 36; ++r) s += p[r * 1024];
    m_s[l] = s * (1.0f / 36.0f);
  }
  __syncthreads();
  const int o = tid & 127, hk = tid >> 7;
  const float* wr = W + (size_t)o * 1024 + hk * 512;
  const float* ms = m_s + hk * 512;
  float acc = 0.f;
#pragma unroll 4
  for (int l = 0; l < 512; ++l) acc = fmaf(ms[l], wr[l], acc);
  if (hk) part[o] = acc;
  __syncthreads();
  if (!hk) base[i * 128 + o] = acc + part[o] + b[o];
}

// ---------------- K2: fused prep — bias (bid<256) | capP pack (bid<320) | basP pack ----------------
__global__ void __launch_bounds__(256) k_prep(
    const float* __restrict__ qbW, const float* __restrict__ qbb,
    const float* __restrict__ kbW, const float* __restrict__ kbb,
    const float* __restrict__ vbW, const float* __restrict__ vbb,
    const float* __restrict__ base, float* __restrict__ ball,
    const float* __restrict__ cap, ushort* __restrict__ capP,
    ushort* __restrict__ basP) {
  __shared__ float shm[32 * 301];
  const int bid = blockIdx.x, tid = threadIdx.x;
  if (bid < 256) {                     // ---- bias: ball[i][512]
    const int i = bid >> 1;
    if (tid < 128) shm[tid] = base[i * 128 + tid];
    __syncthreads();
    const int o = (bid & 1) * 256 + tid;
    const float* Wr = nullptr;
    float bb = 0.0f;
    if (o < 75)                   { Wr = qbW + (size_t)o * 128;         bb = qbb[o]; }
    else if (o >= 96 && o < 171)  { Wr = kbW + (size_t)(o - 96) * 128;  bb = kbb[o - 96]; }
    else if (o >= 192 && o < 492) { Wr = vbW + (size_t)(o - 192) * 128; bb = vbb[o - 192]; }
    float acc = 0.0f;
    if (Wr) {
#pragma unroll 4
      for (int h = 0; h < 128; ++h) acc = fmaf(Wr[h], shm[h], acc);
      acc += bb;
    }
    ball[i * 512 + o] = acc;
  } else if (bid < 320) {              // ---- capP pack
    const int n = bid - 256;
    const float* capn = cap + (size_t)n * 9600;
    {
      const int r = tid >> 3, c8 = tid & 7;
      for (int m = 0; m < 38; ++m) {
        const int c = c8 + 8 * m;
        if (c < 300) shm[r * 301 + c] = capn[r * 300 + c];
      }
    }
    __syncthreads();
    ushort* dst = capP + (size_t)n * 20480;
    for (int u = 0; u < 10; ++u) {
      const int ul = tid + 256 * u;
      const int unit = ul >> 6, lane = ul & 63;
      const int nt = unit / 20, rem = unit % 20;
      const int ks = rem >> 1, pl = rem & 1;
      const int kg = lane >> 4, lr = lane & 15;
      const int t = nt * 16 + lr;
      ushort o8[8];
#pragma unroll
      for (int e = 0; e < 8; ++e) {
        const int c = 32 * ks + 8 * kg + e;
        const float val = (c < 300) ? shm[t * 301 + c] : 0.f;
        const ushort hi = f2bf(val);
        o8[e] = pl ? f2bf(val - bf2f(hi)) : hi;
      }
      uint4 pk;
      pk.x = (uint)o8[0] | ((uint)o8[1] << 16);
      pk.y = (uint)o8[2] | ((uint)o8[3] << 16);
      pk.z = (uint)o8[4] | ((uint)o8[5] << 16);
      pk.w = (uint)o8[6] | ((uint)o8[7] << 16);
      *reinterpret_cast<uint4*>(dst + unit * 512 + lane * 8) = pk;
    }
  } else {                             // ---- basP pack
    const int half = bid - 320;
    for (int m = 0; m < 8; ++m) {
      const int u = tid + 256 * m;
      const int ln = u & 63, unit = u >> 6;
      const int it = unit >> 3, ks = (unit >> 1) & 3, pl = unit & 1;
      const int i = half * 64 + it * 16 + (ln & 15);
      const int h = ks * 32 + (ln >> 4) * 8;
      ushort o8[8];
#pragma unroll
      for (int e = 0; e < 8; ++e) {
        const float v = base[(size_t)i * 128 + h + e];
        const ushort hi = f2bf(v);
        o8[e] = pl ? f2bf(v - bf2f(hi)) : hi;
      }
      uint4 pk;
      pk.x = (uint)o8[0] | ((uint)o8[1] << 16);
      pk.y = (uint)o8[2] | ((uint)o8[3] << 16);
      pk.z = (uint)o8[4] | ((uint)o8[5] << 16);
      pk.w = (uint)o8[6] | ((uint)o8[7] << 16);
      *reinterpret_cast<uint4*>(basP + (size_t)(half * 32 + unit) * 512 + ln * 8) = pk;
    }
  }
}

// ---------------- K3: MFMA hypernet GEMM + row-BN + split-bf16 pack -> compact kall ----------------
__global__ void __launch_bounds__(256) k_hyp4(
    const float* __restrict__ qkW, const float* __restrict__ qkb,
    const float* __restrict__ kkW, const float* __restrict__ kkb,
    const float* __restrict__ vkW, const float* __restrict__ vkb,
    const float* __restrict__ qs, const float* __restrict__ qb,
    const float* __restrict__ ks_, const float* __restrict__ kb_,
    const float* __restrict__ vs, const float* __restrict__ vb,
    const ushort* __restrict__ basP, ushort* __restrict__ kall) {
  __shared__ float smem[19760];   // A: WsF[32][305]=9760 | Af 19456 ushort at +9760; B: outF[300*65]=19500
  __shared__ float scl[64], shf[64];
  const int g = blockIdx.x, half = blockIdx.y, tid = threadIdx.x;
  const int i0g = half * 64;
  const int ot = g >> 4, lr = g & 15;
  const bool isV = (g >= 192);
  if ((g >= 80 && g < 96) || (g >= 176 && g < 192)) return;   // never-read tiles

  const float* Wb = nullptr;
  const float* bvec = nullptr;
  float bns = 0.f, bnb = 0.f;
  if (g < 75)                    { Wb = qkW + (size_t)g * 38400;          bvec = qkb + g * 300;          bns = qs[g];        bnb = qb[g]; }
  else if (g >= 96 && g < 171)   { Wb = kkW + (size_t)(g - 96) * 38400;   bvec = kkb + (g - 96) * 300;   bns = ks_[g - 96];  bnb = kb_[g - 96]; }
  else if (g >= 192 && g < 492)  { Wb = vkW + (size_t)(g - 192) * 38400;  bvec = vkb + (g - 192) * 300;  bns = vs[g - 192];  bnb = vb[g - 192]; }

  if (!Wb) {  // pad rows within read tiles: exact zeros
    const uint4 z = make_uint4(0, 0, 0, 0);
    if (!isV) {
      for (int m = 0; m < 20; ++m) {
        const int idx = tid + 256 * m;
        const int ii = idx & 63, zz = idx >> 6;
        const int kg2 = zz & 3, pl = (zz >> 2) & 1, ks2 = zz >> 3;
        const size_t off = (size_t)(i0g + ii) * 225280 +
                           (size_t)(ot * 20 + ks2 * 2 + pl) * 512 + (kg2 * 16 + lr) * 8;
        *reinterpret_cast<uint4*>(kall + off) = z;
      }
    } else {
      for (int m = 0; m < 10; ++m) {
        const int idx = tid + 256 * m;
        const int ii = idx & 63, zz = idx >> 6;
        const int kg2 = zz & 3, ks2 = zz >> 2;
        const size_t off = (size_t)(i0g + ii) * 225280 +
                           (size_t)(240 + (ot - 12) * 10 + ks2) * 512 + (kg2 * 16 + lr) * 8;
        *reinterpret_cast<uint4*>(kall + off) = z;
      }
    }
    return;
  }

  const int lane = tid & 63, w = tid >> 6;
  const int lrow = lane & 15, kg = lane >> 4;
  ushort* Af = reinterpret_cast<ushort*>(smem + 9760);

  f32x4 acc[19];
#pragma unroll
  for (int ct = 0; ct < 19; ++ct) acc[ct] = (f32x4){0.f, 0.f, 0.f, 0.f};

  for (int hc = 0; hc < 4; ++hc) {
    __syncthreads();
    for (int m = 0; m < 10; ++m) {
      const int u = tid + 256 * m;
      if (u < 2432) {
        const int c = u >> 3, h4 = (u & 7) * 4;
        float4 wv = make_float4(0.f, 0.f, 0.f, 0.f);
        if (c < 300) wv = *reinterpret_cast<const float4*>(Wb + (size_t)c * 128 + hc * 32 + h4);
        smem[(h4 + 0) * 305 + c] = wv.x;
        smem[(h4 + 1) * 305 + c] = wv.y;
        smem[(h4 + 2) * 305 + c] = wv.z;
        smem[(h4 + 3) * 305 + c] = wv.w;
      }
    }
    __syncthreads();
    for (int m = 0; m < 5; ++m) {
      const int u = tid + 256 * m;
      if (u < 1216) {
        const int ln = u & 63, ct = u >> 6;
        const int cc = ct * 16 + (ln & 15);
        const int hb = (ln >> 4) * 8;
        ushort h8[8], l8[8];
#pragma unroll
        for (int e = 0; e < 8; ++e) {
          const float v = smem[(hb + e) * 305 + cc];
          const ushort hi = f2bf(v);
          h8[e] = hi;
          l8[e] = f2bf(v - bf2f(hi));
        }
        uint4 ph, pl4;
        ph.x = (uint)h8[0] | ((uint)h8[1] << 16);
        ph.y = (uint)h8[2] | ((uint)h8[3] << 16);
        ph.z = (uint)h8[4] | ((uint)h8[5] << 16);
        ph.w = (uint)h8[6] | ((uint)h8[7] << 16);
        pl4.x = (uint)l8[0] | ((uint)l8[1] << 16);
        pl4.y = (uint)l8[2] | ((uint)l8[3] << 16);
        pl4.z = (uint)l8[4] | ((uint)l8[5] << 16);
        pl4.w = (uint)l8[6] | ((uint)l8[7] << 16);
        *reinterpret_cast<uint4*>(&Af[(ct * 2 + 0) * 512 + ln * 8]) = ph;
        *reinterpret_cast<uint4*>(&Af[(ct * 2 + 1) * 512 + ln * 8]) = pl4;
      }
    }
    const bf16x8 Bh = *reinterpret_cast<const bf16x8*>(
        basP + (size_t)(half * 32 + w * 8 + hc * 2 + 0) * 512 + lane * 8);
    const bf16x8 Bl = *reinterpret_cast<const bf16x8*>(
        basP + (size_t)(half * 32 + w * 8 + hc * 2 + 1) * 512 + lane * 8);
    __syncthreads();
#pragma unroll
    for (int ct = 0; ct < 19; ++ct) {
      const bf16x8 Ah = *reinterpret_cast<const bf16x8*>(&Af[(ct * 2 + 0) * 512 + lane * 8]);
      const bf16x8 Al = *reinterpret_cast<const bf16x8*>(&Af[(ct * 2 + 1) * 512 + lane * 8]);
      acc[ct] = MFMA16(Ah, Bh, acc[ct]);
      acc[ct] = MFMA16(Ah, Bl, acc[ct]);
      acc[ct] = MFMA16(Al, Bh, acc[ct]);
    }
  }
  __syncthreads();
#pragma unroll
  for (int ct = 0; ct < 19; ++ct)
#pragma unroll
    for (int r = 0; r < 4; ++r) {
      const int c = ct * 16 + kg * 4 + r;
      if (c < 300) smem[c * 65 + w * 16 + lrow] = acc[ct][r] + bvec[c];
    }
  __syncthreads();
  {
    const int si = tid >> 2, p = tid & 3;
    float s1 = 0.f, s2 = 0.f;
    for (int c = p; c < 300; c += 4) {
      const float x = smem[c * 65 + si];
      s1 += x;
      s2 += x * x;
    }
    s1 += __shfl_xor(s1, 1); s2 += __shfl_xor(s2, 1);
    s1 += __shfl_xor(s1, 2); s2 += __shfl_xor(s2, 2);
    const float mu = s1 * (1.0f / 300.0f);
    const float var = s2 * (1.0f / 300.0f) - mu * mu;
    const float scale = bns / sqrtf(var + EPSB);
    if (p == 0) { scl[si] = scale; shf[si] = bnb - mu * scale; }
  }
  __syncthreads();
  if (!isV) {
    for (int m = 0; m < 20; ++m) {
      const int idx = tid + 256 * m;
      const int ii = idx & 63, zz = idx >> 6;
      const int kg2 = zz & 3, pl = (zz >> 2) & 1, ks2 = zz >> 3;
      const float sc = scl[ii], sh = shf[ii];
      ushort o8[8];
#pragma unroll
      for (int e = 0; e < 8; ++e) {
        const int c = ks2 * 32 + kg2 * 8 + e;
        float val = 0.f;
        if (c < 300) val = fmaf(smem[c * 65 + ii], sc, sh);
        const ushort hi = f2bf(val);
        o8[e] = pl ? f2bf(val - bf2f(hi)) : hi;
      }
      uint4 pk;
      pk.x = (uint)o8[0] | ((uint)o8[1] << 16);
      pk.y = (uint)o8[2] | ((uint)o8[3] << 16);
      pk.z = (uint)o8[4] | ((uint)o8[5] << 16);
      pk.w = (uint)o8[6] | ((uint)o8[7] << 16);
      const size_t off = (size_t)(i0g + ii) * 225280 +
                         (size_t)(ot * 20 + ks2 * 2 + pl) * 512 + (kg2 * 16 + lr) * 8;
      *reinterpret_cast<uint4*>(kall + off) = pk;
    }
  } else {
    for (int m = 0; m < 10; ++m) {
      const int idx = tid + 256 * m;
      const int ii = idx & 63, zz = idx >> 6;
      const int kg2 = zz & 3, ks2 = zz >> 2;
      const float sc = scl[ii], sh = shf[ii];
      ushort o8[8];
#pragma unroll
      for (int e = 0; e < 8; ++e) {
        const int c = ks2 * 32 + kg2 * 8 + e;
        float val = 0.f;
        if (c < 300) val = fmaf(smem[c * 65 + ii], sc, sh);
        o8[e] = f2bf(val);
      }
      uint4 pk;
      pk.x = (uint)o8[0] | ((uint)o8[1] << 16);
      pk.y = (uint)o8[2] | ((uint)o8[3] << 16);
      pk.z = (uint)o8[4] | ((uint)o8[5] << 16);
      pk.w = (uint)o8[6] | ((uint)o8[7] << 16);
      const size_t off = (size_t)(i0g + ii) * 225280 +
                         (size_t)(240 + (ot - 12) * 10 + ks2) * 512 + (kg2 * 16 + lr) * 8;
      *reinterpret_cast<uint4*>(kall + off) = pk;
    }
  }
}

// ---------------- K4: fused attention; vectorized epilogues (P3a operand-swapped) ----------------
__global__ void __launch_bounds__(256, 4) k_attn12(
    const float* __restrict__ cap, const ushort* __restrict__ kall,
    const ushort* __restrict__ capP, const float* __restrict__ ball,
    const float* __restrict__ gptr, float* __restrict__ x_all) {
  __shared__ ushort qkp[24 * 512];       // P1/P2: packed q (units 0-11) + k (12-23); P3: vt
  __shared__ float sc_s[32 * 36];        // fp32 scores [t][s]
  __shared__ ushort at_p[2 * 2 * 64 * 8];
  const int bid = blockIdx.x;
  const int xcd = bid & 7, q = bid >> 3;
  const int i = xcd * 16 + (q >> 6), n = q & 63;
  const int tid = threadIdx.x;
  const int lane = tid & 63, w = tid >> 6;
  const int lrow = lane & 15, kg = lane >> 4;
  const float gamma = gptr[0];
  const ushort* kpL = kall + (size_t)i * 225280 + lane * 8;
  const ushort* cpL = capP + (size_t)n * 20480 + lane * 8;
  const float* bal = ball + i * 512;
  const bool oddw = (w & 1);   // waves 1,3 own only 2 real tiles (tiles 5,11 are all-pad)

  // ---- P1: q+k tiles {0..4, 6..10}, wave w tiles {3w..}; 2-deep A-prefetch
  {
    f32x4 acc[3][2];
#pragma unroll
    for (int a = 0; a < 3; ++a)
#pragma unroll
      for (int b2 = 0; b2 < 2; ++b2) acc[a][b2] = (f32x4){0.f, 0.f, 0.f, 0.f};
    bf16x8 AhA[3], AlA[3], AhB[3], AlB[3];
#pragma unroll
    for (int mt = 0; mt < 3; ++mt)
      if (!oddw || mt < 2) {   // preload kstep 0
        const ushort* p = kpL + (size_t)((w * 3 + mt) * 20) * 512;
        AhA[mt] = *reinterpret_cast<const bf16x8*>(p);
        AlA[mt] = *reinterpret_cast<const bf16x8*>(p + 512);
      }
#pragma unroll
    for (int kp = 0; kp < 5; ++kp) {
      {  // even kstep 2kp
        const int ks = 2 * kp;
        bf16x8 Bh[2], Bl[2];
#pragma unroll
        for (int nt = 0; nt < 2; ++nt) {
          const ushort* p = cpL + (size_t)(nt * 20 + ks * 2) * 512;
          Bh[nt] = *reinterpret_cast<const bf16x8*>(p);
          Bl[nt] = *reinterpret_cast<const bf16x8*>(p + 512);
        }
#pragma unroll
        for (int mt = 0; mt < 3; ++mt)
          if (!oddw || mt < 2) {
            const ushort* p = kpL + (size_t)((w * 3 + mt) * 20 + (ks + 1) * 2) * 512;
            AhB[mt] = *reinterpret_cast<const bf16x8*>(p);
            AlB[mt] = *reinterpret_cast<const bf16x8*>(p + 512);
          }
#pragma unroll
        for (int mt = 0; mt < 3; ++mt)
          if (!oddw || mt < 2)
#pragma unroll
            for (int nt = 0; nt < 2; ++nt) {
              acc[mt][nt] = MFMA16(AhA[mt], Bh[nt], acc[mt][nt]);
              acc[mt][nt] = MFMA16(AhA[mt], Bl[nt], acc[mt][nt]);
              acc[mt][nt] = MFMA16(AlA[mt], Bh[nt], acc[mt][nt]);
            }
      }
      {  // odd kstep 2kp+1
        const int ks = 2 * kp + 1;
        bf16x8 Bh[2], Bl[2];
#pragma unroll
        for (int nt = 0; nt < 2; ++nt) {
          const ushort* p = cpL + (size_t)(nt * 20 + ks * 2) * 512;
          Bh[nt] = *reinterpret_cast<const bf16x8*>(p);
          Bl[nt] = *reinterpret_cast<const bf16x8*>(p + 512);
        }
        if (kp < 4) {
#pragma unroll
          for (int mt = 0; mt < 3; ++mt)
            if (!oddw || mt < 2) {
              const ushort* p = kpL + (size_t)((w * 3 + mt) * 20 + (ks + 1) * 2) * 512;
              AhA[mt] = *reinterpret_cast<const bf16x8*>(p);
              AlA[mt] = *reinterpret_cast<const bf16x8*>(p + 512);
            }
        }
#pragma unroll
        for (int mt = 0; mt < 3; ++mt)
          if (!oddw || mt < 2)
#pragma unroll
            for (int nt = 0; nt < 2; ++nt) {
              acc[mt][nt] = MFMA16(AhB[mt], Bh[nt], acc[mt][nt]);
              acc[mt][nt] = MFMA16(AhB[mt], Bl[nt], acc[mt][nt]);
              acc[mt][nt] = MFMA16(AlB[mt], Bh[nt], acc[mt][nt]);
            }
      }
    }
    // epilogue: q/k packed fragments; 4 r-values land at consecutive e -> uint2 hi/lo writes
    // (phantom tiles: acc=0, bal=0 -> exact zero fragments)
#pragma unroll
    for (int mt = 0; mt < 3; ++mt)
#pragma unroll
      for (int nt = 0; nt < 2; ++nt) {
        const int og0 = w * 48 + mt * 16 + kg * 4;     // r = 0
        const int os0 = (w < 2) ? og0 : og0 - 96;
        const int ub = ((w < 2) ? 0 : 12) + nt * 6 + (os0 >> 5) * 2;
        const int lp = ((os0 & 31) >> 3) * 16 + lrow;
        const int e0 = os0 & 7;                         // = (kg&1)*4
        ushort h4[4], l4[4];
#pragma unroll
        for (int r = 0; r < 4; ++r) {
          const float val = acc[mt][nt][r] + bal[og0 + r];
          const ushort hi = f2bf(val);
          h4[r] = hi;
          l4[r] = f2bf(val - bf2f(hi));
        }
        uint2 ph, pl2;
        ph.x = (uint)h4[0] | ((uint)h4[1] << 16);
        ph.y = (uint)h4[2] | ((uint)h4[3] << 16);
        pl2.x = (uint)l4[0] | ((uint)l4[1] << 16);
        pl2.y = (uint)l4[2] | ((uint)l4[3] << 16);
        *reinterpret_cast<uint2*>(&qkp[(ub + 0) * 512 + lp * 8 + e0]) = ph;
        *reinterpret_cast<uint2*>(&qkp[(ub + 1) * 512 + lp * 8 + e0]) = pl2;
      }
  }
  __syncthreads();

  // ---- P2a: scores via MFMA (4-pass split, K=96); wave w -> quadrant (tt,st)
  {
    const int tt = w >> 1, st = w & 1;
    bf16x8 Aq[3][2], Bk[3][2];
#pragma unroll
    for (int k3 = 0; k3 < 3; ++k3)
#pragma unroll
      for (int pl = 0; pl < 2; ++pl) {
        Aq[k3][pl] = *reinterpret_cast<const bf16x8*>(&qkp[(tt * 6 + k3 * 2 + pl) * 512 + lane * 8]);
        Bk[k3][pl] = *reinterpret_cast<const bf16x8*>(&qkp[(12 + st * 6 + k3 * 2 + pl) * 512 + lane * 8]);
      }
    f32x4 D = (f32x4){0.f, 0.f, 0.f, 0.f};
#pragma unroll
    for (int k3 = 0; k3 < 3; ++k3) {
      D = MFMA16(Aq[k3][0], Bk[k3][0], D);
      D = MFMA16(Aq[k3][0], Bk[k3][1], D);
      D = MFMA16(Aq[k3][1], Bk[k3][0], D);
      D = MFMA16(Aq[k3][1], Bk[k3][1], D);
    }
#pragma unroll
    for (int r = 0; r < 4; ++r)
      sc_s[(tt * 16 + kg * 4 + r) * 36 + st * 16 + lrow] = D[r];
  }
  __syncthreads();

  // ---- P2b: softmax (fp32) + pack attn to at_p (bf16 hi/lo, MFMA-B layout)
  {
    const int sg = tid & 7, tq = tid >> 3;
    const int s0 = sg * 4;
    const float4 sv = *reinterpret_cast<const float4*>(&sc_s[tq * 36 + s0]);
    float sc[4] = {sv.x, sv.y, sv.z, sv.w};
    float m = fmaxf(fmaxf(sc[0], sc[1]), fmaxf(sc[2], sc[3]));
    m = fmaxf(m, __shfl_xor(m, 1));
    m = fmaxf(m, __shfl_xor(m, 2));
    m = fmaxf(m, __shfl_xor(m, 4));
    float ev[4], ssum = 0.f;
#pragma unroll
    for (int u = 0; u < 4; ++u) { ev[u] = expf(sc[u] - m); ssum += ev[u]; }
    ssum += __shfl_xor(ssum, 1);
    ssum += __shfl_xor(ssum, 2);
    ssum += __shfl_xor(ssum, 4);
    const float inv = 1.0f / ssum;
    const int tt = tq >> 4, lrp = tq & 15, kgp = sg >> 1, eb = (sg & 1) * 4;
    ushort h4[4], l4[4];
#pragma unroll
    for (int u = 0; u < 4; ++u) {
      const float val = ev[u] * inv;
      const ushort hi = f2bf(val);
      h4[u] = hi;
      l4[u] = f2bf(val - bf2f(hi));
    }
    uint2 ph, pl2;
    ph.x = (uint)h4[0] | ((uint)h4[1] << 16);
    ph.y = (uint)h4[2] | ((uint)h4[3] << 16);
    pl2.x = (uint)l4[0] | ((uint)l4[1] << 16);
    pl2.y = (uint)l4[2] | ((uint)l4[3] << 16);
    *reinterpret_cast<uint2*>(&at_p[((tt * 2 + 0) * 64 + kgp * 16 + lrp) * 8 + eb]) = ph;
    *reinterpret_cast<uint2*>(&at_p[((tt * 2 + 1) * 64 + kgp * 16 + lrp) * 8 + eb]) = pl2;
  }
  __syncthreads();

  // ---- P3: v tiles [12,32) in 2 chunks; SWAPPED proj (A=cap, B=v) -> D[t][c] -> vectorized vt writes
  ushort* vt = qkp;
#pragma unroll
  for (int ch = 0; ch < 2; ++ch) {
    const int TB = 12 + ch * 12;
    const int RB = TB * 16;
    const int nmt = ch ? 2 : 3;
    f32x4 vacc[3][2];
#pragma unroll
    for (int a = 0; a < 3; ++a)
#pragma unroll
      for (int b2 = 0; b2 < 2; ++b2) vacc[a][b2] = (f32x4){0.f, 0.f, 0.f, 0.f};
    bf16x8 AvA[3], AvB[3];
    for (int mi = 0; mi < nmt; ++mi)   // preload kstep 0
      AvA[mi] = *reinterpret_cast<const bf16x8*>(
          kpL + (size_t)(240 + (TB - 12 + w + mi * 4) * 10) * 512);
#pragma unroll
    for (int kp = 0; kp < 5; ++kp) {
      {  // even ks=2kp
        const int ks = 2 * kp;
        bf16x8 Ch[2];
#pragma unroll
        for (int nt = 0; nt < 2; ++nt)
          Ch[nt] = *reinterpret_cast<const bf16x8*>(cpL + (size_t)(nt * 20 + ks * 2) * 512);
        for (int mi = 0; mi < nmt; ++mi)
          AvB[mi] = *reinterpret_cast<const bf16x8*>(
              kpL + (size_t)(240 + (TB - 12 + w + mi * 4) * 10 + ks + 1) * 512);
        for (int mi = 0; mi < nmt; ++mi)
#pragma unroll
          for (int nt = 0; nt < 2; ++nt)
            vacc[mi][nt] = MFMA16(Ch[nt], AvA[mi], vacc[mi][nt]);
      }
      {  // odd ks=2kp+1
        const int ks = 2 * kp + 1;
        bf16x8 Ch[2];
#pragma unroll
        for (int nt = 0; nt < 2; ++nt)
          Ch[nt] = *reinterpret_cast<const bf16x8*>(cpL + (size_t)(nt * 20 + ks * 2) * 512);
        if (kp < 4) {
          for (int mi = 0; mi < nmt; ++mi)
            AvA[mi] = *reinterpret_cast<const bf16x8*>(
                kpL + (size_t)(240 + (TB - 12 + w + mi * 4) * 10 + ks + 1) * 512);
        }
        for (int mi = 0; mi < nmt; ++mi)
#pragma unroll
          for (int nt = 0; nt < 2; ++nt)
            vacc[mi][nt] = MFMA16(Ch[nt], AvB[mi], vacc[mi][nt]);
      }
    }
    if (ch) __syncthreads();   // prior P3b readers of vt done
    // epilogue: D[t][c]: lane holds c = lrow (fixed), t = nt*16 + kg*4 + r -> contiguous e
    for (int mi = 0; mi < nmt; ++mi) {
      const int tile = w + mi * 4;
      const float bb = bal[RB + tile * 16 + lrow];
#pragma unroll
      for (int nt = 0; nt < 2; ++nt) {
        const int lpv = (nt * 2 + (kg >> 1)) * 16 + lrow;
        const int e0v = (kg & 1) * 4;
        ushort h4[4], l4[4];
#pragma unroll
        for (int r = 0; r < 4; ++r) {
          const float val = vacc[mi][nt][r] + bb;
          const ushort hi = f2bf(val);
          h4[r] = hi;
          l4[r] = f2bf(val - bf2f(hi));
        }
        uint2 ph, pl2;
        ph.x = (uint)h4[0] | ((uint)h4[1] << 16);
        ph.y = (uint)h4[2] | ((uint)h4[3] << 16);
        pl2.x = (uint)l4[0] | ((uint)l4[1] << 16);
        pl2.y = (uint)l4[2] | ((uint)l4[3] << 16);
        *reinterpret_cast<uint2*>(&vt[((tile * 2 + 0) * 64 + lpv) * 8 + e0v]) = ph;
        *reinterpret_cast<uint2*>(&vt[((tile * 2 + 1) * 64 + lpv) * 8 + e0v]) = pl2;
      }
    }
    __syncthreads();
    {  // P3b: MFMA PV + residual + max
      bf16x8 ah[2], al[2];
#pragma unroll
      for (int tt = 0; tt < 2; ++tt) {
        ah[tt] = *reinterpret_cast<const bf16x8*>(&at_p[((tt * 2 + 0) * 64 + lane) * 8]);
        al[tt] = *reinterpret_cast<const bf16x8*>(&at_p[((tt * 2 + 1) * 64 + lane) * 8]);
      }
      const int npw = ch ? 2 : 3;
      for (int j = 0; j < npw; ++j) {
        const int ct = w * npw + j;
        const int c0 = ch * 192 + ct * 16 + (lane >> 4) * 4;
        const bf16x8 vh  = *reinterpret_cast<const bf16x8*>(&vt[((ct * 2 + 0) * 64 + lane) * 8]);
        const bf16x8 vl8 = *reinterpret_cast<const bf16x8*>(&vt[((ct * 2 + 1) * 64 + lane) * 8]);
        f32x4 a0 = (f32x4){0.f, 0.f, 0.f, 0.f}, a1 = (f32x4){0.f, 0.f, 0.f, 0.f};
        a0 = MFMA16(vh, ah[0], a0);
        a0 = MFMA16(vh, al[0], a0);
        a0 = MFMA16(vl8, ah[0], a0);
        a1 = MFMA16(vh, ah[1], a1);
        a1 = MFMA16(vh, al[1], a1);
        a1 = MFMA16(vl8, ah[1], a1);
        if (c0 < 300) {
          const int t0 = lane & 15;
          const float4 c4a = *reinterpret_cast<const float4*>(&cap[(size_t)n * 9600 + t0 * 300 + c0]);
          const float4 c4b = *reinterpret_cast<const float4*>(&cap[(size_t)n * 9600 + (t0 + 16) * 300 + c0]);
          float mx[4];
          mx[0] = fmaxf(fmaf(gamma, a0[0], c4a.x), fmaf(gamma, a1[0], c4b.x));
          mx[1] = fmaxf(fmaf(gamma, a0[1], c4a.y), fmaf(gamma, a1[1], c4b.y));
          mx[2] = fmaxf(fmaf(gamma, a0[2], c4a.z), fmaf(gamma, a1[2], c4b.z));
          mx[3] = fmaxf(fmaf(gamma, a0[3], c4a.w), fmaf(gamma, a1[3], c4b.w));
#pragma unroll
          for (int mmask = 1; mmask < 16; mmask <<= 1)
#pragma unroll
            for (int r = 0; r < 4; ++r) mx[r] = fmaxf(mx[r], __shfl_xor(mx[r], mmask));
          if ((lane & 15) == 0)
            *reinterpret_cast<float4*>(&x_all[((size_t)i * 64 + n) * 300 + c0]) =
                make_float4(mx[0], mx[1], mx[2], mx[3]);
        }
      }
    }
  }
}

// ---------------- K5a: h1 = relu(BN1(x @ W1^T + b1)) — BN1 fused ----------------
__global__ void __launch_bounds__(256, 4) k_h1b(
    const float* __restrict__ x_all, const float* __restrict__ W1,
    const float* __restrict__ b1, const float* __restrict__ bn1s,
    const float* __restrict__ bn1b, float* __restrict__ h1) {
  __shared__ float xt[32 * 68];
  __shared__ float wt[32 * 132];
  __shared__ float sc1[128], sh1[128];
  const int ec = blockIdx.x, i = blockIdx.y, tid = threadIdx.x;
  const int e0c = ec * 128;
  const int eg = tid & 15, ng = tid >> 4;
  const int e0 = eg * 8, n0 = ng * 4;
  float acc[4][8] = {};
  for (int cb = 0; cb < 10; ++cb) {
    const int c0 = cb * 32;
    __syncthreads();
    for (int k = 0; k < 8; ++k) {
      const int idx = tid + 256 * k;
      const int nn = idx >> 5, cl = idx & 31;
      const int c = c0 + cl;
      xt[cl * 68 + nn] = (c < 300) ? x_all[((size_t)i * 64 + nn) * 300 + c] : 0.0f;
    }
    for (int k = 0; k < 16; ++k) {
      const int idx = tid + 256 * k;
      const int ee = idx >> 5, cl = idx & 31;
      const int c = c0 + cl;
      wt[cl * 132 + ee] = (c < 300) ? W1[(size_t)(e0c + ee) * 300 + c] : 0.0f;
    }
    __syncthreads();
#pragma unroll 4
    for (int cl = 0; cl < 32; ++cl) {
      const float4 xv = *reinterpret_cast<const float4*>(&xt[cl * 68 + n0]);
      const float4 wa = *reinterpret_cast<const float4*>(&wt[cl * 132 + e0]);
      const float4 wb = *reinterpret_cast<const float4*>(&wt[cl * 132 + e0 + 4]);
      const float xv4[4] = {xv.x, xv.y, xv.z, xv.w};
      const float wv8[8] = {wa.x, wa.y, wa.z, wa.w, wb.x, wb.y, wb.z, wb.w};
#pragma unroll
      for (int u = 0; u < 4; ++u)
#pragma unroll
        for (int v = 0; v < 8; ++v) acc[u][v] = fmaf(xv4[u], wv8[v], acc[u][v]);
    }
  }
  float b1v[8];
#pragma unroll
  for (int v = 0; v < 8; ++v) b1v[v] = b1[e0c + e0 + v];
  float val[4][8];
#pragma unroll
  for (int u = 0; u < 4; ++u)
#pragma unroll
    for (int v = 0; v < 8; ++v) val[u][v] = acc[u][v] + b1v[v];
  __syncthreads();
  float* ps1 = xt;   // [16][132]
  float* ps2 = wt;   // [16][132]
#pragma unroll
  for (int v = 0; v < 8; ++v) {
    float su = 0.f, sq = 0.f;
#pragma unroll
    for (int u = 0; u < 4; ++u) { su += val[u][v]; sq += val[u][v] * val[u][v]; }
    ps1[ng * 132 + e0 + v] = su;
    ps2[ng * 132 + e0 + v] = sq;
  }
  __syncthreads();
  if (tid < 128) {
    const int e = tid;
    float s1 = 0.f, s2 = 0.f;
#pragma unroll 4
    for (int gq = 0; gq < 16; ++gq) { s1 += ps1[gq * 132 + e]; s2 += ps2[gq * 132 + e]; }
    const float mu = s1 * (1.0f / 64.0f);
    const float var = s2 * (1.0f / 64.0f) - mu * mu;
    const float scale = bn1s[e0c + e] / sqrtf(var + EPSB);
    sc1[e] = scale;
    sh1[e] = bn1b[e0c + e] - mu * scale;
  }
  __syncthreads();
#pragma unroll
  for (int u = 0; u < 4; ++u) {
    float o8[8];
#pragma unroll
    for (int v = 0; v < 8; ++v)
      o8[v] = fmaxf(fmaf(val[u][v], sc1[e0 + v], sh1[e0 + v]), 0.0f);
    float* dst = h1 + ((size_t)i * 64 + n0 + u) * 512 + e0c + e0;
    *reinterpret_cast<float4*>(dst) = make_float4(o8[0], o8[1], o8[2], o8[3]);
    *reinterpret_cast<float4*>(dst + 4) = make_float4(o8[4], o8[5], o8[6], o8[7]);
  }
}

// ---------------- K5b: h2 = h1 @ W2^T + b2 ----------------
__global__ void __launch_bounds__(256) k_h2(
    const float* __restrict__ h1, const float* __restrict__ W2,
    const float* __restrict__ b2, float* __restrict__ h2buf) {
  __shared__ float h1s[32 * 517];
  const int jn = blockIdx.x, i = blockIdx.y, tid = threadIdx.x;
  const int bn = jn * 32;
  for (int m = 0; m < 64; ++m) {
    const int idx = tid + 256 * m;   // 16384
    h1s[(idx >> 9) * 517 + (idx & 511)] = h1[((size_t)i * 64 + bn) * 512 + idx];
  }
  __syncthreads();
  const int dg = tid & 15, ng2 = tid >> 4;
  const int d0 = dg * 4, n0 = ng2 * 2;
  float a0[4] = {}, a1[4] = {};
#pragma unroll 4
  for (int e = 0; e < 512; ++e) {
    const float h0 = h1s[n0 * 517 + e];
    const float h1v = h1s[(n0 + 1) * 517 + e];
#pragma unroll
    for (int v = 0; v < 4; ++v) {
      const float wv = W2[(size_t)(d0 + v) * 512 + e];
      a0[v] = fmaf(h0, wv, a0[v]);
      a1[v] = fmaf(h1v, wv, a1[v]);
    }
  }
  const float4 bb = *reinterpret_cast<const float4*>(&b2[d0]);
  float* dst0 = h2buf + ((size_t)i * 64 + bn + n0) * 64 + d0;
  *reinterpret_cast<float4*>(dst0) = make_float4(a0[0] + bb.x, a0[1] + bb.y, a0[2] + bb.z, a0[3] + bb.w);
  *reinterpret_cast<float4*>(dst0 + 64) = make_float4(a1[0] + bb.x, a1[1] + bb.y, a1[2] + bb.z, a1[3] + bb.w);
}

// ---------------- K5c: BN2 + relu + W3 dot -> out ----------------
__global__ void __launch_bounds__(256) k_out(
    const float* __restrict__ h2buf, const float* __restrict__ bn2s,
    const float* __restrict__ bn2b, const float* __restrict__ W3,
    const float* __restrict__ b3, float* __restrict__ out) {
  __shared__ float h2s[64 * 65];
  const int i = blockIdx.x, tid = threadIdx.x;
  for (int m = 0; m < 16; ++m) {
    const int idx = tid + 256 * m;   // 4096
    h2s[(idx >> 6) * 65 + (idx & 63)] = h2buf[(size_t)i * 4096 + idx];
  }
  __syncthreads();
  if (tid < 64) {
    const int d = tid;
    float s1 = 0.f, s2 = 0.f;
    for (int nn = 0; nn < 64; ++nn) {
      const float v = h2s[nn * 65 + d];
      s1 += v;
      s2 += v * v;
    }
    const float mu = s1 * (1.0f / 64.0f);
    const float var = s2 * (1.0f / 64.0f) - mu * mu;
    const float scale = bn2s[d] / sqrtf(var + EPSB);
    const float shift = bn2b[d] - mu * scale;
    for (int nn = 0; nn < 64; ++nn)
      h2s[nn * 65 + d] = fmaxf(fmaf(h2s[nn * 65 + d], scale, shift), 0.0f);
  }
  __syncthreads();
  if (tid < 64) {
    const int nn = tid;
    float acc = b3[0];
    for (int d = 0; d < 64; ++d) acc = fmaf(h2s[nn * 65 + d], W3[d], acc);
    out[i * 64 + nn] = acc;
  }
}

extern "C" void kernel_launch(void* const* d_in, const int* in_sizes, int n_in,
                              void* d_out, int out_size, void* d_ws, size_t ws_size,
                              hipStream_t stream) {
  const float* img  = (const float*)d_in[0];
  const float* cap  = (const float*)d_in[1];
  const float* adW  = (const float*)d_in[2];
  const float* adb  = (const float*)d_in[3];
  const float* qkW  = (const float*)d_in[4];
  const float* qkb  = (const float*)d_in[5];
  const float* qbW  = (const float*)d_in[6];
  const float* qbb  = (const float*)d_in[7];
  const float* qbns = (const float*)d_in[8];
  const float* qbnb = (const float*)d_in[9];
  const float* kkW  = (const float*)d_in[10];
  const float* kkb  = (const float*)d_in[11];
  const float* kbW  = (const float*)d_in[12];
  const float* kbb  = (const float*)d_in[13];
  const float* kbns = (const float*)d_in[14];
  const float* kbnb = (const float*)d_in[15];
  const float* vkW  = (const float*)d_in[16];
  const float* vkb  = (const float*)d_in[17];
  const float* vbW  = (const float*)d_in[18];
  const float* vbb  = (const float*)d_in[19];
  const float* vbns = (const float*)d_in[20];
  const float* vbnb = (const float*)d_in[21];
  const float* gamma= (const float*)d_in[22];
  const float* W1   = (const float*)d_in[23];
  const float* b1   = (const float*)d_in[24];
  const float* bn1s = (const float*)d_in[25];
  const float* bn1b = (const float*)d_in[26];
  const float* W2   = (const float*)d_in[27];
  const float* b2   = (const float*)d_in[28];
  const float* bn2s = (const float*)d_in[29];
  const float* bn2b = (const float*)d_in[30];
  const float* W3   = (const float*)d_in[31];
  const float* b3   = (const float*)d_in[32];

  float* ws    = (float*)d_ws;
  float* base  = ws + OFS_BASE;
  float* ball  = ws + OFS_BALL;
  ushort* capP = (ushort*)(ws + OFS_CAPB);
  ushort* kall = (ushort*)(ws + OFS_RAWP);
  float* x_all = ws + OFS_X;
  float* h2buf = ws + OFS_H2;
  ushort* basP = (ushort*)(ws + OFS_BASP);
  float* h1    = ws + OFS_H1;    // aliases kall (dead after k_attn12)
  float* out   = (float*)d_out;

  k_mb<<<128, 256, 0, stream>>>(img, adW, adb, base);
  k_prep<<<322, 256, 0, stream>>>(qbW, qbb, kbW, kbb, vbW, vbb, base, ball, cap, capP, basP);
  k_hyp4<<<dim3(512, 2), 256, 0, stream>>>(qkW, qkb, kkW, kkb, vkW, vkb,
                                           qbns, qbnb, kbns, kbnb, vbns, vbnb, basP, kall);
  k_attn12<<<8192, 256, 0, stream>>>(cap, kall, capP, ball, gamma, x_all);
  k_h1b<<<dim3(4, 128), 256, 0, stream>>>(x_all, W1, b1, bn1s, bn1b, h1);
  k_h2<<<dim3(2, 128), 256, 0, stream>>>(h1, W2, b2, h2buf);
  k_out<<<128, 256, 0, stream>>>(h2buf, bn2s, bn2b, W3, b3, out);
}

// Round 13
// 469.711 us; speedup vs baseline: 1.5369x; 1.0346x over previous
//
#include <hip/hip_runtime.h>
#include <math.h>

#define EPSB 1e-5f

// Bi=128 Bc=64 T=32 C=300 OQK=75 H=128 LAT=1024
// Padded stacked o-dim (512): q [0,96) (75 real), k [96,192) (75 real), v [192,512) (300 real)
// Compact packed kall (per image, ushort): q/k tiles ot 0..11: units ot*20+ks*2+pl (hi+lo);
//   v tiles ot 12..31: units 240+(ot-12)*10+ks (hi only). 440 units x 512 ushort = 225280 ushort/img.
// Unit layout: [lane=64][8] ushort; element (o=16*ot+lr, c=32*ks+8*kg+e), lane=kg*16+lr.
// NOTE: o-tiles 5 and 11 are ALL-PAD; k_attn skips them (bit-exact) and k_hyp5 never writes them.
// ws layout (float offsets):
static const long OFS_BASE  = 0;                      // 128*128
static const long OFS_BALL  = 16384;                  // 128*512
static const long OFS_CAPB  = 212992;                 // capP: 64*20480 ushort = 655360 floats
static const long OFS_RAWP  = 868352;                 // kall: 128*225280 ushort = 14,417,920 floats
static const long OFS_X     = 15286272;               // 128*64*300
static const long OFS_H2    = 17743872;               // 128*64*64
static const long OFS_BASP  = 18268160;               // basP: 2*32*512 ushort = 16384 floats
static const long OFS_H1    = OFS_RAWP;               // alias (kall dead after k_attn12)

using bf16x8 = __attribute__((ext_vector_type(8))) __bf16;
using f32x4  = __attribute__((ext_vector_type(4))) float;
#define MFMA16(a, b, c) __builtin_amdgcn_mfma_f32_16x16x32_bf16(a, b, c, 0, 0, 0)

// Native RNE bf16 conversion (bit-identical to manual round-to-nearest-even;
// compiler emits v_cvt_*bf16* which is faster than the manual 5-op sequence).
__device__ inline ushort f2bf(float f) {
  const __bf16 h = (__bf16)f;
  return __builtin_bit_cast(ushort, h);
}
__device__ inline float bf2f(ushort h) { return __uint_as_float(((unsigned)h) << 16); }

// ---------------- K1: fused img_mean + base GEMM (one block per image) ----------------
__global__ void __launch_bounds__(256) k_mb(const float* __restrict__ img,
                                            const float* __restrict__ W,
                                            const float* __restrict__ b,
                                            float* __restrict__ base) {
  __shared__ float m_s[1024];
  __shared__ float part[128];
  const int i = blockIdx.x, tid = threadIdx.x;
#pragma unroll
  for (int lc = 0; lc < 4; ++lc) {
    const int l = lc * 256 + tid;
    const float* p = img + (size_t)i * 36864 + l;
    float s = 0.f;
#pragma unroll
    for (int r = 0; r < 36; ++r) s += p[r * 1024];
    m_s[l] = s * (1.0f / 36.0f);
  }
  __syncthreads();
  const int o = tid & 127, hk = tid >> 7;
  const float* wr = W + (size_t)o * 1024 + hk * 512;
  const float* ms = m_s + hk * 512;
  float acc = 0.f;
#pragma unroll 4
  for (int l = 0; l < 512; ++l) acc = fmaf(ms[l], wr[l], acc);
  if (hk) part[o] = acc;
  __syncthreads();
  if (!hk) base[i * 128 + o] = acc + part[o] + b[o];
}

// ---------------- K2: fused prep — bias (bid<256) | capP pack (bid<320) | basP pack ----------------
__global__ void __launch_bounds__(256) k_prep(
    const float* __restrict__ qbW, const float* __restrict__ qbb,
    const float* __restrict__ kbW, const float* __restrict__ kbb,
    const float* __restrict__ vbW, const float* __restrict__ vbb,
    const float* __restrict__ base, float* __restrict__ ball,
    const float* __restrict__ cap, ushort* __restrict__ capP,
    ushort* __restrict__ basP) {
  __shared__ float shm[32 * 301];
  const int bid = blockIdx.x, tid = threadIdx.x;
  if (bid < 256) {                     // ---- bias: ball[i][512]
    const int i = bid >> 1;
    if (tid < 128) shm[tid] = base[i * 128 + tid];
    __syncthreads();
    const int o = (bid & 1) * 256 + tid;
    const float* Wr = nullptr;
    float bb = 0.0f;
    if (o < 75)                   { Wr = qbW + (size_t)o * 128;         bb = qbb[o]; }
    else if (o >= 96 && o < 171)  { Wr = kbW + (size_t)(o - 96) * 128;  bb = kbb[o - 96]; }
    else if (o >= 192 && o < 492) { Wr = vbW + (size_t)(o - 192) * 128; bb = vbb[o - 192]; }
    float acc = 0.0f;
    if (Wr) {
#pragma unroll 4
      for (int h = 0; h < 128; ++h) acc = fmaf(Wr[h], shm[h], acc);
      acc += bb;
    }
    ball[i * 512 + o] = acc;
  } else if (bid < 320) {              // ---- capP pack
    const int n = bid - 256;
    const float* capn = cap + (size_t)n * 9600;
    {
      const int r = tid >> 3, c8 = tid & 7;
      for (int m = 0; m < 38; ++m) {
        const int c = c8 + 8 * m;
        if (c < 300) shm[r * 301 + c] = capn[r * 300 + c];
      }
    }
    __syncthreads();
    ushort* dst = capP + (size_t)n * 20480;
    for (int u = 0; u < 10; ++u) {
      const int ul = tid + 256 * u;
      const int unit = ul >> 6, lane = ul & 63;
      const int nt = unit / 20, rem = unit % 20;
      const int ks = rem >> 1, pl = rem & 1;
      const int kg = lane >> 4, lr = lane & 15;
      const int t = nt * 16 + lr;
      ushort o8[8];
#pragma unroll
      for (int e = 0; e < 8; ++e) {
        const int c = 32 * ks + 8 * kg + e;
        const float val = (c < 300) ? shm[t * 301 + c] : 0.f;
        const ushort hi = f2bf(val);
        o8[e] = pl ? f2bf(val - bf2f(hi)) : hi;
      }
      uint4 pk;
      pk.x = (uint)o8[0] | ((uint)o8[1] << 16);
      pk.y = (uint)o8[2] | ((uint)o8[3] << 16);
      pk.z = (uint)o8[4] | ((uint)o8[5] << 16);
      pk.w = (uint)o8[6] | ((uint)o8[7] << 16);
      *reinterpret_cast<uint4*>(dst + unit * 512 + lane * 8) = pk;
    }
  } else {                             // ---- basP pack
    const int half = bid - 320;
    for (int m = 0; m < 8; ++m) {
      const int u = tid + 256 * m;
      const int ln = u & 63, unit = u >> 6;
      const int it = unit >> 3, ks = (unit >> 1) & 3, pl = unit & 1;
      const int i = half * 64 + it * 16 + (ln & 15);
      const int h = ks * 32 + (ln >> 4) * 8;
      ushort o8[8];
#pragma unroll
      for (int e = 0; e < 8; ++e) {
        const float v = base[(size_t)i * 128 + h + e];
        const ushort hi = f2bf(v);
        o8[e] = pl ? f2bf(v - bf2f(hi)) : hi;
      }
      uint4 pk;
      pk.x = (uint)o8[0] | ((uint)o8[1] << 16);
      pk.y = (uint)o8[2] | ((uint)o8[3] << 16);
      pk.z = (uint)o8[4] | ((uint)o8[5] << 16);
      pk.w = (uint)o8[6] | ((uint)o8[7] << 16);
      *reinterpret_cast<uint4*>(basP + (size_t)(half * 32 + unit) * 512 + ln * 8) = pk;
    }
  }
}

// ---------------- K3: MFMA hypernet GEMM, direct-register A + row-BN + pack -> compact kall ----------------
// Wave w owns c-tiles [5w, 5w+5) (w=3: 4 tiles) x ALL 4 i-tiles. A loaded straight from W
// (each lane: 32B contiguous), split to bf16 hi/lo in registers, MFMA'd immediately.
// No A-staging LDS, 2 barriers total. outF/BN/pack stages identical to verified k_hyp4.
__global__ void __launch_bounds__(256) k_hyp5(
    const float* __restrict__ qkW, const float* __restrict__ qkb,
    const float* __restrict__ kkW, const float* __restrict__ kkb,
    const float* __restrict__ vkW, const float* __restrict__ vkb,
    const float* __restrict__ qs, const float* __restrict__ qb,
    const float* __restrict__ ks_, const float* __restrict__ kb_,
    const float* __restrict__ vs, const float* __restrict__ vb,
    const ushort* __restrict__ basP, ushort* __restrict__ kall) {
  __shared__ float smem[19500];   // outF [300][65]
  __shared__ float scl[64], shf[64];
  const int g = blockIdx.x, half = blockIdx.y, tid = threadIdx.x;
  const int i0g = half * 64;
  const int ot = g >> 4, lr = g & 15;
  const bool isV = (g >= 192);
  if ((g >= 80 && g < 96) || (g >= 176 && g < 192)) return;   // never-read tiles

  const float* Wb = nullptr;
  const float* bvec = nullptr;
  float bns = 0.f, bnb = 0.f;
  if (g < 75)                    { Wb = qkW + (size_t)g * 38400;          bvec = qkb + g * 300;          bns = qs[g];        bnb = qb[g]; }
  else if (g >= 96 && g < 171)   { Wb = kkW + (size_t)(g - 96) * 38400;   bvec = kkb + (g - 96) * 300;   bns = ks_[g - 96];  bnb = kb_[g - 96]; }
  else if (g >= 192 && g < 492)  { Wb = vkW + (size_t)(g - 192) * 38400;  bvec = vkb + (g - 192) * 300;  bns = vs[g - 192];  bnb = vb[g - 192]; }

  if (!Wb) {  // pad rows within read tiles: exact zeros
    const uint4 z = make_uint4(0, 0, 0, 0);
    if (!isV) {
      for (int m = 0; m < 20; ++m) {
        const int idx = tid + 256 * m;
        const int ii = idx & 63, zz = idx >> 6;
        const int kg2 = zz & 3, pl = (zz >> 2) & 1, ks2 = zz >> 3;
        const size_t off = (size_t)(i0g + ii) * 225280 +
                           (size_t)(ot * 20 + ks2 * 2 + pl) * 512 + (kg2 * 16 + lr) * 8;
        *reinterpret_cast<uint4*>(kall + off) = z;
      }
    } else {
      for (int m = 0; m < 10; ++m) {
        const int idx = tid + 256 * m;
        const int ii = idx & 63, zz = idx >> 6;
        const int kg2 = zz & 3, ks2 = zz >> 2;
        const size_t off = (size_t)(i0g + ii) * 225280 +
                           (size_t)(240 + (ot - 12) * 10 + ks2) * 512 + (kg2 * 16 + lr) * 8;
        *reinterpret_cast<uint4*>(kall + off) = z;
      }
    }
    return;
  }

  const int lane = tid & 63, w = tid >> 6;
  const int lrow = lane & 15, kg = lane >> 4;
  const int CT0 = w * 5;                 // wave's first c-tile (w=3 -> 15..18)

  f32x4 acc[5][4];
#pragma unroll
  for (int t = 0; t < 5; ++t)
#pragma unroll
    for (int it = 0; it < 4; ++it) acc[t][it] = (f32x4){0.f, 0.f, 0.f, 0.f};

#pragma unroll
  for (int hc = 0; hc < 4; ++hc) {
    bf16x8 Bh[4], Bl[4];
#pragma unroll
    for (int it = 0; it < 4; ++it) {
      Bh[it] = *reinterpret_cast<const bf16x8*>(
          basP + (size_t)(half * 32 + it * 8 + hc * 2 + 0) * 512 + lane * 8);
      Bl[it] = *reinterpret_cast<const bf16x8*>(
          basP + (size_t)(half * 32 + it * 8 + hc * 2 + 1) * 512 + lane * 8);
    }
#pragma unroll
    for (int t = 0; t < 5; ++t) {
      const int ct = CT0 + t;
      if (ct < 19) {
        const int c = ct * 16 + lrow;
        float wv[8];
        if (c < 300) {
          const float4 w0 = *reinterpret_cast<const float4*>(Wb + (size_t)c * 128 + hc * 32 + kg * 8);
          const float4 w1 = *reinterpret_cast<const float4*>(Wb + (size_t)c * 128 + hc * 32 + kg * 8 + 4);
          wv[0] = w0.x; wv[1] = w0.y; wv[2] = w0.z; wv[3] = w0.w;
          wv[4] = w1.x; wv[5] = w1.y; wv[6] = w1.z; wv[7] = w1.w;
        } else {
#pragma unroll
          for (int e = 0; e < 8; ++e) wv[e] = 0.f;
        }
        bf16x8 Ah, Al;
#pragma unroll
        for (int e = 0; e < 8; ++e) {
          const __bf16 h = (__bf16)wv[e];
          Ah[e] = h;
          Al[e] = (__bf16)(wv[e] - (float)h);
        }
#pragma unroll
        for (int it = 0; it < 4; ++it) {
          acc[t][it] = MFMA16(Ah, Bh[it], acc[t][it]);
          acc[t][it] = MFMA16(Ah, Bl[it], acc[t][it]);
          acc[t][it] = MFMA16(Al, Bh[it], acc[t][it]);
        }
      }
    }
  }
  // epilogue: outF[c][i] (+ hypernet bias); D: col=lane&15 -> i-within-tile, row=kg*4+r -> c-within-tile
#pragma unroll
  for (int t = 0; t < 5; ++t) {
    const int ct = CT0 + t;
    if (ct < 19) {
#pragma unroll
      for (int r = 0; r < 4; ++r) {
        const int c = ct * 16 + kg * 4 + r;
        if (c < 300) {
          const float bv = bvec[c];
#pragma unroll
          for (int it = 0; it < 4; ++it)
            smem[c * 65 + it * 16 + lrow] = acc[t][it][r] + bv;
        }
      }
    }
  }
  __syncthreads();
  {  // BN stats per i over c<300 (verified code, stride 65)
    const int si = tid >> 2, p = tid & 3;
    float s1 = 0.f, s2 = 0.f;
    for (int c = p; c < 300; c += 4) {
      const float x = smem[c * 65 + si];
      s1 += x;
      s2 += x * x;
    }
    s1 += __shfl_xor(s1, 1); s2 += __shfl_xor(s2, 1);
    s1 += __shfl_xor(s1, 2); s2 += __shfl_xor(s2, 2);
    const float mu = s1 * (1.0f / 300.0f);
    const float var = s2 * (1.0f / 300.0f) - mu * mu;
    const float scale = bns / sqrtf(var + EPSB);
    if (p == 0) { scl[si] = scale; shf[si] = bnb - mu * scale; }
  }
  __syncthreads();
  if (!isV) {  // q/k: hi + lo planes
    for (int m = 0; m < 20; ++m) {
      const int idx = tid + 256 * m;
      const int ii = idx & 63, zz = idx >> 6;
      const int kg2 = zz & 3, pl = (zz >> 2) & 1, ks2 = zz >> 3;
      const float sc = scl[ii], sh = shf[ii];
      ushort o8[8];
#pragma unroll
      for (int e = 0; e < 8; ++e) {
        const int c = ks2 * 32 + kg2 * 8 + e;
        float val = 0.f;
        if (c < 300) val = fmaf(smem[c * 65 + ii], sc, sh);
        const ushort hi = f2bf(val);
        o8[e] = pl ? f2bf(val - bf2f(hi)) : hi;
      }
      uint4 pk;
      pk.x = (uint)o8[0] | ((uint)o8[1] << 16);
      pk.y = (uint)o8[2] | ((uint)o8[3] << 16);
      pk.z = (uint)o8[4] | ((uint)o8[5] << 16);
      pk.w = (uint)o8[6] | ((uint)o8[7] << 16);
      const size_t off = (size_t)(i0g + ii) * 225280 +
                         (size_t)(ot * 20 + ks2 * 2 + pl) * 512 + (kg2 * 16 + lr) * 8;
      *reinterpret_cast<uint4*>(kall + off) = pk;
    }
  } else {     // v: hi plane only
    for (int m = 0; m < 10; ++m) {
      const int idx = tid + 256 * m;
      const int ii = idx & 63, zz = idx >> 6;
      const int kg2 = zz & 3, ks2 = zz >> 2;
      const float sc = scl[ii], sh = shf[ii];
      ushort o8[8];
#pragma unroll
      for (int e = 0; e < 8; ++e) {
        const int c = ks2 * 32 + kg2 * 8 + e;
        float val = 0.f;
        if (c < 300) val = fmaf(smem[c * 65 + ii], sc, sh);
        o8[e] = f2bf(val);
      }
      uint4 pk;
      pk.x = (uint)o8[0] | ((uint)o8[1] << 16);
      pk.y = (uint)o8[2] | ((uint)o8[3] << 16);
      pk.z = (uint)o8[4] | ((uint)o8[5] << 16);
      pk.w = (uint)o8[6] | ((uint)o8[7] << 16);
      const size_t off = (size_t)(i0g + ii) * 225280 +
                         (size_t)(240 + (ot - 12) * 10 + ks2) * 512 + (kg2 * 16 + lr) * 8;
      *reinterpret_cast<uint4*>(kall + off) = pk;
    }
  }
}

// ---------------- K4: fused attention; vectorized epilogues (P3a operand-swapped) ----------------
__global__ void __launch_bounds__(256, 4) k_attn12(
    const float* __restrict__ cap, const ushort* __restrict__ kall,
    const ushort* __restrict__ capP, const float* __restrict__ ball,
    const float* __restrict__ gptr, float* __restrict__ x_all) {
  __shared__ ushort qkp[24 * 512];       // P1/P2: packed q (units 0-11) + k (12-23); P3: vt
  __shared__ float sc_s[32 * 36];        // fp32 scores [t][s]
  __shared__ ushort at_p[2 * 2 * 64 * 8];
  const int bid = blockIdx.x;
  const int xcd = bid & 7, q = bid >> 3;
  const int i = xcd * 16 + (q >> 6), n = q & 63;
  const int tid = threadIdx.x;
  const int lane = tid & 63, w = tid >> 6;
  const int lrow = lane & 15, kg = lane >> 4;
  const float gamma = gptr[0];
  const ushort* kpL = kall + (size_t)i * 225280 + lane * 8;
  const ushort* cpL = capP + (size_t)n * 20480 + lane * 8;
  const float* bal = ball + i * 512;
  const bool oddw = (w & 1);   // waves 1,3 own only 2 real tiles (tiles 5,11 are all-pad)

  // ---- P1: q+k tiles {0..4, 6..10}, wave w tiles {3w..}; 2-deep A-prefetch
  {
    f32x4 acc[3][2];
#pragma unroll
    for (int a = 0; a < 3; ++a)
#pragma unroll
      for (int b2 = 0; b2 < 2; ++b2) acc[a][b2] = (f32x4){0.f, 0.f, 0.f, 0.f};
    bf16x8 AhA[3], AlA[3], AhB[3], AlB[3];
#pragma unroll
    for (int mt = 0; mt < 3; ++mt)
      if (!oddw || mt < 2) {   // preload kstep 0
        const ushort* p = kpL + (size_t)((w * 3 + mt) * 20) * 512;
        AhA[mt] = *reinterpret_cast<const bf16x8*>(p);
        AlA[mt] = *reinterpret_cast<const bf16x8*>(p + 512);
      }
#pragma unroll
    for (int kp = 0; kp < 5; ++kp) {
      {  // even kstep 2kp
        const int ks = 2 * kp;
        bf16x8 Bh[2], Bl[2];
#pragma unroll
        for (int nt = 0; nt < 2; ++nt) {
          const ushort* p = cpL + (size_t)(nt * 20 + ks * 2) * 512;
          Bh[nt] = *reinterpret_cast<const bf16x8*>(p);
          Bl[nt] = *reinterpret_cast<const bf16x8*>(p + 512);
        }
#pragma unroll
        for (int mt = 0; mt < 3; ++mt)
          if (!oddw || mt < 2) {
            const ushort* p = kpL + (size_t)((w * 3 + mt) * 20 + (ks + 1) * 2) * 512;
            AhB[mt] = *reinterpret_cast<const bf16x8*>(p);
            AlB[mt] = *reinterpret_cast<const bf16x8*>(p + 512);
          }
#pragma unroll
        for (int mt = 0; mt < 3; ++mt)
          if (!oddw || mt < 2)
#pragma unroll
            for (int nt = 0; nt < 2; ++nt) {
              acc[mt][nt] = MFMA16(AhA[mt], Bh[nt], acc[mt][nt]);
              acc[mt][nt] = MFMA16(AhA[mt], Bl[nt], acc[mt][nt]);
              acc[mt][nt] = MFMA16(AlA[mt], Bh[nt], acc[mt][nt]);
            }
      }
      {  // odd kstep 2kp+1
        const int ks = 2 * kp + 1;
        bf16x8 Bh[2], Bl[2];
#pragma unroll
        for (int nt = 0; nt < 2; ++nt) {
          const ushort* p = cpL + (size_t)(nt * 20 + ks * 2) * 512;
          Bh[nt] = *reinterpret_cast<const bf16x8*>(p);
          Bl[nt] = *reinterpret_cast<const bf16x8*>(p + 512);
        }
        if (kp < 4) {
#pragma unroll
          for (int mt = 0; mt < 3; ++mt)
            if (!oddw || mt < 2) {
              const ushort* p = kpL + (size_t)((w * 3 + mt) * 20 + (ks + 1) * 2) * 512;
              AhA[mt] = *reinterpret_cast<const bf16x8*>(p);
              AlA[mt] = *reinterpret_cast<const bf16x8*>(p + 512);
            }
        }
#pragma unroll
        for (int mt = 0; mt < 3; ++mt)
          if (!oddw || mt < 2)
#pragma unroll
            for (int nt = 0; nt < 2; ++nt) {
              acc[mt][nt] = MFMA16(AhB[mt], Bh[nt], acc[mt][nt]);
              acc[mt][nt] = MFMA16(AhB[mt], Bl[nt], acc[mt][nt]);
              acc[mt][nt] = MFMA16(AlB[mt], Bh[nt], acc[mt][nt]);
            }
      }
    }
    // epilogue: q/k packed fragments; 4 r-values land at consecutive e -> uint2 hi/lo writes
#pragma unroll
    for (int mt = 0; mt < 3; ++mt)
#pragma unroll
      for (int nt = 0; nt < 2; ++nt) {
        const int og0 = w * 48 + mt * 16 + kg * 4;     // r = 0
        const int os0 = (w < 2) ? og0 : og0 - 96;
        const int ub = ((w < 2) ? 0 : 12) + nt * 6 + (os0 >> 5) * 2;
        const int lp = ((os0 & 31) >> 3) * 16 + lrow;
        const int e0 = os0 & 7;                         // = (kg&1)*4
        ushort h4[4], l4[4];
#pragma unroll
        for (int r = 0; r < 4; ++r) {
          const float val = acc[mt][nt][r] + bal[og0 + r];
          const ushort hi = f2bf(val);
          h4[r] = hi;
          l4[r] = f2bf(val - bf2f(hi));
        }
        uint2 ph, pl2;
        ph.x = (uint)h4[0] | ((uint)h4[1] << 16);
        ph.y = (uint)h4[2] | ((uint)h4[3] << 16);
        pl2.x = (uint)l4[0] | ((uint)l4[1] << 16);
        pl2.y = (uint)l4[2] | ((uint)l4[3] << 16);
        *reinterpret_cast<uint2*>(&qkp[(ub + 0) * 512 + lp * 8 + e0]) = ph;
        *reinterpret_cast<uint2*>(&qkp[(ub + 1) * 512 + lp * 8 + e0]) = pl2;
      }
  }
  __syncthreads();

  // ---- P2a: scores via MFMA (4-pass split, K=96); wave w -> quadrant (tt,st)
  {
    const int tt = w >> 1, st = w & 1;
    bf16x8 Aq[3][2], Bk[3][2];
#pragma unroll
    for (int k3 = 0; k3 < 3; ++k3)
#pragma unroll
      for (int pl = 0; pl < 2; ++pl) {
        Aq[k3][pl] = *reinterpret_cast<const bf16x8*>(&qkp[(tt * 6 + k3 * 2 + pl) * 512 + lane * 8]);
        Bk[k3][pl] = *reinterpret_cast<const bf16x8*>(&qkp[(12 + st * 6 + k3 * 2 + pl) * 512 + lane * 8]);
      }
    f32x4 D = (f32x4){0.f, 0.f, 0.f, 0.f};
#pragma unroll
    for (int k3 = 0; k3 < 3; ++k3) {
      D = MFMA16(Aq[k3][0], Bk[k3][0], D);
      D = MFMA16(Aq[k3][0], Bk[k3][1], D);
      D = MFMA16(Aq[k3][1], Bk[k3][0], D);
      D = MFMA16(Aq[k3][1], Bk[k3][1], D);
    }
#pragma unroll
    for (int r = 0; r < 4; ++r)
      sc_s[(tt * 16 + kg * 4 + r) * 36 + st * 16 + lrow] = D[r];
  }
  __syncthreads();

  // ---- P2b: softmax (fp32) + pack attn to at_p (bf16 hi/lo, MFMA-B layout)
  {
    const int sg = tid & 7, tq = tid >> 3;
    const int s0 = sg * 4;
    const float4 sv = *reinterpret_cast<const float4*>(&sc_s[tq * 36 + s0]);
    float sc[4] = {sv.x, sv.y, sv.z, sv.w};
    float m = fmaxf(fmaxf(sc[0], sc[1]), fmaxf(sc[2], sc[3]));
    m = fmaxf(m, __shfl_xor(m, 1));
    m = fmaxf(m, __shfl_xor(m, 2));
    m = fmaxf(m, __shfl_xor(m, 4));
    float ev[4], ssum = 0.f;
#pragma unroll
    for (int u = 0; u < 4; ++u) { ev[u] = expf(sc[u] - m); ssum += ev[u]; }
    ssum += __shfl_xor(ssum, 1);
    ssum += __shfl_xor(ssum, 2);
    ssum += __shfl_xor(ssum, 4);
    const float inv = 1.0f / ssum;
    const int tt = tq >> 4, lrp = tq & 15, kgp = sg >> 1, eb = (sg & 1) * 4;
    ushort h4[4], l4[4];
#pragma unroll
    for (int u = 0; u < 4; ++u) {
      const float val = ev[u] * inv;
      const ushort hi = f2bf(val);
      h4[u] = hi;
      l4[u] = f2bf(val - bf2f(hi));
    }
    uint2 ph, pl2;
    ph.x = (uint)h4[0] | ((uint)h4[1] << 16);
    ph.y = (uint)h4[2] | ((uint)h4[3] << 16);
    pl2.x = (uint)l4[0] | ((uint)l4[1] << 16);
    pl2.y = (uint)l4[2] | ((uint)l4[3] << 16);
    *reinterpret_cast<uint2*>(&at_p[((tt * 2 + 0) * 64 + kgp * 16 + lrp) * 8 + eb]) = ph;
    *reinterpret_cast<uint2*>(&at_p[((tt * 2 + 1) * 64 + kgp * 16 + lrp) * 8 + eb]) = pl2;
  }
  __syncthreads();

  // ---- P3: v tiles [12,32) in 2 chunks; SWAPPED proj (A=cap, B=v) -> D[t][c] -> vectorized vt writes
  ushort* vt = qkp;
#pragma unroll
  for (int ch = 0; ch < 2; ++ch) {
    const int TB = 12 + ch * 12;
    const int RB = TB * 16;
    const int nmt = ch ? 2 : 3;
    f32x4 vacc[3][2];
#pragma unroll
    for (int a = 0; a < 3; ++a)
#pragma unroll
      for (int b2 = 0; b2 < 2; ++b2) vacc[a][b2] = (f32x4){0.f, 0.f, 0.f, 0.f};
    bf16x8 AvA[3], AvB[3];
    for (int mi = 0; mi < nmt; ++mi)   // preload kstep 0
      AvA[mi] = *reinterpret_cast<const bf16x8*>(
          kpL + (size_t)(240 + (TB - 12 + w + mi * 4) * 10) * 512);
#pragma unroll
    for (int kp = 0; kp < 5; ++kp) {
      {  // even ks=2kp
        const int ks = 2 * kp;
        bf16x8 Ch[2];
#pragma unroll
        for (int nt = 0; nt < 2; ++nt)
          Ch[nt] = *reinterpret_cast<const bf16x8*>(cpL + (size_t)(nt * 20 + ks * 2) * 512);
        for (int mi = 0; mi < nmt; ++mi)
          AvB[mi] = *reinterpret_cast<const bf16x8*>(
              kpL + (size_t)(240 + (TB - 12 + w + mi * 4) * 10 + ks + 1) * 512);
        for (int mi = 0; mi < nmt; ++mi)
#pragma unroll
          for (int nt = 0; nt < 2; ++nt)
            vacc[mi][nt] = MFMA16(Ch[nt], AvA[mi], vacc[mi][nt]);
      }
      {  // odd ks=2kp+1
        const int ks = 2 * kp + 1;
        bf16x8 Ch[2];
#pragma unroll
        for (int nt = 0; nt < 2; ++nt)
          Ch[nt] = *reinterpret_cast<const bf16x8*>(cpL + (size_t)(nt * 20 + ks * 2) * 512);
        if (kp < 4) {
          for (int mi = 0; mi < nmt; ++mi)
            AvA[mi] = *reinterpret_cast<const bf16x8*>(
                kpL + (size_t)(240 + (TB - 12 + w + mi * 4) * 10 + ks + 1) * 512);
        }
        for (int mi = 0; mi < nmt; ++mi)
#pragma unroll
          for (int nt = 0; nt < 2; ++nt)
            vacc[mi][nt] = MFMA16(Ch[nt], AvB[mi], vacc[mi][nt]);
      }
    }
    if (ch) __syncthreads();   // prior P3b readers of vt done
    // epilogue: D[t][c]: lane holds c = lrow (fixed), t = nt*16 + kg*4 + r -> contiguous e
    for (int mi = 0; mi < nmt; ++mi) {
      const int tile = w + mi * 4;
      const float bb = bal[RB + tile * 16 + lrow];
#pragma unroll
      for (int nt = 0; nt < 2; ++nt) {
        const int lpv = (nt * 2 + (kg >> 1)) * 16 + lrow;
        const int e0v = (kg & 1) * 4;
        ushort h4[4], l4[4];
#pragma unroll
        for (int r = 0; r < 4; ++r) {
          const float val = vacc[mi][nt][r] + bb;
          const ushort hi = f2bf(val);
          h4[r] = hi;
          l4[r] = f2bf(val - bf2f(hi));
        }
        uint2 ph, pl2;
        ph.x = (uint)h4[0] | ((uint)h4[1] << 16);
        ph.y = (uint)h4[2] | ((uint)h4[3] << 16);
        pl2.x = (uint)l4[0] | ((uint)l4[1] << 16);
        pl2.y = (uint)l4[2] | ((uint)l4[3] << 16);
        *reinterpret_cast<uint2*>(&vt[((tile * 2 + 0) * 64 + lpv) * 8 + e0v]) = ph;
        *reinterpret_cast<uint2*>(&vt[((tile * 2 + 1) * 64 + lpv) * 8 + e0v]) = pl2;
      }
    }
    __syncthreads();
    {  // P3b: MFMA PV + residual + max
      bf16x8 ah[2], al[2];
#pragma unroll
      for (int tt = 0; tt < 2; ++tt) {
        ah[tt] = *reinterpret_cast<const bf16x8*>(&at_p[((tt * 2 + 0) * 64 + lane) * 8]);
        al[tt] = *reinterpret_cast<const bf16x8*>(&at_p[((tt * 2 + 1) * 64 + lane) * 8]);
      }
      const int npw = ch ? 2 : 3;
      for (int j = 0; j < npw; ++j) {
        const int ct = w * npw + j;
        const int c0 = ch * 192 + ct * 16 + (lane >> 4) * 4;
        const bf16x8 vh  = *reinterpret_cast<const bf16x8*>(&vt[((ct * 2 + 0) * 64 + lane) * 8]);
        const bf16x8 vl8 = *reinterpret_cast<const bf16x8*>(&vt[((ct * 2 + 1) * 64 + lane) * 8]);
        f32x4 a0 = (f32x4){0.f, 0.f, 0.f, 0.f}, a1 = (f32x4){0.f, 0.f, 0.f, 0.f};
        a0 = MFMA16(vh, ah[0], a0);
        a0 = MFMA16(vh, al[0], a0);
        a0 = MFMA16(vl8, ah[0], a0);
        a1 = MFMA16(vh, ah[1], a1);
        a1 = MFMA16(vh, al[1], a1);
        a1 = MFMA16(vl8, ah[1], a1);
        if (c0 < 300) {
          const int t0 = lane & 15;
          const float4 c4a = *reinterpret_cast<const float4*>(&cap[(size_t)n * 9600 + t0 * 300 + c0]);
          const float4 c4b = *reinterpret_cast<const float4*>(&cap[(size_t)n * 9600 + (t0 + 16) * 300 + c0]);
          float mx[4];
          mx[0] = fmaxf(fmaf(gamma, a0[0], c4a.x), fmaf(gamma, a1[0], c4b.x));
          mx[1] = fmaxf(fmaf(gamma, a0[1], c4a.y), fmaf(gamma, a1[1], c4b.y));
          mx[2] = fmaxf(fmaf(gamma, a0[2], c4a.z), fmaf(gamma, a1[2], c4b.z));
          mx[3] = fmaxf(fmaf(gamma, a0[3], c4a.w), fmaf(gamma, a1[3], c4b.w));
#pragma unroll
          for (int mmask = 1; mmask < 16; mmask <<= 1)
#pragma unroll
            for (int r = 0; r < 4; ++r) mx[r] = fmaxf(mx[r], __shfl_xor(mx[r], mmask));
          if ((lane & 15) == 0)
            *reinterpret_cast<float4*>(&x_all[((size_t)i * 64 + n) * 300 + c0]) =
                make_float4(mx[0], mx[1], mx[2], mx[3]);
        }
      }
    }
  }
}

// ---------------- K5a: h1 = relu(BN1(x @ W1^T + b1)) — BN1 fused ----------------
__global__ void __launch_bounds__(256, 4) k_h1b(
    const float* __restrict__ x_all, const float* __restrict__ W1,
    const float* __restrict__ b1, const float* __restrict__ bn1s,
    const float* __restrict__ bn1b, float* __restrict__ h1) {
  __shared__ float xt[32 * 68];
  __shared__ float wt[32 * 132];
  __shared__ float sc1[128], sh1[128];
  const int ec = blockIdx.x, i = blockIdx.y, tid = threadIdx.x;
  const int e0c = ec * 128;
  const int eg = tid & 15, ng = tid >> 4;
  const int e0 = eg * 8, n0 = ng * 4;
  float acc[4][8] = {};
  for (int cb = 0; cb < 10; ++cb) {
    const int c0 = cb * 32;
    __syncthreads();
    for (int k = 0; k < 8; ++k) {
      const int idx = tid + 256 * k;
      const int nn = idx >> 5, cl = idx & 31;
      const int c = c0 + cl;
      xt[cl * 68 + nn] = (c < 300) ? x_all[((size_t)i * 64 + nn) * 300 + c] : 0.0f;
    }
    for (int k = 0; k < 16; ++k) {
      const int idx = tid + 256 * k;
      const int ee = idx >> 5, cl = idx & 31;
      const int c = c0 + cl;
      wt[cl * 132 + ee] = (c < 300) ? W1[(size_t)(e0c + ee) * 300 + c] : 0.0f;
    }
    __syncthreads();
#pragma unroll 4
    for (int cl = 0; cl < 32; ++cl) {
      const float4 xv = *reinterpret_cast<const float4*>(&xt[cl * 68 + n0]);
      const float4 wa = *reinterpret_cast<const float4*>(&wt[cl * 132 + e0]);
      const float4 wb = *reinterpret_cast<const float4*>(&wt[cl * 132 + e0 + 4]);
      const float xv4[4] = {xv.x, xv.y, xv.z, xv.w};
      const float wv8[8] = {wa.x, wa.y, wa.z, wa.w, wb.x, wb.y, wb.z, wb.w};
#pragma unroll
      for (int u = 0; u < 4; ++u)
#pragma unroll
        for (int v = 0; v < 8; ++v) acc[u][v] = fmaf(xv4[u], wv8[v], acc[u][v]);
    }
  }
  float b1v[8];
#pragma unroll
  for (int v = 0; v < 8; ++v) b1v[v] = b1[e0c + e0 + v];
  float val[4][8];
#pragma unroll
  for (int u = 0; u < 4; ++u)
#pragma unroll
    for (int v = 0; v < 8; ++v) val[u][v] = acc[u][v] + b1v[v];
  __syncthreads();
  float* ps1 = xt;   // [16][132]
  float* ps2 = wt;   // [16][132]
#pragma unroll
  for (int v = 0; v < 8; ++v) {
    float su = 0.f, sq = 0.f;
#pragma unroll
    for (int u = 0; u < 4; ++u) { su += val[u][v]; sq += val[u][v] * val[u][v]; }
    ps1[ng * 132 + e0 + v] = su;
    ps2[ng * 132 + e0 + v] = sq;
  }
  __syncthreads();
  if (tid < 128) {
    const int e = tid;
    float s1 = 0.f, s2 = 0.f;
#pragma unroll 4
    for (int gq = 0; gq < 16; ++gq) { s1 += ps1[gq * 132 + e]; s2 += ps2[gq * 132 + e]; }
    const float mu = s1 * (1.0f / 64.0f);
    const float var = s2 * (1.0f / 64.0f) - mu * mu;
    const float scale = bn1s[e0c + e] / sqrtf(var + EPSB);
    sc1[e] = scale;
    sh1[e] = bn1b[e0c + e] - mu * scale;
  }
  __syncthreads();
#pragma unroll
  for (int u = 0; u < 4; ++u) {
    float o8[8];
#pragma unroll
    for (int v = 0; v < 8; ++v)
      o8[v] = fmaxf(fmaf(val[u][v], sc1[e0 + v], sh1[e0 + v]), 0.0f);
    float* dst = h1 + ((size_t)i * 64 + n0 + u) * 512 + e0c + e0;
    *reinterpret_cast<float4*>(dst) = make_float4(o8[0], o8[1], o8[2], o8[3]);
    *reinterpret_cast<float4*>(dst + 4) = make_float4(o8[4], o8[5], o8[6], o8[7]);
  }
}

// ---------------- K5b: h2 = h1 @ W2^T + b2 ----------------
__global__ void __launch_bounds__(256) k_h2(
    const float* __restrict__ h1, const float* __restrict__ W2,
    const float* __restrict__ b2, float* __restrict__ h2buf) {
  __shared__ float h1s[32 * 517];
  const int jn = blockIdx.x, i = blockIdx.y, tid = threadIdx.x;
  const int bn = jn * 32;
  for (int m = 0; m < 64; ++m) {
    const int idx = tid + 256 * m;   // 16384
    h1s[(idx >> 9) * 517 + (idx & 511)] = h1[((size_t)i * 64 + bn) * 512 + idx];
  }
  __syncthreads();
  const int dg = tid & 15, ng2 = tid >> 4;
  const int d0 = dg * 4, n0 = ng2 * 2;
  float a0[4] = {}, a1[4] = {};
#pragma unroll 4
  for (int e = 0; e < 512; ++e) {
    const float h0 = h1s[n0 * 517 + e];
    const float h1v = h1s[(n0 + 1) * 517 + e];
#pragma unroll
    for (int v = 0; v < 4; ++v) {
      const float wv = W2[(size_t)(d0 + v) * 512 + e];
      a0[v] = fmaf(h0, wv, a0[v]);
      a1[v] = fmaf(h1v, wv, a1[v]);
    }
  }
  const float4 bb = *reinterpret_cast<const float4*>(&b2[d0]);
  float* dst0 = h2buf + ((size_t)i * 64 + bn + n0) * 64 + d0;
  *reinterpret_cast<float4*>(dst0) = make_float4(a0[0] + bb.x, a0[1] + bb.y, a0[2] + bb.z, a0[3] + bb.w);
  *reinterpret_cast<float4*>(dst0 + 64) = make_float4(a1[0] + bb.x, a1[1] + bb.y, a1[2] + bb.z, a1[3] + bb.w);
}

// ---------------- K5c: BN2 + relu + W3 dot -> out ----------------
__global__ void __launch_bounds__(256) k_out(
    const float* __restrict__ h2buf, const float* __restrict__ bn2s,
    const float* __restrict__ bn2b, const float* __restrict__ W3,
    const float* __restrict__ b3, float* __restrict__ out) {
  __shared__ float h2s[64 * 65];
  const int i = blockIdx.x, tid = threadIdx.x;
  for (int m = 0; m < 16; ++m) {
    const int idx = tid + 256 * m;   // 4096
    h2s[(idx >> 6) * 65 + (idx & 63)] = h2buf[(size_t)i * 4096 + idx];
  }
  __syncthreads();
  if (tid < 64) {
    const int d = tid;
    float s1 = 0.f, s2 = 0.f;
    for (int nn = 0; nn < 64; ++nn) {
      const float v = h2s[nn * 65 + d];
      s1 += v;
      s2 += v * v;
    }
    const float mu = s1 * (1.0f / 64.0f);
    const float var = s2 * (1.0f / 64.0f) - mu * mu;
    const float scale = bn2s[d] / sqrtf(var + EPSB);
    const float shift = bn2b[d] - mu * scale;
    for (int nn = 0; nn < 64; ++nn)
      h2s[nn * 65 + d] = fmaxf(fmaf(h2s[nn * 65 + d], scale, shift), 0.0f);
  }
  __syncthreads();
  if (tid < 64) {
    const int nn = tid;
    float acc = b3[0];
    for (int d = 0; d < 64; ++d) acc = fmaf(h2s[nn * 65 + d], W3[d], acc);
    out[i * 64 + nn] = acc;
  }
}

extern "C" void kernel_launch(void* const* d_in, const int* in_sizes, int n_in,
                              void* d_out, int out_size, void* d_ws, size_t ws_size,
                              hipStream_t stream) {
  const float* img  = (const float*)d_in[0];
  const float* cap  = (const float*)d_in[1];
  const float* adW  = (const float*)d_in[2];
  const float* adb  = (const float*)d_in[3];
  const float* qkW  = (const float*)d_in[4];
  const float* qkb  = (const float*)d_in[5];
  const float* qbW  = (const float*)d_in[6];
  const float* qbb  = (const float*)d_in[7];
  const float* qbns = (const float*)d_in[8];
  const float* qbnb = (const float*)d_in[9];
  const float* kkW  = (const float*)d_in[10];
  const float* kkb  = (const float*)d_in[11];
  const float* kbW  = (const float*)d_in[12];
  const float* kbb  = (const float*)d_in[13];
  const float* kbns = (const float*)d_in[14];
  const float* kbnb = (const float*)d_in[15];
  const float* vkW  = (const float*)d_in[16];
  const float* vkb  = (const float*)d_in[17];
  const float* vbW  = (const float*)d_in[18];
  const float* vbb  = (const float*)d_in[19];
  const float* vbns = (const float*)d_in[20];
  const float* vbnb = (const float*)d_in[21];
  const float* gamma= (const float*)d_in[22];
  const float* W1   = (const float*)d_in[23];
  const float* b1   = (const float*)d_in[24];
  const float* bn1s = (const float*)d_in[25];
  const float* bn1b = (const float*)d_in[26];
  const float* W2   = (const float*)d_in[27];
  const float* b2   = (const float*)d_in[28];
  const float* bn2s = (const float*)d_in[29];
  const float* bn2b = (const float*)d_in[30];
  const float* W3   = (const float*)d_in[31];
  const float* b3   = (const float*)d_in[32];

  float* ws    = (float*)d_ws;
  float* base  = ws + OFS_BASE;
  float* ball  = ws + OFS_BALL;
  ushort* capP = (ushort*)(ws + OFS_CAPB);
  ushort* kall = (ushort*)(ws + OFS_RAWP);
  float* x_all = ws + OFS_X;
  float* h2buf = ws + OFS_H2;
  ushort* basP = (ushort*)(ws + OFS_BASP);
  float* h1    = ws + OFS_H1;    // aliases kall (dead after k_attn12)
  float* out   = (float*)d_out;

  k_mb<<<128, 256, 0, stream>>>(img, adW, adb, base);
  k_prep<<<322, 256, 0, stream>>>(qbW, qbb, kbW, kbb, vbW, vbb, base, ball, cap, capP, basP);
  k_hyp5<<<dim3(512, 2), 256, 0, stream>>>(qkW, qkb, kkW, kkb, vkW, vkb,
                                           qbns, qbnb, kbns, kbnb, vbns, vbnb, basP, kall);
  k_attn12<<<8192, 256, 0, stream>>>(cap, kall, capP, ball, gamma, x_all);
  k_h1b<<<dim3(4, 128), 256, 0, stream>>>(x_all, W1, b1, bn1s, bn1b, h1);
  k_h2<<<dim3(2, 128), 256, 0, stream>>>(h1, W2, b2, h2buf);
  k_out<<<128, 256, 0, stream>>>(h2buf, bn2s, bn2b, W3, b3, out);
}